// Round 19
// baseline (897.755 us; speedup 1.0000x reference)
//
#include <hip/hip_runtime.h>
#include <cstdint>

typedef long long i64;
typedef unsigned short u16;
typedef __attribute__((ext_vector_type(8))) short short8;
typedef __attribute__((ext_vector_type(8))) unsigned short us8;
typedef __attribute__((ext_vector_type(4))) float f32x4;

#define NTOK 5456
#define BNROWS 10912
#define NLAYERS 6

__device__ __forceinline__ u16 f2bf(float f) {
  unsigned u = __float_as_uint(f);
  return (u16)((u + 0x7FFFu + ((u >> 16) & 1u)) >> 16);
}
__device__ __forceinline__ float bf2f(u16 h) {
  return __uint_as_float(((unsigned)h) << 16);
}

// ---------------- bf16 MFMA GEMM, 2-phase double-buffered ----------------
template<int BNT>
__global__ __launch_bounds__(256) void mgemm_k(
    const u16* __restrict__ A, const u16* __restrict__ B, int K,
    float* __restrict__ C, float* __restrict__ C2, u16* __restrict__ C16, i64 sCm,
    const float* __restrict__ bias, int relu, int addres, int qkv,
    int M, int N, int mbsh, i64 bCz,
    int KS, float* __restrict__ part)
{
  constexpr int NW = BNT / 32;
  __shared__ u16 Asm[2][128 * 64];
  __shared__ u16 Bsm[2][BNT * 64];
  int tid = threadIdx.x;

  int bx = blockIdx.x, by = blockIdx.y;
  int gx = gridDim.x, gy = gridDim.y;
  int nwg = gx * gy;
  if (KS == 1 && nwg >= 16) {
    int lin = bx + gx * by;
    int xcd = lin & 7, k = lin >> 3;
    int q = nwg >> 3, r = nwg & 7;
    int f = (xcd < r) ? (xcd * (q + 1) + k) : (r * (q + 1) + (xcd - r) * q + k);
    bx = f / gy;
    by = f - bx * gy;
  }
  int m0 = bx * 128, n0 = by * BNT;

  int ks = blockIdx.z;
  int Kc = K / KS;
  int k0 = ks * Kc;
  int lane = tid & 63, w = tid >> 6;
  int wr = w >> 1, wc = w & 1;
  int r16 = lane & 15, g = lane >> 4;

  f32x4 acc[4][NW];
#pragma unroll
  for (int mi = 0; mi < 4; mi++)
#pragma unroll
    for (int nj = 0; nj < NW; nj++) acc[mi][nj] = (f32x4){0.f, 0.f, 0.f, 0.f};

  const u16* Ag = A + (i64)m0 * K + k0;
  const u16* Bg = B + (i64)n0 * K + k0;
  int nt = Kc >> 6;

  auto stage = [&](int buf, int kt) {
#pragma unroll
    for (int r = 0; r < 4; r++) {
      int s = r * 256 + tid;
      int row = s >> 3, c = s & 7;
      int cs = ((c ^ (row & 7)) << 3);
      __builtin_amdgcn_global_load_lds(
          (const __attribute__((address_space(1))) void*)(Ag + (i64)row * K + kt + cs),
          (__attribute__((address_space(3))) void*)(&Asm[buf][(r * 256 + (w << 6)) << 3]),
          16, 0, 0);
    }
#pragma unroll
    for (int r = 0; r < NW; r++) {
      int s = r * 256 + tid;
      int row = s >> 3, c = s & 7;
      int cs = ((c ^ (row & 7)) << 3);
      __builtin_amdgcn_global_load_lds(
          (const __attribute__((address_space(1))) void*)(Bg + (i64)row * K + kt + cs),
          (__attribute__((address_space(3))) void*)(&Bsm[buf][(r * 256 + (w << 6)) << 3]),
          16, 0, 0);
    }
  };

  stage(0, 0);
  __syncthreads();
  for (int t = 0; t < nt; t++) {
    int cur = t & 1;
    if (t + 1 < nt) stage(cur ^ 1, (t + 1) << 6);
#pragma unroll
    for (int h = 0; h < 2; h++) {
      short8 av[4], bv[NW];
#pragma unroll
      for (int mi = 0; mi < 4; mi++) {
        int row = wr * 64 + mi * 16 + r16;
        av[mi] = *(const short8*)&Asm[cur][row * 64 + ((((h << 2) + g) ^ (row & 7)) << 3)];
      }
#pragma unroll
      for (int nj = 0; nj < NW; nj++) {
        int row = wc * (NW * 16) + nj * 16 + r16;
        bv[nj] = *(const short8*)&Bsm[cur][row * 64 + ((((h << 2) + g) ^ (row & 7)) << 3)];
      }
#pragma unroll
      for (int mi = 0; mi < 4; mi++)
#pragma unroll
        for (int nj = 0; nj < NW; nj++)
          acc[mi][nj] = __builtin_amdgcn_mfma_f32_16x16x32_bf16(
              av[mi], bv[nj], acc[mi][nj], 0, 0, 0);
    }
    __syncthreads();
  }

  if (KS > 1) {
#pragma unroll
    for (int mi = 0; mi < 4; mi++)
#pragma unroll
      for (int nj = 0; nj < NW; nj++)
#pragma unroll
        for (int r = 0; r < 4; r++) {
          int grow = m0 + wr * 64 + mi * 16 + g * 4 + r;
          int gcol = n0 + wc * (NW * 16) + nj * 16 + r16;
          if (grow < M) part[((i64)ks * M + grow) * N + gcol] = acc[mi][nj][r];
        }
  } else if (qkv) {
    u16* off16 = (u16*)C;
    u16* att16 = (u16*)C2;
#pragma unroll
    for (int mi = 0; mi < 4; mi++)
#pragma unroll
      for (int nj = 0; nj < NW; nj++)
#pragma unroll
        for (int r = 0; r < 4; r++) {
          int grow = m0 + wr * 64 + mi * 16 + g * 4 + r;
          int gcol = n0 + wc * (NW * 16) + nj * 16 + r16;
          if (grow < M) {
            float v = acc[mi][nj][r] + bias[gcol];
            if (gcol < 320) off16[(i64)grow * 320 + gcol] = f2bf(v);
            else if (gcol < 480) att16[(i64)grow * 160 + (gcol - 320)] = f2bf(v);
            else if (gcol < 736) C16[(i64)grow * 256 + (gcol - 480)] = f2bf(v);
          }
        }
  } else {
    float bv[NW];
    int gc0 = n0 + wc * (NW * 16) + r16;
#pragma unroll
    for (int nj = 0; nj < NW; nj++)
      bv[nj] = bias ? bias[gc0 + nj * 16] : 0.f;
    int mask = (1 << mbsh) - 1;
#pragma unroll
    for (int mi = 0; mi < 4; mi++) {
#pragma unroll
      for (int r = 0; r < 4; r++) {
        int grow = m0 + wr * 64 + mi * 16 + g * 4 + r;
        if (grow >= M) continue;
        i64 rowb = (i64)(grow >> mbsh) * bCz + (i64)(grow & mask) * sCm;
#pragma unroll
        for (int nj = 0; nj < NW; nj++) {
          int gcol = gc0 + nj * 16;
          if (gcol >= N) continue;
          float v = acc[mi][nj][r] + bv[nj];
          if (relu) v = fmaxf(v, 0.f);
          i64 ci = rowb + gcol;
          if (C16) C16[ci] = f2bf(v);
          else {
            if (addres) v += C[ci];
            C[ci] = v;
          }
        }
      }
    }
  }
}

// ---------------- fused LN2+FFN v5: single-buffered weights, 2 blocks/CU ---
// Same per-wave indexing as v3; As overlays B1s before the chunk loop.
__global__ __launch_bounds__(512, 4) void ffn_fused_k(
    float* __restrict__ feats, const u16* __restrict__ w1n,
    const u16* __restrict__ w2n, const float* __restrict__ b1,
    const float* __restrict__ b2, const float* __restrict__ lng,
    const float* __restrict__ lnb, int M)
{
  __shared__ u16 B1s[64 * 256];   // 32 KB (also As overlay pre-loop)
  __shared__ u16 B2s[256 * 64];   // 32 KB
  __shared__ u16 Hs[64 * 88];     // 11 KB
  __shared__ float b1s[1024];     // 4 KB  -> 79 KB total
  u16* As = B1s;

  int tid = threadIdx.x;
  int lane = tid & 63, w = tid >> 6;
  int wr = w >> 1, wc = w & 1;
  int r16 = lane & 15, g = lane >> 4;
  int m0 = blockIdx.x * 64;

  auto stageW = [&](int ch) {
#pragma unroll
    for (int r = 0; r < 4; r++) {
      int s = r * 512 + tid;
      int row = s >> 5, c = s & 31;
      int cs = ((c ^ (row & 7)) << 3);
      __builtin_amdgcn_global_load_lds(
          (const __attribute__((address_space(1))) void*)(w1n + (i64)(ch * 64 + row) * 256 + cs),
          (__attribute__((address_space(3))) void*)(&B1s[(r * 512 + (w << 6)) << 3]),
          16, 0, 0);
    }
#pragma unroll
    for (int r = 0; r < 4; r++) {
      int s = r * 512 + tid;
      int row = s >> 3, c = s & 7;
      int cs = ((c ^ (row & 7)) << 3);
      __builtin_amdgcn_global_load_lds(
          (const __attribute__((address_space(1))) void*)(w2n + (i64)row * 1024 + ch * 64 + cs),
          (__attribute__((address_space(3))) void*)(&B2s[(r * 512 + (w << 6)) << 3]),
          16, 0, 0);
    }
  };

  for (int i = tid; i < 1024; i += 512) b1s[i] = b1[i];

  // LN2 on rows m0..m0+63 -> As (overlays B1s; no staging yet)
  {
    int rw = tid >> 3, c0 = (tid & 7) * 32;
    const float* fr = feats + (i64)(m0 + rw) * 256 + c0;
    float4 x[8];
    float s = 0.f, ss = 0.f;
#pragma unroll
    for (int j = 0; j < 8; j++) {
      x[j] = ((const float4*)fr)[j];
      s += x[j].x + x[j].y + x[j].z + x[j].w;
      ss += x[j].x * x[j].x + x[j].y * x[j].y + x[j].z * x[j].z + x[j].w * x[j].w;
    }
#pragma unroll
    for (int o = 1; o <= 4; o <<= 1) { s += __shfl_xor(s, o); ss += __shfl_xor(ss, o); }
    float mean = s * (1.f / 256.f);
    float rs = rsqrtf(ss * (1.f / 256.f) - mean * mean + 1e-5f);
    const float4* gp = (const float4*)(lng + c0);
    const float4* bp = (const float4*)(lnb + c0);
#pragma unroll
    for (int j = 0; j < 8; j += 2) {
      float4 g0 = gp[j], g1 = gp[j + 1];
      float4 b0 = bp[j], b1_ = bp[j + 1];
      us8 o;
      o[0] = f2bf((x[j].x - mean) * rs * g0.x + b0.x);
      o[1] = f2bf((x[j].y - mean) * rs * g0.y + b0.y);
      o[2] = f2bf((x[j].z - mean) * rs * g0.z + b0.z);
      o[3] = f2bf((x[j].w - mean) * rs * g0.w + b0.w);
      o[4] = f2bf((x[j + 1].x - mean) * rs * g1.x + b1_.x);
      o[5] = f2bf((x[j + 1].y - mean) * rs * g1.y + b1_.y);
      o[6] = f2bf((x[j + 1].z - mean) * rs * g1.z + b1_.z);
      o[7] = f2bf((x[j + 1].w - mean) * rs * g1.w + b1_.w);
      int gr = (tid & 7) * 4 + (j >> 1);
      *(us8*)&As[rw * 256 + ((gr ^ (rw & 7)) << 3)] = o;
    }
  }
  __syncthreads();

  short8 av_all[8];
  {
    int row = wr * 16 + r16;
#pragma unroll
    for (int ks = 0; ks < 8; ks++)
      av_all[ks] = *(const short8*)&As[row * 256 + (((ks * 4 + g) ^ (row & 7)) << 3)];
  }
  __syncthreads();   // As reads done; B1s free for staging

  f32x4 acc2[8];
#pragma unroll
  for (int nj = 0; nj < 8; nj++) acc2[nj] = (f32x4){0.f, 0.f, 0.f, 0.f};

  for (int ch = 0; ch < 16; ch++) {
    stageW(ch);
    __syncthreads();   // weights resident (drains vmcnt)

    f32x4 acc1[2];
#pragma unroll
    for (int nj = 0; nj < 2; nj++) acc1[nj] = (f32x4){0.f, 0.f, 0.f, 0.f};
#pragma unroll
    for (int ks = 0; ks < 8; ks++) {
      short8 bv[2];
#pragma unroll
      for (int nj = 0; nj < 2; nj++) {
        int row = wc * 32 + nj * 16 + r16;
        bv[nj] = *(const short8*)&B1s[row * 256 + (((ks * 4 + g) ^ (row & 7)) << 3)];
      }
#pragma unroll
      for (int nj = 0; nj < 2; nj++)
        acc1[nj] = __builtin_amdgcn_mfma_f32_16x16x32_bf16(
            av_all[ks], bv[nj], acc1[nj], 0, 0, 0);
    }
#pragma unroll
    for (int nj = 0; nj < 2; nj++)
#pragma unroll
      for (int r = 0; r < 4; r++) {
        int hr = wr * 16 + g * 4 + r;
        int hc = wc * 32 + nj * 16 + r16;
        float v = acc1[nj][r] + b1s[ch * 64 + hc];
        Hs[hr * 88 + hc] = f2bf(fmaxf(v, 0.f));
      }
    __syncthreads();   // Hs visible

#pragma unroll
    for (int hh = 0; hh < 2; hh++) {
      short8 av2 = *(const short8*)&Hs[(wr * 16 + r16) * 88 + hh * 32 + g * 8];
      short8 bv2[8];
#pragma unroll
      for (int nj = 0; nj < 8; nj++) {
        int n = wc * 128 + nj * 16 + r16;
        bv2[nj] = *(const short8*)&B2s[n * 64 + (((hh * 4 + g) ^ (n & 7)) << 3)];
      }
#pragma unroll
      for (int nj = 0; nj < 8; nj++)
        acc2[nj] = __builtin_amdgcn_mfma_f32_16x16x32_bf16(
            av2, bv2[nj], acc2[nj], 0, 0, 0);
    }
    __syncthreads();   // all reads done before next stage overwrites
  }

#pragma unroll
  for (int r = 0; r < 4; r++) {
    int grow = m0 + wr * 16 + g * 4 + r;
    if (grow >= M) continue;
#pragma unroll
    for (int nj = 0; nj < 8; nj++) {
      int col = wc * 128 + nj * 16 + r16;
      i64 ci = (i64)grow * 256 + col;
      feats[ci] += acc2[nj][r] + b2[col];
    }
  }
}

// reduce split-K fp32 partials (stride N); row map via shift/mask
__global__ void reduce_k(const float* __restrict__ part, float* __restrict__ C,
    const float* __restrict__ bias, int mbsh, i64 bCz, i64 sCm, int M, int N, int KS)
{
  int idx = blockIdx.x * 256 + threadIdx.x;
  if (idx >= M * N) return;
  int m = idx / N, n = idx - m * N;
  float v = bias ? bias[n] : 0.f;
  for (int ks = 0; ks < KS; ks++) v += part[((i64)ks * M + m) * N + n];
  C[(i64)(m >> mbsh) * bCz + (i64)(m & ((1 << mbsh) - 1)) * sCm + n] = v;
}

// ---------------- prologue weight conversion (linear, coalesced) -----------
__global__ void cvt_pro_k(const float* __restrict__ pw0, const float* __restrict__ pw1,
    const float* __restrict__ pw2, const float* __restrict__ buw0,
    const float* __restrict__ buw1, u16* __restrict__ dst)
{
  int idx = blockIdx.x * 256 + threadIdx.x;
  if (idx >= 6225920) return;
  float v;
  if (idx < 131072) v = pw0[idx];
  else if (idx < 393216) v = pw1[idx - 131072];
  else if (idx < 917504) v = pw2[idx - 393216];
  else if (idx < 5636096) v = buw0[idx - 917504];
  else v = buw1[idx - 5636096];
  dst[idx] = f2bf(v);
}

// generic tiled transpose-convert for layer weights
__global__ __launch_bounds__(256) void trans_w_k(const float* __restrict__ src,
    u16* __restrict__ dst, i64 srcLS, i64 dstLS, int srcStride, int dstStride)
{
  __shared__ float tile[32][33];
  int n0 = blockIdx.x * 32, k0 = blockIdx.y * 32, L = blockIdx.z;
  const float* s = src + (i64)L * srcLS;
  u16* d = dst + (i64)L * dstLS;
  int tx = threadIdx.x & 31, ty = threadIdx.x >> 5;
  for (int i = ty; i < 32; i += 8)
    tile[i][tx] = s[(i64)(k0 + i) * srcStride + n0 + tx];
  __syncthreads();
  for (int i = ty; i < 32; i += 8)
    d[(i64)(n0 + i) * dstStride + k0 + tx] = f2bf(tile[tx][i]);
}

// zero qkv pad rows [736,768) per layer + combined qkv bias
__global__ void fill_bias_k(u16* __restrict__ wb6, float* __restrict__ bq,
    const float* __restrict__ boff, const float* __restrict__ batt,
    const float* __restrict__ bval)
{
  int idx = blockIdx.x * 256 + threadIdx.x;
  if (idx < 49152) {
    int L = idx >> 13, o = idx & 8191;
    wb6[(i64)L * 786432 + 736 * 256 + o] = 0;
  }
  if (idx < NLAYERS * 768) {
    int L = idx / 768, n = idx - L * 768;
    float v;
    if (n < 320) v = boff[(i64)L * 320 + n];
    else if (n < 480) v = batt[(i64)L * 160 + (n - 320)];
    else if (n < 736) v = bval[(i64)L * 256 + (n - 480)];
    else v = 0.f;
    bq[idx] = v;
  }
}

// tiled transpose-convert: in [2][K][P] f32 -> out [2*P][K] bf16
__global__ __launch_bounds__(256) void trans_cvt_k(const float* __restrict__ in,
    u16* __restrict__ out, int K, int P)
{
  __shared__ float tile[32][33];
  int p0 = blockIdx.x * 32, k0 = blockIdx.y * 32, b = blockIdx.z;
  int tx = threadIdx.x & 31, ty = threadIdx.x >> 5;
  const float* ib = in + (i64)b * K * P;
  for (int i = ty; i < 32; i += 8)
    tile[i][tx] = ib[(i64)(k0 + i) * P + p0 + tx];
  __syncthreads();
  for (int i = ty; i < 32; i += 8)
    out[((i64)b * P + p0 + i) * K + k0 + tx] = f2bf(tile[tx][i]);
}

__global__ void im2col_bf16_k(const float* __restrict__ in, u16* __restrict__ out,
    int Cin, int Hin, int Win, int Ho, int Wo)
{
  int Kk = Cin * 9;
  i64 total = (i64)2 * Ho * Wo * Kk;
  i64 o = (i64)blockIdx.x * 256 + threadIdx.x;
  if (o >= total) return;
  int k = (int)(o % Kk);
  int m = (int)(o / Kk);
  int hw = Ho * Wo;
  int b = m / hw, pix = m - b * hw;
  int oy = pix / Wo, ox = pix - oy * Wo;
  int ci = k / 9, r = k - ci * 9;
  int ky = r / 3, kx = r - ky * 3;
  int iy = oy * 2 - 1 + ky, ix = ox * 2 - 1 + kx;
  float v = 0.f;
  if (iy >= 0 && iy < Hin && ix >= 0 && ix < Win)
    v = in[(((i64)b * Cin + ci) * Hin + iy) * Win + ix];
  out[o] = f2bf(v);
}

__global__ void gn_relu_k(const float* __restrict__ feats, float* __restrict__ y,
    const float* __restrict__ g, const float* __restrict__ bt)
{
  int grp = blockIdx.x, b = blockIdx.y;
  int tid = threadIdx.x;
  const float* fb = feats + ((i64)b * NTOK + 5376) * 256 + grp * 32;
  float s = 0.f, ss = 0.f;
  for (int i = tid; i < 2048; i += 256) {
    int cl = i >> 6, p = i & 63;
    float v = fb[(i64)p * 256 + cl];
    s += v; ss += v * v;
  }
  __shared__ float sb[4], ssb[4];
#pragma unroll
  for (int o = 32; o > 0; o >>= 1) { s += __shfl_down(s, o); ss += __shfl_down(ss, o); }
  int wv = tid >> 6;
  if ((tid & 63) == 0) { sb[wv] = s; ssb[wv] = ss; }
  __syncthreads();
  float ts = sb[0] + sb[1] + sb[2] + sb[3];
  float tss = ssb[0] + ssb[1] + ssb[2] + ssb[3];
  float mean = ts * (1.f / 2048.f);
  float rs = rsqrtf(tss * (1.f / 2048.f) - mean * mean + 1e-5f);
  for (int i = tid; i < 2048; i += 256) {
    int cl = i >> 6, p = i & 63;
    int c = grp * 32 + cl;
    float v = (fb[(i64)p * 256 + cl] - mean) * rs * g[c] + bt[c];
    y[((i64)b * 256 + c) * 64 + p] = fmaxf(v, 0.f);
  }
}

__global__ __launch_bounds__(256) void ln_k(const float* __restrict__ x,
    u16* __restrict__ y, const float* __restrict__ g, const float* __restrict__ bt,
    int rows)
{
  int row = blockIdx.x * 4 + (threadIdx.x >> 6);
  if (row >= rows) return;
  int lane = threadIdx.x & 63;
  float4 v = ((const float4*)(x + (i64)row * 256))[lane];
  float s = v.x + v.y + v.z + v.w;
  float ss = v.x * v.x + v.y * v.y + v.z * v.z + v.w * v.w;
#pragma unroll
  for (int o = 32; o > 0; o >>= 1) { s += __shfl_down(s, o); ss += __shfl_down(ss, o); }
  s = __shfl(s, 0);
  ss = __shfl(ss, 0);
  float mean = s * (1.f / 256.f);
  float rs = rsqrtf(ss * (1.f / 256.f) - mean * mean + 1e-5f);
  float4 gg = ((const float4*)g)[lane];
  float4 bb = ((const float4*)bt)[lane];
  ushort4 o4;
  o4.x = f2bf((v.x - mean) * rs * gg.x + bb.x);
  o4.y = f2bf((v.y - mean) * rs * gg.y + bb.y);
  o4.z = f2bf((v.z - mean) * rs * gg.z + bb.z);
  o4.w = f2bf((v.w - mean) * rs * gg.w + bb.w);
  ((ushort4*)(y + (i64)row * 256))[lane] = o4;
}

// deformable sampling v5 (known-good)
__global__ __launch_bounds__(256) void dsample_k(
    const u16* __restrict__ val, const u16* __restrict__ off,
    const u16* __restrict__ att, u16* __restrict__ out)
{
  const int FH[5] = {64, 32, 16, 8, 4};
  const int ST[5] = {0, 4096, 5120, 5376, 5440};
  int bid = blockIdx.x;
  int chunk = (bid & 7) * 86 + (bid >> 3);
  if (chunk >= 682) return;
  int lane = threadIdx.x & 63;
  int half = lane >> 5;
  int l32 = lane & 31;
  int t = chunk * 8 + ((threadIdx.x >> 6) << 1) + half;
  int b = blockIdx.y;
  int h = l32 >> 2, d4 = l32 & 3;

  int lv;
  if (t < 4096)      lv = 0;
  else if (t < 5120) lv = 1;
  else if (t < 5376) lv = 2;
  else if (t < 5440) lv = 3;
  else               lv = 4;
  int loc = t - ST[lv];
  int sh = 6 - lv;
  int py = loc >> sh, px = loc - (py << sh);
  float inv = 1.f / (float)FH[lv];
  float prx = (px + 0.5f) * inv, pry = (py + 0.5f) * inv;
  i64 bt = (i64)b * NTOK + t;
  const u16* offp = off + bt * 320 + h * 40;
  const u16* attp = att + bt * 160 + h * 20;
  const u16* vbase = val + ((i64)b * NTOK) * 256 + h * 32 + d4 * 8;

  float own_a[5], own_fx[5], own_fy[5];
  int own_pk[5];
  float mx = -1e30f;
#pragma unroll
  for (int j = 0; j < 5; j++) {
    float lg = bf2f(attp[d4 + 4 * j]);
    own_a[j] = lg;
    mx = fmaxf(mx, lg);
  }
  mx = fmaxf(mx, __shfl_xor(mx, 1));
  mx = fmaxf(mx, __shfl_xor(mx, 2));
  float sum = 0.f;
#pragma unroll
  for (int j = 0; j < 5; j++) {
    float e = __expf(own_a[j] - mx);
    own_a[j] = e;
    sum += e;
  }
  sum += __shfl_xor(sum, 1);
  sum += __shfl_xor(sum, 2);
  float rinv = 1.f / sum;
#pragma unroll
  for (int j = 0; j < 5; j++) {
    int p = d4 + 4 * j;
    own_a[j] *= rinv;
    unsigned opk = *(const unsigned*)(offp + 2 * p);
    float ox = bf2f((u16)(opk & 0xFFFF));
    float oy = bf2f((u16)(opk >> 16));
    float sff = (float)(64 >> j);
    float xx = prx * sff + ox - 0.5f;
    float yy = pry * sff + oy - 0.5f;
    float xf = floorf(xx), yf = floorf(yy);
    own_fx[j] = xx - xf;
    own_fy[j] = yy - yf;
    own_pk[j] = (((int)yf) << 16) | (((int)xf) & 0xFFFF);
  }

  float acc[8] = {0.f, 0.f, 0.f, 0.f, 0.f, 0.f, 0.f, 0.f};
#pragma unroll
  for (int p = 0; p < 20; p++) {
    const int j = p >> 2;
    const int sf = FH[j], st = ST[j];
    int src = (half << 5) | (h << 2) | (p & 3);
    float wa = __shfl(own_a[j], src);
    float fx = __shfl(own_fx[j], src);
    float fy = __shfl(own_fy[j], src);
    int pk = __shfl(own_pk[j], src);
    int x0 = (pk << 16) >> 16;
    int y0 = pk >> 16;
    float gx0 = wa - wa * fx, gx1 = wa * fx;
    float w00 = gx0 - gx0 * fy, w01 = gx0 * fy;
    float w10 = gx1 - gx1 * fy, w11 = gx1 * fy;
    bool xin0 = (x0 >= 0) & (x0 < sf), xin1 = (x0 + 1 >= 0) & (x0 + 1 < sf);
    bool yin0 = (y0 >= 0) & (y0 < sf), yin1 = (y0 + 1 >= 0) & (y0 + 1 < sf);
    int ibase = st + y0 * sf + x0;
#define FMA8(W, IDX) { \
      us8 v = *(const us8*)(vbase + (i64)(IDX) * 256); \
      acc[0] = fmaf(W, bf2f(v[0]), acc[0]); acc[1] = fmaf(W, bf2f(v[1]), acc[1]); \
      acc[2] = fmaf(W, bf2f(v[2]), acc[2]); acc[3] = fmaf(W, bf2f(v[3]), acc[3]); \
      acc[4] = fmaf(W, bf2f(v[4]), acc[4]); acc[5] = fmaf(W, bf2f(v[5]), acc[5]); \
      acc[6] = fmaf(W, bf2f(v[6]), acc[6]); acc[7] = fmaf(W, bf2f(v[7]), acc[7]); }
    if (xin0 & yin0) FMA8(w00, ibase);
    if (xin1 & yin0) FMA8(w10, ibase + 1);
    if (xin0 & yin1) FMA8(w01, ibase + sf);
    if (xin1 & yin1) FMA8(w11, ibase + sf + 1);
#undef FMA8
  }
  us8 o;
#pragma unroll
  for (int i = 0; i < 8; i++) o[i] = f2bf(acc[i]);
  *(us8*)(out + ((bt * 8 + h) * 32 + d4 * 8)) = o;
}

// all 5 levels in one dispatch
__global__ __launch_bounds__(256) void untranspose_all_k(
    const float* __restrict__ feats, float* __restrict__ out)
{
  int u = blockIdx.x;
  int pt0, start, S; i64 ooff;
  if (u < 128)      { pt0 = u;       start = 0;    S = 4096; ooff = 0; }
  else if (u < 160) { pt0 = u - 128; start = 4096; S = 1024; ooff = 2097152; }
  else if (u < 168) { pt0 = u - 160; start = 5120; S = 256;  ooff = 2621440; }
  else if (u < 170) { pt0 = u - 168; start = 5376; S = 64;   ooff = 2752512; }
  else              { pt0 = 0;       start = 5440; S = 16;   ooff = 2785280; }
  __shared__ float tile[32][33];
  int pt = pt0 * 32, ct = blockIdx.y * 32, b = blockIdx.z;
  int tx = threadIdx.x & 31, ty = threadIdx.x >> 5;
  for (int i = ty; i < 32; i += 8) {
    int p = pt + i;
    tile[i][tx] = (p < S) ? feats[((i64)b * NTOK + start + p) * 256 + ct + tx] : 0.f;
  }
  __syncthreads();
  for (int i = ty; i < 32; i += 8) {
    int c = ct + i, p = pt + tx;
    if (p < S) out[ooff + ((i64)b * 256 + c) * S + p] = tile[tx][i];
  }
}

extern "C" void kernel_launch(void* const* d_in, const int* in_sizes, int n_in,
                              void* d_out, int out_size, void* d_ws, size_t ws_size,
                              hipStream_t stream)
{
  const float* in0  = (const float*)d_in[0];
  const float* in1  = (const float*)d_in[1];
  const float* in2  = (const float*)d_in[2];
  const float* pw0  = (const float*)d_in[3];
  const float* pb0  = (const float*)d_in[4];
  const float* pw1  = (const float*)d_in[5];
  const float* pb1  = (const float*)d_in[6];
  const float* pw2  = (const float*)d_in[7];
  const float* pb2  = (const float*)d_in[8];
  const float* buw0 = (const float*)d_in[9];
  const float* bub0 = (const float*)d_in[10];
  const float* gng  = (const float*)d_in[11];
  const float* gnb  = (const float*)d_in[12];
  const float* buw1 = (const float*)d_in[13];
  const float* bub1 = (const float*)d_in[14];
  const float* ln1g = (const float*)d_in[15];
  const float* ln1b = (const float*)d_in[16];
  const float* woff = (const float*)d_in[17];
  const float* boff = (const float*)d_in[18];
  const float* watt = (const float*)d_in[19];
  const float* batt = (const float*)d_in[20];
  const float* wval = (const float*)d_in[21];
  const float* bval = (const float*)d_in[22];
  const float* wout = (const float*)d_in[23];
  const float* bout = (const float*)d_in[24];
  const float* ln2g = (const float*)d_in[25];
  const float* ln2b = (const float*)d_in[26];
  const float* w1   = (const float*)d_in[27];
  const float* b1   = (const float*)d_in[28];
  const float* w2   = (const float*)d_in[29];
  const float* b2   = (const float*)d_in[30];
  float* out = (float*)d_out;

  const i64 TC = (i64)NTOK * 256;

  // ---- ws layout (f32 units) ----
  float* ws    = (float*)d_ws;
  float* feats = ws;                               // 2,793,472
  u16*   qb    = (u16*)(feats + 2793472);          // 11008x256 bf16
  u16*   valb  = qb + 2818048;
  u16*   sampb = valb + 2818048;
  float* U     = (float*)(sampb + 2818048);        // union region: 5,637,120 f32
  u16*   off16 = (u16*)U;                          // [10912][320] bf16
  u16*   att16 = off16 + 3491840;                  // [10912][160] bf16
  u16*   abuf  = (u16*)U;                          // prologue A
  float* part  = U + 2097152;                      // split-K partials
  u16*   wb    = (u16*)(U + 5637120);              // 10,944,512 bf16
  float* bqkv  = (float*)(wb + 10944512);          // 4,608 f32
  float* m4gn  = bqkv + 4608;                      // 32,768 f32

  auto mg64 = [&](dim3 grid, const u16* A, const u16* B, int K,
                  float* C, float* C2, u16* C16, i64 sCm, const float* bias,
                  int relu, int addres, int qkv, int M, int N, int mbsh, i64 bCz, int KS) {
    mgemm_k<64><<<grid, dim3(256), 0, stream>>>(A, B, K, C, C2, C16, sCm, bias,
        relu, addres, qkv, M, N, mbsh, bCz, KS, part);
  };

  // ---- weight conversion (coalesced) ----
  cvt_pro_k<<<dim3(24320), dim3(256), 0, stream>>>(pw0, pw1, pw2, buw0, buw1, wb);
  u16* wbL0 = wb + 6225920;
  trans_w_k<<<dim3(10, 8, NLAYERS), dim3(256), 0, stream>>>(
      woff, wbL0, 81920, 786432, 320, 256);
  trans_w_k<<<dim3(5, 8, NLAYERS), dim3(256), 0, stream>>>(
      watt, wbL0 + 320 * 256, 40960, 786432, 160, 256);
  trans_w_k<<<dim3(8, 8, NLAYERS), dim3(256), 0, stream>>>(
      wval, wbL0 + 480 * 256, 65536, 786432, 256, 256);
  trans_w_k<<<dim3(8, 8, NLAYERS), dim3(256), 0, stream>>>(
      wout, wbL0 + 196608, 65536, 786432, 256, 256);
  trans_w_k<<<dim3(32, 8, NLAYERS), dim3(256), 0, stream>>>(
      w1, wbL0 + 262144, 262144, 786432, 1024, 256);
  trans_w_k<<<dim3(8, 32, NLAYERS), dim3(256), 0, stream>>>(
      w2, wbL0 + 524288, 262144, 786432, 256, 1024);
  fill_bias_k<<<dim3(192), dim3(256), 0, stream>>>(wbL0, bqkv, boff, batt, bval);

  // ---- projections (tiled transpose-convert, coalesced) ----
  trans_cvt_k<<<dim3(128, 16, 2), dim3(256), 0, stream>>>(in0, abuf, 512, 4096);
  mg64(dim3(64, 4, 1), abuf, wb, 512, feats, nullptr, nullptr, 256, pb0, 0, 0, 0,
       8192, 256, 12, TC, 1);
  trans_cvt_k<<<dim3(32, 32, 2), dim3(256), 0, stream>>>(in1, abuf, 1024, 1024);
  mg64(dim3(16, 4, 1), abuf, wb + 131072, 1024, feats + (i64)4096 * 256, nullptr,
       nullptr, 256, pb1, 0, 0, 0, 2048, 256, 10, TC, 1);
  trans_cvt_k<<<dim3(8, 64, 2), dim3(256), 0, stream>>>(in2, abuf, 2048, 256);
  mg64(dim3(4, 4, 4), abuf, wb + 393216, 2048, nullptr, nullptr, nullptr, 256,
       nullptr, 0, 0, 0, 512, 256, 8, 0, 4);
  reduce_k<<<dim3(512), dim3(256), 0, stream>>>(part, feats + (i64)5120 * 256, pb2,
      8, TC, 256, 512, 256, 4);

  // ---- bottom-up conv0 ----
  im2col_bf16_k<<<dim3(9216), dim3(256), 0, stream>>>(in2, abuf, 2048, 16, 16, 8, 8);
  mg64(dim3(1, 4, 16), abuf, wb + 917504, 18432, nullptr, nullptr, nullptr, 256,
       nullptr, 0, 0, 0, 128, 256, 6, 0, 16);
  reduce_k<<<dim3(128), dim3(256), 0, stream>>>(part, feats + (i64)5376 * 256, bub0,
      6, TC, 256, 128, 256, 16);

  // ---- GN+ReLU, bottom-up conv1 ----
  gn_relu_k<<<dim3(8, 2), dim3(256), 0, stream>>>(feats, m4gn, gng, gnb);
  im2col_bf16_k<<<dim3(288), dim3(256), 0, stream>>>(m4gn, abuf, 256, 8, 8, 4, 4);
  mg64(dim3(1, 4, 4), abuf, wb + 5636096, 2304, nullptr, nullptr, nullptr, 256,
       nullptr, 0, 0, 0, 32, 256, 4, 0, 4);
  reduce_k<<<dim3(32), dim3(256), 0, stream>>>(part, feats + (i64)5440 * 256, bub1,
      4, TC, 256, 32, 256, 4);

  // ---- 6 transformer layers ----
  for (int i = 0; i < NLAYERS; i++) {
    const u16* wbL = wb + 6225920 + (i64)i * 786432;
    ln_k<<<dim3(2728), dim3(256), 0, stream>>>(feats, qb,
        ln1g + (i64)i * 256, ln1b + (i64)i * 256, BNROWS);
    mg64(dim3(86, 12, 1), qb, wbL, 256, (float*)off16, (float*)att16, valb, 0,
         bqkv + (i64)i * 768, 0, 0, 1, BNROWS, 768, 14, 0, 1);
    dsample_k<<<dim3(688, 2), dim3(256), 0, stream>>>(valb, off16, att16, sampb);
    mg64(dim3(86, 4, 1), sampb, wbL + 196608, 256, feats, nullptr, nullptr, 256,
         bout + (i64)i * 256, 0, 1, 0, BNROWS, 256, 14, 0, 1);
    ffn_fused_k<<<dim3(171), dim3(512), 0, stream>>>(feats, wbL + 262144,
        wbL + 524288, b1 + (i64)i * 1024, b2 + (i64)i * 256,
        ln2g + (i64)i * 256, ln2b + (i64)i * 256, BNROWS);
  }

  // ---- split into 5 level maps (one dispatch) ----
  untranspose_all_k<<<dim3(171, 8, 2), dim3(256), 0, stream>>>(feats, out);
  (void)in_sizes; (void)n_in; (void)out_size; (void)ws_size;
}

// Round 20
// 879.821 us; speedup vs baseline: 1.0204x; 1.0204x over previous
//
#include <hip/hip_runtime.h>
#include <cstdint>

typedef long long i64;
typedef unsigned short u16;
typedef __attribute__((ext_vector_type(8))) short short8;
typedef __attribute__((ext_vector_type(8))) unsigned short us8;
typedef __attribute__((ext_vector_type(4))) float f32x4;

#define NTOK 5456
#define BNROWS 10912
#define NLAYERS 6

__device__ __forceinline__ u16 f2bf(float f) {
  unsigned u = __float_as_uint(f);
  return (u16)((u + 0x7FFFu + ((u >> 16) & 1u)) >> 16);
}
__device__ __forceinline__ float bf2f(u16 h) {
  return __uint_as_float(((unsigned)h) << 16);
}

// ---------------- bf16 MFMA GEMM, 2-phase double-buffered ----------------
template<int BNT>
__global__ __launch_bounds__(256) void mgemm_k(
    const u16* __restrict__ A, const u16* __restrict__ B, int K,
    float* __restrict__ C, float* __restrict__ C2, u16* __restrict__ C16, i64 sCm,
    const float* __restrict__ bias, int relu, int addres, int qkv,
    int M, int N, int mbsh, i64 bCz,
    int KS, float* __restrict__ part)
{
  constexpr int NW = BNT / 32;
  __shared__ u16 Asm[2][128 * 64];
  __shared__ u16 Bsm[2][BNT * 64];
  int tid = threadIdx.x;

  int bx = blockIdx.x, by = blockIdx.y;
  int gx = gridDim.x, gy = gridDim.y;
  int nwg = gx * gy;
  if (KS == 1 && nwg >= 16) {
    int lin = bx + gx * by;
    int xcd = lin & 7, k = lin >> 3;
    int q = nwg >> 3, r = nwg & 7;
    int f = (xcd < r) ? (xcd * (q + 1) + k) : (r * (q + 1) + (xcd - r) * q + k);
    bx = f / gy;
    by = f - bx * gy;
  }
  int m0 = bx * 128, n0 = by * BNT;

  int ks = blockIdx.z;
  int Kc = K / KS;
  int k0 = ks * Kc;
  int lane = tid & 63, w = tid >> 6;
  int wr = w >> 1, wc = w & 1;
  int r16 = lane & 15, g = lane >> 4;

  f32x4 acc[4][NW];
#pragma unroll
  for (int mi = 0; mi < 4; mi++)
#pragma unroll
    for (int nj = 0; nj < NW; nj++) acc[mi][nj] = (f32x4){0.f, 0.f, 0.f, 0.f};

  const u16* Ag = A + (i64)m0 * K + k0;
  const u16* Bg = B + (i64)n0 * K + k0;
  int nt = Kc >> 6;

  auto stage = [&](int buf, int kt) {
#pragma unroll
    for (int r = 0; r < 4; r++) {
      int s = r * 256 + tid;
      int row = s >> 3, c = s & 7;
      int cs = ((c ^ (row & 7)) << 3);
      __builtin_amdgcn_global_load_lds(
          (const __attribute__((address_space(1))) void*)(Ag + (i64)row * K + kt + cs),
          (__attribute__((address_space(3))) void*)(&Asm[buf][(r * 256 + (w << 6)) << 3]),
          16, 0, 0);
    }
#pragma unroll
    for (int r = 0; r < NW; r++) {
      int s = r * 256 + tid;
      int row = s >> 3, c = s & 7;
      int cs = ((c ^ (row & 7)) << 3);
      __builtin_amdgcn_global_load_lds(
          (const __attribute__((address_space(1))) void*)(Bg + (i64)row * K + kt + cs),
          (__attribute__((address_space(3))) void*)(&Bsm[buf][(r * 256 + (w << 6)) << 3]),
          16, 0, 0);
    }
  };

  stage(0, 0);
  __syncthreads();
  for (int t = 0; t < nt; t++) {
    int cur = t & 1;
    if (t + 1 < nt) stage(cur ^ 1, (t + 1) << 6);
#pragma unroll
    for (int h = 0; h < 2; h++) {
      short8 av[4], bv[NW];
#pragma unroll
      for (int mi = 0; mi < 4; mi++) {
        int row = wr * 64 + mi * 16 + r16;
        av[mi] = *(const short8*)&Asm[cur][row * 64 + ((((h << 2) + g) ^ (row & 7)) << 3)];
      }
#pragma unroll
      for (int nj = 0; nj < NW; nj++) {
        int row = wc * (NW * 16) + nj * 16 + r16;
        bv[nj] = *(const short8*)&Bsm[cur][row * 64 + ((((h << 2) + g) ^ (row & 7)) << 3)];
      }
#pragma unroll
      for (int mi = 0; mi < 4; mi++)
#pragma unroll
        for (int nj = 0; nj < NW; nj++)
          acc[mi][nj] = __builtin_amdgcn_mfma_f32_16x16x32_bf16(
              av[mi], bv[nj], acc[mi][nj], 0, 0, 0);
    }
    __syncthreads();
  }

  if (KS > 1) {
#pragma unroll
    for (int mi = 0; mi < 4; mi++)
#pragma unroll
      for (int nj = 0; nj < NW; nj++)
#pragma unroll
        for (int r = 0; r < 4; r++) {
          int grow = m0 + wr * 64 + mi * 16 + g * 4 + r;
          int gcol = n0 + wc * (NW * 16) + nj * 16 + r16;
          if (grow < M) part[((i64)ks * M + grow) * N + gcol] = acc[mi][nj][r];
        }
  } else if (qkv) {
    u16* off16 = (u16*)C;
    u16* att16 = (u16*)C2;
#pragma unroll
    for (int mi = 0; mi < 4; mi++)
#pragma unroll
      for (int nj = 0; nj < NW; nj++)
#pragma unroll
        for (int r = 0; r < 4; r++) {
          int grow = m0 + wr * 64 + mi * 16 + g * 4 + r;
          int gcol = n0 + wc * (NW * 16) + nj * 16 + r16;
          if (grow < M) {
            float v = acc[mi][nj][r] + bias[gcol];
            if (gcol < 320) off16[(i64)grow * 320 + gcol] = f2bf(v);
            else if (gcol < 480) att16[(i64)grow * 160 + (gcol - 320)] = f2bf(v);
            else if (gcol < 736) C16[(i64)grow * 256 + (gcol - 480)] = f2bf(v);
          }
        }
  } else {
    float bv[NW];
    int gc0 = n0 + wc * (NW * 16) + r16;
#pragma unroll
    for (int nj = 0; nj < NW; nj++)
      bv[nj] = bias ? bias[gc0 + nj * 16] : 0.f;
    int mask = (1 << mbsh) - 1;
#pragma unroll
    for (int mi = 0; mi < 4; mi++) {
#pragma unroll
      for (int r = 0; r < 4; r++) {
        int grow = m0 + wr * 64 + mi * 16 + g * 4 + r;
        if (grow >= M) continue;
        i64 rowb = (i64)(grow >> mbsh) * bCz + (i64)(grow & mask) * sCm;
#pragma unroll
        for (int nj = 0; nj < NW; nj++) {
          int gcol = gc0 + nj * 16;
          if (gcol >= N) continue;
          float v = acc[mi][nj][r] + bv[nj];
          if (relu) v = fmaxf(v, 0.f);
          i64 ci = rowb + gcol;
          if (C16) C16[ci] = f2bf(v);
          else {
            if (addres) v += C[ci];
            C[ci] = v;
          }
        }
      }
    }
  }
}

// ---------------- fused LN2+FFN v3 (known-good) ----------------------------
__global__ __launch_bounds__(512, 1) void ffn_fused_k(
    float* __restrict__ feats, const u16* __restrict__ w1n,
    const u16* __restrict__ w2n, const float* __restrict__ b1,
    const float* __restrict__ b2, const float* __restrict__ lng,
    const float* __restrict__ lnb, int M)
{
  __shared__ u16 B1s[2][64 * 256];
  __shared__ u16 B2s[2][256 * 64];
  __shared__ u16 Hs[64 * 88];
  __shared__ float b1s[1024];
  u16* As = &B1s[1][0];

  int tid = threadIdx.x;
  int lane = tid & 63, w = tid >> 6;
  int wr = w >> 1, wc = w & 1;
  int r16 = lane & 15, g = lane >> 4;
  int m0 = blockIdx.x * 64;

  auto stageW = [&](int buf, int ch) {
#pragma unroll
    for (int r = 0; r < 4; r++) {
      int s = r * 512 + tid;
      int row = s >> 5, c = s & 31;
      int cs = ((c ^ (row & 7)) << 3);
      __builtin_amdgcn_global_load_lds(
          (const __attribute__((address_space(1))) void*)(w1n + (i64)(ch * 64 + row) * 256 + cs),
          (__attribute__((address_space(3))) void*)(&B1s[buf][(r * 512 + (w << 6)) << 3]),
          16, 0, 0);
    }
#pragma unroll
    for (int r = 0; r < 4; r++) {
      int s = r * 512 + tid;
      int row = s >> 3, c = s & 7;
      int cs = ((c ^ (row & 7)) << 3);
      __builtin_amdgcn_global_load_lds(
          (const __attribute__((address_space(1))) void*)(w2n + (i64)row * 1024 + ch * 64 + cs),
          (__attribute__((address_space(3))) void*)(&B2s[buf][(r * 512 + (w << 6)) << 3]),
          16, 0, 0);
    }
  };

  stageW(0, 0);
  for (int i = tid; i < 1024; i += 512) b1s[i] = b1[i];

  // LN2 on rows m0..m0+63: 8 lanes per row, 32 cols each
  {
    int rw = tid >> 3, c0 = (tid & 7) * 32;
    const float* fr = feats + (i64)(m0 + rw) * 256 + c0;
    float4 x[8];
    float s = 0.f, ss = 0.f;
#pragma unroll
    for (int j = 0; j < 8; j++) {
      x[j] = ((const float4*)fr)[j];
      s += x[j].x + x[j].y + x[j].z + x[j].w;
      ss += x[j].x * x[j].x + x[j].y * x[j].y + x[j].z * x[j].z + x[j].w * x[j].w;
    }
#pragma unroll
    for (int o = 1; o <= 4; o <<= 1) { s += __shfl_xor(s, o); ss += __shfl_xor(ss, o); }
    float mean = s * (1.f / 256.f);
    float rs = rsqrtf(ss * (1.f / 256.f) - mean * mean + 1e-5f);
    const float4* gp = (const float4*)(lng + c0);
    const float4* bp = (const float4*)(lnb + c0);
#pragma unroll
    for (int j = 0; j < 8; j += 2) {
      float4 g0 = gp[j], g1 = gp[j + 1];
      float4 b0 = bp[j], b1_ = bp[j + 1];
      us8 o;
      o[0] = f2bf((x[j].x - mean) * rs * g0.x + b0.x);
      o[1] = f2bf((x[j].y - mean) * rs * g0.y + b0.y);
      o[2] = f2bf((x[j].z - mean) * rs * g0.z + b0.z);
      o[3] = f2bf((x[j].w - mean) * rs * g0.w + b0.w);
      o[4] = f2bf((x[j + 1].x - mean) * rs * g1.x + b1_.x);
      o[5] = f2bf((x[j + 1].y - mean) * rs * g1.y + b1_.y);
      o[6] = f2bf((x[j + 1].z - mean) * rs * g1.z + b1_.z);
      o[7] = f2bf((x[j + 1].w - mean) * rs * g1.w + b1_.w);
      int gr = (tid & 7) * 4 + (j >> 1);
      *(us8*)&As[rw * 256 + ((gr ^ (rw & 7)) << 3)] = o;
    }
  }
  __syncthreads();

  short8 av_all[8];
  {
    int row = wr * 16 + r16;
#pragma unroll
    for (int ks = 0; ks < 8; ks++)
      av_all[ks] = *(const short8*)&As[row * 256 + (((ks * 4 + g) ^ (row & 7)) << 3)];
  }
  __syncthreads();

  f32x4 acc2[8];
#pragma unroll
  for (int nj = 0; nj < 8; nj++) acc2[nj] = (f32x4){0.f, 0.f, 0.f, 0.f};

  int cur = 0;
  for (int ch = 0; ch < 16; ch++) {
    if (ch + 1 < 16) stageW(cur ^ 1, ch + 1);

    f32x4 acc1[2];
#pragma unroll
    for (int nj = 0; nj < 2; nj++) acc1[nj] = (f32x4){0.f, 0.f, 0.f, 0.f};
#pragma unroll
    for (int ks = 0; ks < 8; ks++) {
      short8 bv[2];
#pragma unroll
      for (int nj = 0; nj < 2; nj++) {
        int row = wc * 32 + nj * 16 + r16;
        bv[nj] = *(const short8*)&B1s[cur][row * 256 + (((ks * 4 + g) ^ (row & 7)) << 3)];
      }
#pragma unroll
      for (int nj = 0; nj < 2; nj++)
        acc1[nj] = __builtin_amdgcn_mfma_f32_16x16x32_bf16(
            av_all[ks], bv[nj], acc1[nj], 0, 0, 0);
    }
#pragma unroll
    for (int nj = 0; nj < 2; nj++)
#pragma unroll
      for (int r = 0; r < 4; r++) {
        int hr = wr * 16 + g * 4 + r;
        int hc = wc * 32 + nj * 16 + r16;
        float v = acc1[nj][r] + b1s[ch * 64 + hc];
        Hs[hr * 88 + hc] = f2bf(fmaxf(v, 0.f));
      }
    __syncthreads();

#pragma unroll
    for (int hh = 0; hh < 2; hh++) {
      short8 av2 = *(const short8*)&Hs[(wr * 16 + r16) * 88 + hh * 32 + g * 8];
      short8 bv2[8];
#pragma unroll
      for (int nj = 0; nj < 8; nj++) {
        int n = wc * 128 + nj * 16 + r16;
        bv2[nj] = *(const short8*)&B2s[cur][n * 64 + (((hh * 4 + g) ^ (n & 7)) << 3)];
      }
#pragma unroll
      for (int nj = 0; nj < 8; nj++)
        acc2[nj] = __builtin_amdgcn_mfma_f32_16x16x32_bf16(
            av2, bv2[nj], acc2[nj], 0, 0, 0);
    }
    __syncthreads();
    cur ^= 1;
  }

#pragma unroll
  for (int r = 0; r < 4; r++) {
    int grow = m0 + wr * 16 + g * 4 + r;
    if (grow >= M) continue;
#pragma unroll
    for (int nj = 0; nj < 8; nj++) {
      int col = wc * 128 + nj * 16 + r16;
      i64 ci = (i64)grow * 256 + col;
      feats[ci] += acc2[nj][r] + b2[col];
    }
  }
}

// reduce split-K fp32 partials (stride N); row map via shift/mask
__global__ void reduce_k(const float* __restrict__ part, float* __restrict__ C,
    const float* __restrict__ bias, int mbsh, i64 bCz, i64 sCm, int M, int N, int KS)
{
  int idx = blockIdx.x * 256 + threadIdx.x;
  if (idx >= M * N) return;
  int m = idx / N, n = idx - m * N;
  float v = bias ? bias[n] : 0.f;
  for (int ks = 0; ks < KS; ks++) v += part[((i64)ks * M + m) * N + n];
  C[(i64)(m >> mbsh) * bCz + (i64)(m & ((1 << mbsh) - 1)) * sCm + n] = v;
}

// ---------------- prologue weight conversion (linear, coalesced) -----------
__global__ void cvt_pro_k(const float* __restrict__ pw0, const float* __restrict__ pw1,
    const float* __restrict__ pw2, const float* __restrict__ buw0,
    const float* __restrict__ buw1, u16* __restrict__ dst)
{
  int idx = blockIdx.x * 256 + threadIdx.x;
  if (idx >= 6225920) return;
  float v;
  if (idx < 131072) v = pw0[idx];
  else if (idx < 393216) v = pw1[idx - 131072];
  else if (idx < 917504) v = pw2[idx - 393216];
  else if (idx < 5636096) v = buw0[idx - 917504];
  else v = buw1[idx - 5636096];
  dst[idx] = f2bf(v);
}

// generic tiled transpose-convert for layer weights
__global__ __launch_bounds__(256) void trans_w_k(const float* __restrict__ src,
    u16* __restrict__ dst, i64 srcLS, i64 dstLS, int srcStride, int dstStride)
{
  __shared__ float tile[32][33];
  int n0 = blockIdx.x * 32, k0 = blockIdx.y * 32, L = blockIdx.z;
  const float* s = src + (i64)L * srcLS;
  u16* d = dst + (i64)L * dstLS;
  int tx = threadIdx.x & 31, ty = threadIdx.x >> 5;
  for (int i = ty; i < 32; i += 8)
    tile[i][tx] = s[(i64)(k0 + i) * srcStride + n0 + tx];
  __syncthreads();
  for (int i = ty; i < 32; i += 8)
    d[(i64)(n0 + i) * dstStride + k0 + tx] = f2bf(tile[tx][i]);
}

// zero qkv pad rows [736,768) per layer + combined qkv bias
__global__ void fill_bias_k(u16* __restrict__ wb6, float* __restrict__ bq,
    const float* __restrict__ boff, const float* __restrict__ batt,
    const float* __restrict__ bval)
{
  int idx = blockIdx.x * 256 + threadIdx.x;
  if (idx < 49152) {
    int L = idx >> 13, o = idx & 8191;
    wb6[(i64)L * 786432 + 736 * 256 + o] = 0;
  }
  if (idx < NLAYERS * 768) {
    int L = idx / 768, n = idx - L * 768;
    float v;
    if (n < 320) v = boff[(i64)L * 320 + n];
    else if (n < 480) v = batt[(i64)L * 160 + (n - 320)];
    else if (n < 736) v = bval[(i64)L * 256 + (n - 480)];
    else v = 0.f;
    bq[idx] = v;
  }
}

// tiled transpose-convert: in [2][K][P] f32 -> out [2*P][K] bf16
__global__ __launch_bounds__(256) void trans_cvt_k(const float* __restrict__ in,
    u16* __restrict__ out, int K, int P)
{
  __shared__ float tile[32][33];
  int p0 = blockIdx.x * 32, k0 = blockIdx.y * 32, b = blockIdx.z;
  int tx = threadIdx.x & 31, ty = threadIdx.x >> 5;
  const float* ib = in + (i64)b * K * P;
  for (int i = ty; i < 32; i += 8)
    tile[i][tx] = ib[(i64)(k0 + i) * P + p0 + tx];
  __syncthreads();
  for (int i = ty; i < 32; i += 8)
    out[((i64)b * P + p0 + i) * K + k0 + tx] = f2bf(tile[tx][i]);
}

__global__ void im2col_bf16_k(const float* __restrict__ in, u16* __restrict__ out,
    int Cin, int Hin, int Win, int Ho, int Wo)
{
  int Kk = Cin * 9;
  i64 total = (i64)2 * Ho * Wo * Kk;
  i64 o = (i64)blockIdx.x * 256 + threadIdx.x;
  if (o >= total) return;
  int k = (int)(o % Kk);
  int m = (int)(o / Kk);
  int hw = Ho * Wo;
  int b = m / hw, pix = m - b * hw;
  int oy = pix / Wo, ox = pix - oy * Wo;
  int ci = k / 9, r = k - ci * 9;
  int ky = r / 3, kx = r - ky * 3;
  int iy = oy * 2 - 1 + ky, ix = ox * 2 - 1 + kx;
  float v = 0.f;
  if (iy >= 0 && iy < Hin && ix >= 0 && ix < Win)
    v = in[(((i64)b * Cin + ci) * Hin + iy) * Win + ix];
  out[o] = f2bf(v);
}

__global__ void gn_relu_k(const float* __restrict__ feats, float* __restrict__ y,
    const float* __restrict__ g, const float* __restrict__ bt)
{
  int grp = blockIdx.x, b = blockIdx.y;
  int tid = threadIdx.x;
  const float* fb = feats + ((i64)b * NTOK + 5376) * 256 + grp * 32;
  float s = 0.f, ss = 0.f;
  for (int i = tid; i < 2048; i += 256) {
    int cl = i >> 6, p = i & 63;
    float v = fb[(i64)p * 256 + cl];
    s += v; ss += v * v;
  }
  __shared__ float sb[4], ssb[4];
#pragma unroll
  for (int o = 32; o > 0; o >>= 1) { s += __shfl_down(s, o); ss += __shfl_down(ss, o); }
  int wv = tid >> 6;
  if ((tid & 63) == 0) { sb[wv] = s; ssb[wv] = ss; }
  __syncthreads();
  float ts = sb[0] + sb[1] + sb[2] + sb[3];
  float tss = ssb[0] + ssb[1] + ssb[2] + ssb[3];
  float mean = ts * (1.f / 2048.f);
  float rs = rsqrtf(tss * (1.f / 2048.f) - mean * mean + 1e-5f);
  for (int i = tid; i < 2048; i += 256) {
    int cl = i >> 6, p = i & 63;
    int c = grp * 32 + cl;
    float v = (fb[(i64)p * 256 + cl] - mean) * rs * g[c] + bt[c];
    y[((i64)b * 256 + c) * 64 + p] = fmaxf(v, 0.f);
  }
}

__global__ __launch_bounds__(256) void ln_k(const float* __restrict__ x,
    u16* __restrict__ y, const float* __restrict__ g, const float* __restrict__ bt,
    int rows)
{
  int row = blockIdx.x * 4 + (threadIdx.x >> 6);
  if (row >= rows) return;
  int lane = threadIdx.x & 63;
  float4 v = ((const float4*)(x + (i64)row * 256))[lane];
  float s = v.x + v.y + v.z + v.w;
  float ss = v.x * v.x + v.y * v.y + v.z * v.z + v.w * v.w;
#pragma unroll
  for (int o = 32; o > 0; o >>= 1) { s += __shfl_down(s, o); ss += __shfl_down(ss, o); }
  s = __shfl(s, 0);
  ss = __shfl(ss, 0);
  float mean = s * (1.f / 256.f);
  float rs = rsqrtf(ss * (1.f / 256.f) - mean * mean + 1e-5f);
  float4 gg = ((const float4*)g)[lane];
  float4 bb = ((const float4*)bt)[lane];
  ushort4 o4;
  o4.x = f2bf((v.x - mean) * rs * gg.x + bb.x);
  o4.y = f2bf((v.y - mean) * rs * gg.y + bb.y);
  o4.z = f2bf((v.z - mean) * rs * gg.z + bb.z);
  o4.w = f2bf((v.w - mean) * rs * gg.w + bb.w);
  ((ushort4*)(y + (i64)row * 256))[lane] = o4;
}

// deformable sampling v5 (known-good)
__global__ __launch_bounds__(256) void dsample_k(
    const u16* __restrict__ val, const u16* __restrict__ off,
    const u16* __restrict__ att, u16* __restrict__ out)
{
  const int FH[5] = {64, 32, 16, 8, 4};
  const int ST[5] = {0, 4096, 5120, 5376, 5440};
  int bid = blockIdx.x;
  int chunk = (bid & 7) * 86 + (bid >> 3);
  if (chunk >= 682) return;
  int lane = threadIdx.x & 63;
  int half = lane >> 5;
  int l32 = lane & 31;
  int t = chunk * 8 + ((threadIdx.x >> 6) << 1) + half;
  int b = blockIdx.y;
  int h = l32 >> 2, d4 = l32 & 3;

  int lv;
  if (t < 4096)      lv = 0;
  else if (t < 5120) lv = 1;
  else if (t < 5376) lv = 2;
  else if (t < 5440) lv = 3;
  else               lv = 4;
  int loc = t - ST[lv];
  int sh = 6 - lv;
  int py = loc >> sh, px = loc - (py << sh);
  float inv = 1.f / (float)FH[lv];
  float prx = (px + 0.5f) * inv, pry = (py + 0.5f) * inv;
  i64 bt = (i64)b * NTOK + t;
  const u16* offp = off + bt * 320 + h * 40;
  const u16* attp = att + bt * 160 + h * 20;
  const u16* vbase = val + ((i64)b * NTOK) * 256 + h * 32 + d4 * 8;

  float own_a[5], own_fx[5], own_fy[5];
  int own_pk[5];
  float mx = -1e30f;
#pragma unroll
  for (int j = 0; j < 5; j++) {
    float lg = bf2f(attp[d4 + 4 * j]);
    own_a[j] = lg;
    mx = fmaxf(mx, lg);
  }
  mx = fmaxf(mx, __shfl_xor(mx, 1));
  mx = fmaxf(mx, __shfl_xor(mx, 2));
  float sum = 0.f;
#pragma unroll
  for (int j = 0; j < 5; j++) {
    float e = __expf(own_a[j] - mx);
    own_a[j] = e;
    sum += e;
  }
  sum += __shfl_xor(sum, 1);
  sum += __shfl_xor(sum, 2);
  float rinv = 1.f / sum;
#pragma unroll
  for (int j = 0; j < 5; j++) {
    int p = d4 + 4 * j;
    own_a[j] *= rinv;
    unsigned opk = *(const unsigned*)(offp + 2 * p);
    float ox = bf2f((u16)(opk & 0xFFFF));
    float oy = bf2f((u16)(opk >> 16));
    float sff = (float)(64 >> j);
    float xx = prx * sff + ox - 0.5f;
    float yy = pry * sff + oy - 0.5f;
    float xf = floorf(xx), yf = floorf(yy);
    own_fx[j] = xx - xf;
    own_fy[j] = yy - yf;
    own_pk[j] = (((int)yf) << 16) | (((int)xf) & 0xFFFF);
  }

  float acc[8] = {0.f, 0.f, 0.f, 0.f, 0.f, 0.f, 0.f, 0.f};
#pragma unroll
  for (int p = 0; p < 20; p++) {
    const int j = p >> 2;
    const int sf = FH[j], st = ST[j];
    int src = (half << 5) | (h << 2) | (p & 3);
    float wa = __shfl(own_a[j], src);
    float fx = __shfl(own_fx[j], src);
    float fy = __shfl(own_fy[j], src);
    int pk = __shfl(own_pk[j], src);
    int x0 = (pk << 16) >> 16;
    int y0 = pk >> 16;
    float gx0 = wa - wa * fx, gx1 = wa * fx;
    float w00 = gx0 - gx0 * fy, w01 = gx0 * fy;
    float w10 = gx1 - gx1 * fy, w11 = gx1 * fy;
    bool xin0 = (x0 >= 0) & (x0 < sf), xin1 = (x0 + 1 >= 0) & (x0 + 1 < sf);
    bool yin0 = (y0 >= 0) & (y0 < sf), yin1 = (y0 + 1 >= 0) & (y0 + 1 < sf);
    int ibase = st + y0 * sf + x0;
#define FMA8(W, IDX) { \
      us8 v = *(const us8*)(vbase + (i64)(IDX) * 256); \
      acc[0] = fmaf(W, bf2f(v[0]), acc[0]); acc[1] = fmaf(W, bf2f(v[1]), acc[1]); \
      acc[2] = fmaf(W, bf2f(v[2]), acc[2]); acc[3] = fmaf(W, bf2f(v[3]), acc[3]); \
      acc[4] = fmaf(W, bf2f(v[4]), acc[4]); acc[5] = fmaf(W, bf2f(v[5]), acc[5]); \
      acc[6] = fmaf(W, bf2f(v[6]), acc[6]); acc[7] = fmaf(W, bf2f(v[7]), acc[7]); }
    if (xin0 & yin0) FMA8(w00, ibase);
    if (xin1 & yin0) FMA8(w10, ibase + 1);
    if (xin0 & yin1) FMA8(w01, ibase + sf);
    if (xin1 & yin1) FMA8(w11, ibase + sf + 1);
#undef FMA8
  }
  us8 o;
#pragma unroll
  for (int i = 0; i < 8; i++) o[i] = f2bf(acc[i]);
  *(us8*)(out + ((bt * 8 + h) * 32 + d4 * 8)) = o;
}

// all 5 levels in one dispatch
__global__ __launch_bounds__(256) void untranspose_all_k(
    const float* __restrict__ feats, float* __restrict__ out)
{
  int u = blockIdx.x;
  int pt0, start, S; i64 ooff;
  if (u < 128)      { pt0 = u;       start = 0;    S = 4096; ooff = 0; }
  else if (u < 160) { pt0 = u - 128; start = 4096; S = 1024; ooff = 2097152; }
  else if (u < 168) { pt0 = u - 160; start = 5120; S = 256;  ooff = 2621440; }
  else if (u < 170) { pt0 = u - 168; start = 5376; S = 64;   ooff = 2752512; }
  else              { pt0 = 0;       start = 5440; S = 16;   ooff = 2785280; }
  __shared__ float tile[32][33];
  int pt = pt0 * 32, ct = blockIdx.y * 32, b = blockIdx.z;
  int tx = threadIdx.x & 31, ty = threadIdx.x >> 5;
  for (int i = ty; i < 32; i += 8) {
    int p = pt + i;
    tile[i][tx] = (p < S) ? feats[((i64)b * NTOK + start + p) * 256 + ct + tx] : 0.f;
  }
  __syncthreads();
  for (int i = ty; i < 32; i += 8) {
    int c = ct + i, p = pt + tx;
    if (p < S) out[ooff + ((i64)b * 256 + c) * S + p] = tile[tx][i];
  }
}

extern "C" void kernel_launch(void* const* d_in, const int* in_sizes, int n_in,
                              void* d_out, int out_size, void* d_ws, size_t ws_size,
                              hipStream_t stream)
{
  const float* in0  = (const float*)d_in[0];
  const float* in1  = (const float*)d_in[1];
  const float* in2  = (const float*)d_in[2];
  const float* pw0  = (const float*)d_in[3];
  const float* pb0  = (const float*)d_in[4];
  const float* pw1  = (const float*)d_in[5];
  const float* pb1  = (const float*)d_in[6];
  const float* pw2  = (const float*)d_in[7];
  const float* pb2  = (const float*)d_in[8];
  const float* buw0 = (const float*)d_in[9];
  const float* bub0 = (const float*)d_in[10];
  const float* gng  = (const float*)d_in[11];
  const float* gnb  = (const float*)d_in[12];
  const float* buw1 = (const float*)d_in[13];
  const float* bub1 = (const float*)d_in[14];
  const float* ln1g = (const float*)d_in[15];
  const float* ln1b = (const float*)d_in[16];
  const float* woff = (const float*)d_in[17];
  const float* boff = (const float*)d_in[18];
  const float* watt = (const float*)d_in[19];
  const float* batt = (const float*)d_in[20];
  const float* wval = (const float*)d_in[21];
  const float* bval = (const float*)d_in[22];
  const float* wout = (const float*)d_in[23];
  const float* bout = (const float*)d_in[24];
  const float* ln2g = (const float*)d_in[25];
  const float* ln2b = (const float*)d_in[26];
  const float* w1   = (const float*)d_in[27];
  const float* b1   = (const float*)d_in[28];
  const float* w2   = (const float*)d_in[29];
  const float* b2   = (const float*)d_in[30];
  float* out = (float*)d_out;

  const i64 TC = (i64)NTOK * 256;

  // ---- ws layout (f32 units) ----
  float* ws    = (float*)d_ws;
  float* feats = ws;                               // 2,793,472
  u16*   qb    = (u16*)(feats + 2793472);          // 11008x256 bf16
  u16*   valb  = qb + 2818048;
  u16*   sampb = valb + 2818048;
  float* U     = (float*)(sampb + 2818048);        // union region: 5,637,120 f32
  u16*   off16 = (u16*)U;                          // [10912][320] bf16
  u16*   att16 = off16 + 3491840;                  // [10912][160] bf16
  u16*   abuf  = (u16*)U;                          // prologue A
  float* part  = U + 2097152;                      // split-K partials
  u16*   wb    = (u16*)(U + 5637120);              // 10,944,512 bf16
  float* bqkv  = (float*)(wb + 10944512);          // 4,608 f32
  float* m4gn  = bqkv + 4608;                      // 32,768 f32

  auto mg64 = [&](dim3 grid, const u16* A, const u16* B, int K,
                  float* C, float* C2, u16* C16, i64 sCm, const float* bias,
                  int relu, int addres, int qkv, int M, int N, int mbsh, i64 bCz, int KS) {
    mgemm_k<64><<<grid, dim3(256), 0, stream>>>(A, B, K, C, C2, C16, sCm, bias,
        relu, addres, qkv, M, N, mbsh, bCz, KS, part);
  };

  // ---- weight conversion (coalesced) ----
  cvt_pro_k<<<dim3(24320), dim3(256), 0, stream>>>(pw0, pw1, pw2, buw0, buw1, wb);
  u16* wbL0 = wb + 6225920;
  trans_w_k<<<dim3(10, 8, NLAYERS), dim3(256), 0, stream>>>(
      woff, wbL0, 81920, 786432, 320, 256);
  trans_w_k<<<dim3(5, 8, NLAYERS), dim3(256), 0, stream>>>(
      watt, wbL0 + 320 * 256, 40960, 786432, 160, 256);
  trans_w_k<<<dim3(8, 8, NLAYERS), dim3(256), 0, stream>>>(
      wval, wbL0 + 480 * 256, 65536, 786432, 256, 256);
  trans_w_k<<<dim3(8, 8, NLAYERS), dim3(256), 0, stream>>>(
      wout, wbL0 + 196608, 65536, 786432, 256, 256);
  trans_w_k<<<dim3(32, 8, NLAYERS), dim3(256), 0, stream>>>(
      w1, wbL0 + 262144, 262144, 786432, 1024, 256);
  trans_w_k<<<dim3(8, 32, NLAYERS), dim3(256), 0, stream>>>(
      w2, wbL0 + 524288, 262144, 786432, 256, 1024);
  fill_bias_k<<<dim3(192), dim3(256), 0, stream>>>(wbL0, bqkv, boff, batt, bval);

  // ---- projections (tiled transpose-convert, coalesced) ----
  trans_cvt_k<<<dim3(128, 16, 2), dim3(256), 0, stream>>>(in0, abuf, 512, 4096);
  mg64(dim3(64, 4, 1), abuf, wb, 512, feats, nullptr, nullptr, 256, pb0, 0, 0, 0,
       8192, 256, 12, TC, 1);
  trans_cvt_k<<<dim3(32, 32, 2), dim3(256), 0, stream>>>(in1, abuf, 1024, 1024);
  mg64(dim3(16, 4, 1), abuf, wb + 131072, 1024, feats + (i64)4096 * 256, nullptr,
       nullptr, 256, pb1, 0, 0, 0, 2048, 256, 10, TC, 1);
  trans_cvt_k<<<dim3(8, 64, 2), dim3(256), 0, stream>>>(in2, abuf, 2048, 256);
  mg64(dim3(4, 4, 4), abuf, wb + 393216, 2048, nullptr, nullptr, nullptr, 256,
       nullptr, 0, 0, 0, 512, 256, 8, 0, 4);
  reduce_k<<<dim3(512), dim3(256), 0, stream>>>(part, feats + (i64)5120 * 256, pb2,
      8, TC, 256, 512, 256, 4);

  // ---- bottom-up conv0 ----
  im2col_bf16_k<<<dim3(9216), dim3(256), 0, stream>>>(in2, abuf, 2048, 16, 16, 8, 8);
  mg64(dim3(1, 4, 16), abuf, wb + 917504, 18432, nullptr, nullptr, nullptr, 256,
       nullptr, 0, 0, 0, 128, 256, 6, 0, 16);
  reduce_k<<<dim3(128), dim3(256), 0, stream>>>(part, feats + (i64)5376 * 256, bub0,
      6, TC, 256, 128, 256, 16);

  // ---- GN+ReLU, bottom-up conv1 ----
  gn_relu_k<<<dim3(8, 2), dim3(256), 0, stream>>>(feats, m4gn, gng, gnb);
  im2col_bf16_k<<<dim3(288), dim3(256), 0, stream>>>(m4gn, abuf, 256, 8, 8, 4, 4);
  mg64(dim3(1, 4, 4), abuf, wb + 5636096, 2304, nullptr, nullptr, nullptr, 256,
       nullptr, 0, 0, 0, 32, 256, 4, 0, 4);
  reduce_k<<<dim3(32), dim3(256), 0, stream>>>(part, feats + (i64)5440 * 256, bub1,
      4, TC, 256, 32, 256, 4);

  // ---- 6 transformer layers ----
  for (int i = 0; i < NLAYERS; i++) {
    const u16* wbL = wb + 6225920 + (i64)i * 786432;
    ln_k<<<dim3(2728), dim3(256), 0, stream>>>(feats, qb,
        ln1g + (i64)i * 256, ln1b + (i64)i * 256, BNROWS);
    mg64(dim3(86, 12, 1), qb, wbL, 256, (float*)off16, (float*)att16, valb, 0,
         bqkv + (i64)i * 768, 0, 0, 1, BNROWS, 768, 14, 0, 1);
    dsample_k<<<dim3(688, 2), dim3(256), 0, stream>>>(valb, off16, att16, sampb);
    mg64(dim3(86, 4, 1), sampb, wbL + 196608, 256, feats, nullptr, nullptr, 256,
         bout + (i64)i * 256, 0, 1, 0, BNROWS, 256, 14, 0, 1);
    ffn_fused_k<<<dim3(171), dim3(512), 0, stream>>>(feats, wbL + 262144,
        wbL + 524288, b1 + (i64)i * 1024, b2 + (i64)i * 256,
        ln2g + (i64)i * 256, ln2b + (i64)i * 256, BNROWS);
  }

  // ---- split into 5 level maps (one dispatch) ----
  untranspose_all_k<<<dim3(171, 8, 2), dim3(256), 0, stream>>>(feats, out);
  (void)in_sizes; (void)n_in; (void)out_size; (void)ws_size;
}

// Round 21
// 865.709 us; speedup vs baseline: 1.0370x; 1.0163x over previous
//
#include <hip/hip_runtime.h>
#include <cstdint>

typedef long long i64;
typedef unsigned short u16;
typedef __attribute__((ext_vector_type(8))) short short8;
typedef __attribute__((ext_vector_type(8))) unsigned short us8;
typedef __attribute__((ext_vector_type(4))) float f32x4;

#define NTOK 5456
#define BNROWS 10912
#define NLAYERS 6

__device__ __forceinline__ u16 f2bf(float f) {
  unsigned u = __float_as_uint(f);
  return (u16)((u + 0x7FFFu + ((u >> 16) & 1u)) >> 16);
}
__device__ __forceinline__ float bf2f(u16 h) {
  return __uint_as_float(((unsigned)h) << 16);
}

// ---------------- bf16 MFMA GEMM, 2-phase double-buffered ----------------
template<int BNT>
__global__ __launch_bounds__(256) void mgemm_k(
    const u16* __restrict__ A, const u16* __restrict__ B, int K,
    float* __restrict__ C, float* __restrict__ C2, u16* __restrict__ C16, i64 sCm,
    const float* __restrict__ bias, int relu, int addres, int qkv,
    int M, int N, int mbsh, i64 bCz,
    int KS, float* __restrict__ part)
{
  constexpr int NW = BNT / 32;
  __shared__ u16 Asm[2][128 * 64];
  __shared__ u16 Bsm[2][BNT * 64];
  int tid = threadIdx.x;

  int bx = blockIdx.x, by = blockIdx.y;
  int gx = gridDim.x, gy = gridDim.y;
  int nwg = gx * gy;
  if (KS == 1 && nwg >= 16) {
    int lin = bx + gx * by;
    int xcd = lin & 7, k = lin >> 3;
    int q = nwg >> 3, r = nwg & 7;
    int f = (xcd < r) ? (xcd * (q + 1) + k) : (r * (q + 1) + (xcd - r) * q + k);
    bx = f / gy;
    by = f - bx * gy;
  }
  int m0 = bx * 128, n0 = by * BNT;

  int ks = blockIdx.z;
  int Kc = K / KS;
  int k0 = ks * Kc;
  int lane = tid & 63, w = tid >> 6;
  int wr = w >> 1, wc = w & 1;
  int r16 = lane & 15, g = lane >> 4;

  f32x4 acc[4][NW];
#pragma unroll
  for (int mi = 0; mi < 4; mi++)
#pragma unroll
    for (int nj = 0; nj < NW; nj++) acc[mi][nj] = (f32x4){0.f, 0.f, 0.f, 0.f};

  const u16* Ag = A + (i64)m0 * K + k0;
  const u16* Bg = B + (i64)n0 * K + k0;
  int nt = Kc >> 6;

  auto stage = [&](int buf, int kt) {
#pragma unroll
    for (int r = 0; r < 4; r++) {
      int s = r * 256 + tid;
      int row = s >> 3, c = s & 7;
      int cs = ((c ^ (row & 7)) << 3);
      __builtin_amdgcn_global_load_lds(
          (const __attribute__((address_space(1))) void*)(Ag + (i64)row * K + kt + cs),
          (__attribute__((address_space(3))) void*)(&Asm[buf][(r * 256 + (w << 6)) << 3]),
          16, 0, 0);
    }
#pragma unroll
    for (int r = 0; r < NW; r++) {
      int s = r * 256 + tid;
      int row = s >> 3, c = s & 7;
      int cs = ((c ^ (row & 7)) << 3);
      __builtin_amdgcn_global_load_lds(
          (const __attribute__((address_space(1))) void*)(Bg + (i64)row * K + kt + cs),
          (__attribute__((address_space(3))) void*)(&Bsm[buf][(r * 256 + (w << 6)) << 3]),
          16, 0, 0);
    }
  };

  stage(0, 0);
  __syncthreads();
  for (int t = 0; t < nt; t++) {
    int cur = t & 1;
    if (t + 1 < nt) stage(cur ^ 1, (t + 1) << 6);
#pragma unroll
    for (int h = 0; h < 2; h++) {
      short8 av[4], bv[NW];
#pragma unroll
      for (int mi = 0; mi < 4; mi++) {
        int row = wr * 64 + mi * 16 + r16;
        av[mi] = *(const short8*)&Asm[cur][row * 64 + ((((h << 2) + g) ^ (row & 7)) << 3)];
      }
#pragma unroll
      for (int nj = 0; nj < NW; nj++) {
        int row = wc * (NW * 16) + nj * 16 + r16;
        bv[nj] = *(const short8*)&Bsm[cur][row * 64 + ((((h << 2) + g) ^ (row & 7)) << 3)];
      }
#pragma unroll
      for (int mi = 0; mi < 4; mi++)
#pragma unroll
        for (int nj = 0; nj < NW; nj++)
          acc[mi][nj] = __builtin_amdgcn_mfma_f32_16x16x32_bf16(
              av[mi], bv[nj], acc[mi][nj], 0, 0, 0);
    }
    __syncthreads();
  }

  if (KS > 1) {
#pragma unroll
    for (int mi = 0; mi < 4; mi++)
#pragma unroll
      for (int nj = 0; nj < NW; nj++)
#pragma unroll
        for (int r = 0; r < 4; r++) {
          int grow = m0 + wr * 64 + mi * 16 + g * 4 + r;
          int gcol = n0 + wc * (NW * 16) + nj * 16 + r16;
          if (grow < M) part[((i64)ks * M + grow) * N + gcol] = acc[mi][nj][r];
        }
  } else if (qkv) {
    u16* off16 = (u16*)C;
    u16* att16 = (u16*)C2;
#pragma unroll
    for (int mi = 0; mi < 4; mi++)
#pragma unroll
      for (int nj = 0; nj < NW; nj++)
#pragma unroll
        for (int r = 0; r < 4; r++) {
          int grow = m0 + wr * 64 + mi * 16 + g * 4 + r;
          int gcol = n0 + wc * (NW * 16) + nj * 16 + r16;
          if (grow < M) {
            float v = acc[mi][nj][r] + bias[gcol];
            if (gcol < 320) off16[(i64)grow * 320 + gcol] = f2bf(v);
            else if (gcol < 480) att16[(i64)grow * 160 + (gcol - 320)] = f2bf(v);
            else if (gcol < 736) C16[(i64)grow * 256 + (gcol - 480)] = f2bf(v);
          }
        }
  } else {
    float bv[NW];
    int gc0 = n0 + wc * (NW * 16) + r16;
#pragma unroll
    for (int nj = 0; nj < NW; nj++)
      bv[nj] = bias ? bias[gc0 + nj * 16] : 0.f;
    int mask = (1 << mbsh) - 1;
#pragma unroll
    for (int mi = 0; mi < 4; mi++) {
#pragma unroll
      for (int r = 0; r < 4; r++) {
        int grow = m0 + wr * 64 + mi * 16 + g * 4 + r;
        if (grow >= M) continue;
        i64 rowb = (i64)(grow >> mbsh) * bCz + (i64)(grow & mask) * sCm;
#pragma unroll
        for (int nj = 0; nj < NW; nj++) {
          int gcol = gc0 + nj * 16;
          if (gcol >= N) continue;
          float v = acc[mi][nj][r] + bv[nj];
          if (relu) v = fmaxf(v, 0.f);
          i64 ci = rowb + gcol;
          if (C16) C16[ci] = f2bf(v);
          else {
            if (addres) v += C[ci];
            C[ci] = v;
          }
        }
      }
    }
  }
}

// ---------------- fused LN2+FFN v3 (known-good) ----------------------------
__global__ __launch_bounds__(512, 1) void ffn_fused_k(
    float* __restrict__ feats, const u16* __restrict__ w1n,
    const u16* __restrict__ w2n, const float* __restrict__ b1,
    const float* __restrict__ b2, const float* __restrict__ lng,
    const float* __restrict__ lnb, int M)
{
  __shared__ u16 B1s[2][64 * 256];
  __shared__ u16 B2s[2][256 * 64];
  __shared__ u16 Hs[64 * 88];
  __shared__ float b1s[1024];
  u16* As = &B1s[1][0];

  int tid = threadIdx.x;
  int lane = tid & 63, w = tid >> 6;
  int wr = w >> 1, wc = w & 1;
  int r16 = lane & 15, g = lane >> 4;
  int m0 = blockIdx.x * 64;

  auto stageW = [&](int buf, int ch) {
#pragma unroll
    for (int r = 0; r < 4; r++) {
      int s = r * 512 + tid;
      int row = s >> 5, c = s & 31;
      int cs = ((c ^ (row & 7)) << 3);
      __builtin_amdgcn_global_load_lds(
          (const __attribute__((address_space(1))) void*)(w1n + (i64)(ch * 64 + row) * 256 + cs),
          (__attribute__((address_space(3))) void*)(&B1s[buf][(r * 512 + (w << 6)) << 3]),
          16, 0, 0);
    }
#pragma unroll
    for (int r = 0; r < 4; r++) {
      int s = r * 512 + tid;
      int row = s >> 3, c = s & 7;
      int cs = ((c ^ (row & 7)) << 3);
      __builtin_amdgcn_global_load_lds(
          (const __attribute__((address_space(1))) void*)(w2n + (i64)row * 1024 + ch * 64 + cs),
          (__attribute__((address_space(3))) void*)(&B2s[buf][(r * 512 + (w << 6)) << 3]),
          16, 0, 0);
    }
  };

  stageW(0, 0);
  for (int i = tid; i < 1024; i += 512) b1s[i] = b1[i];

  // LN2 on rows m0..m0+63: 8 lanes per row, 32 cols each
  {
    int rw = tid >> 3, c0 = (tid & 7) * 32;
    const float* fr = feats + (i64)(m0 + rw) * 256 + c0;
    float4 x[8];
    float s = 0.f, ss = 0.f;
#pragma unroll
    for (int j = 0; j < 8; j++) {
      x[j] = ((const float4*)fr)[j];
      s += x[j].x + x[j].y + x[j].z + x[j].w;
      ss += x[j].x * x[j].x + x[j].y * x[j].y + x[j].z * x[j].z + x[j].w * x[j].w;
    }
#pragma unroll
    for (int o = 1; o <= 4; o <<= 1) { s += __shfl_xor(s, o); ss += __shfl_xor(ss, o); }
    float mean = s * (1.f / 256.f);
    float rs = rsqrtf(ss * (1.f / 256.f) - mean * mean + 1e-5f);
    const float4* gp = (const float4*)(lng + c0);
    const float4* bp = (const float4*)(lnb + c0);
#pragma unroll
    for (int j = 0; j < 8; j += 2) {
      float4 g0 = gp[j], g1 = gp[j + 1];
      float4 b0 = bp[j], b1_ = bp[j + 1];
      us8 o;
      o[0] = f2bf((x[j].x - mean) * rs * g0.x + b0.x);
      o[1] = f2bf((x[j].y - mean) * rs * g0.y + b0.y);
      o[2] = f2bf((x[j].z - mean) * rs * g0.z + b0.z);
      o[3] = f2bf((x[j].w - mean) * rs * g0.w + b0.w);
      o[4] = f2bf((x[j + 1].x - mean) * rs * g1.x + b1_.x);
      o[5] = f2bf((x[j + 1].y - mean) * rs * g1.y + b1_.y);
      o[6] = f2bf((x[j + 1].z - mean) * rs * g1.z + b1_.z);
      o[7] = f2bf((x[j + 1].w - mean) * rs * g1.w + b1_.w);
      int gr = (tid & 7) * 4 + (j >> 1);
      *(us8*)&As[rw * 256 + ((gr ^ (rw & 7)) << 3)] = o;
    }
  }
  __syncthreads();

  short8 av_all[8];
  {
    int row = wr * 16 + r16;
#pragma unroll
    for (int ks = 0; ks < 8; ks++)
      av_all[ks] = *(const short8*)&As[row * 256 + (((ks * 4 + g) ^ (row & 7)) << 3)];
  }
  __syncthreads();

  f32x4 acc2[8];
#pragma unroll
  for (int nj = 0; nj < 8; nj++) acc2[nj] = (f32x4){0.f, 0.f, 0.f, 0.f};

  int cur = 0;
  for (int ch = 0; ch < 16; ch++) {
    if (ch + 1 < 16) stageW(cur ^ 1, ch + 1);

    f32x4 acc1[2];
#pragma unroll
    for (int nj = 0; nj < 2; nj++) acc1[nj] = (f32x4){0.f, 0.f, 0.f, 0.f};
#pragma unroll
    for (int ks = 0; ks < 8; ks++) {
      short8 bv[2];
#pragma unroll
      for (int nj = 0; nj < 2; nj++) {
        int row = wc * 32 + nj * 16 + r16;
        bv[nj] = *(const short8*)&B1s[cur][row * 256 + (((ks * 4 + g) ^ (row & 7)) << 3)];
      }
#pragma unroll
      for (int nj = 0; nj < 2; nj++)
        acc1[nj] = __builtin_amdgcn_mfma_f32_16x16x32_bf16(
            av_all[ks], bv[nj], acc1[nj], 0, 0, 0);
    }
#pragma unroll
    for (int nj = 0; nj < 2; nj++)
#pragma unroll
      for (int r = 0; r < 4; r++) {
        int hr = wr * 16 + g * 4 + r;
        int hc = wc * 32 + nj * 16 + r16;
        float v = acc1[nj][r] + b1s[ch * 64 + hc];
        Hs[hr * 88 + hc] = f2bf(fmaxf(v, 0.f));
      }
    __syncthreads();

#pragma unroll
    for (int hh = 0; hh < 2; hh++) {
      short8 av2 = *(const short8*)&Hs[(wr * 16 + r16) * 88 + hh * 32 + g * 8];
      short8 bv2[8];
#pragma unroll
      for (int nj = 0; nj < 8; nj++) {
        int n = wc * 128 + nj * 16 + r16;
        bv2[nj] = *(const short8*)&B2s[cur][n * 64 + (((hh * 4 + g) ^ (n & 7)) << 3)];
      }
#pragma unroll
      for (int nj = 0; nj < 8; nj++)
        acc2[nj] = __builtin_amdgcn_mfma_f32_16x16x32_bf16(
            av2, bv2[nj], acc2[nj], 0, 0, 0);
    }
    __syncthreads();
    cur ^= 1;
  }

#pragma unroll
  for (int r = 0; r < 4; r++) {
    int grow = m0 + wr * 16 + g * 4 + r;
    if (grow >= M) continue;
#pragma unroll
    for (int nj = 0; nj < 8; nj++) {
      int col = wc * 128 + nj * 16 + r16;
      i64 ci = (i64)grow * 256 + col;
      feats[ci] += acc2[nj][r] + b2[col];
    }
  }
}

// reduce split-K fp32 partials (stride N); row map via shift/mask
__global__ void reduce_k(const float* __restrict__ part, float* __restrict__ C,
    const float* __restrict__ bias, int mbsh, i64 bCz, i64 sCm, int M, int N, int KS)
{
  int idx = blockIdx.x * 256 + threadIdx.x;
  if (idx >= M * N) return;
  int m = idx / N, n = idx - m * N;
  float v = bias ? bias[n] : 0.f;
  for (int ks = 0; ks < KS; ks++) v += part[((i64)ks * M + m) * N + n];
  C[(i64)(m >> mbsh) * bCz + (i64)(m & ((1 << mbsh) - 1)) * sCm + n] = v;
}

// ---------------- prologue weight conversion (linear, coalesced) -----------
__global__ void cvt_pro_k(const float* __restrict__ pw0, const float* __restrict__ pw1,
    const float* __restrict__ pw2, const float* __restrict__ buw0,
    const float* __restrict__ buw1, u16* __restrict__ dst)
{
  int idx = blockIdx.x * 256 + threadIdx.x;
  if (idx >= 6225920) return;
  float v;
  if (idx < 131072) v = pw0[idx];
  else if (idx < 393216) v = pw1[idx - 131072];
  else if (idx < 917504) v = pw2[idx - 393216];
  else if (idx < 5636096) v = buw0[idx - 917504];
  else v = buw1[idx - 5636096];
  dst[idx] = f2bf(v);
}

// ---------------- all layer-weight transposes + bias fill in ONE dispatch --
// grid (761, 6): per layer L, blocks [0,760) are 32x32 transpose tiles over
// {woff 80, watt 40, wval 64, wout 64, w1 256, w2 256}; block 760 zeroes the
// qkv pad rows and fills the combined bias.
__global__ __launch_bounds__(256) void cvt_layer_all_k(
    const float* __restrict__ woff, const float* __restrict__ watt,
    const float* __restrict__ wval, const float* __restrict__ wout,
    const float* __restrict__ w1, const float* __restrict__ w2,
    const float* __restrict__ boff, const float* __restrict__ batt,
    const float* __restrict__ bval,
    u16* __restrict__ wb6, float* __restrict__ bq)
{
  int t = blockIdx.x, L = blockIdx.y;
  u16* wbL = wb6 + (i64)L * 786432;

  if (t == 760) {
    // pad rows [736,768): 32*256 = 8192 u16
    for (int idx = threadIdx.x; idx < 8192; idx += 256)
      wbL[736 * 256 + idx] = 0;
    // combined qkv bias [768]
    for (int n = threadIdx.x; n < 768; n += 256) {
      float v;
      if (n < 320) v = boff[(i64)L * 320 + n];
      else if (n < 480) v = batt[(i64)L * 160 + (n - 320)];
      else if (n < 736) v = bval[(i64)L * 256 + (n - 480)];
      else v = 0.f;
      bq[(i64)L * 768 + n] = v;
    }
    return;
  }

  const float* src;
  u16* dst;
  int srcStride, dstStride, gxn, ti;
  if (t < 80)       { ti = t;       src = woff + (i64)L * 81920;  dst = wbL;            srcStride = 320;  dstStride = 256;  gxn = 10; }
  else if (t < 120) { ti = t - 80;  src = watt + (i64)L * 40960;  dst = wbL + 320 * 256; srcStride = 160;  dstStride = 256;  gxn = 5;  }
  else if (t < 184) { ti = t - 120; src = wval + (i64)L * 65536;  dst = wbL + 480 * 256; srcStride = 256;  dstStride = 256;  gxn = 8;  }
  else if (t < 248) { ti = t - 184; src = wout + (i64)L * 65536;  dst = wbL + 196608;   srcStride = 256;  dstStride = 256;  gxn = 8;  }
  else if (t < 504) { ti = t - 248; src = w1 + (i64)L * 262144;   dst = wbL + 262144;   srcStride = 1024; dstStride = 256;  gxn = 32; }
  else              { ti = t - 504; src = w2 + (i64)L * 262144;   dst = wbL + 524288;   srcStride = 256;  dstStride = 1024; gxn = 8;  }
  int n0 = (ti % gxn) * 32, k0 = (ti / gxn) * 32;

  __shared__ float tile[32][33];
  int tx = threadIdx.x & 31, ty = threadIdx.x >> 5;
  for (int i = ty; i < 32; i += 8)
    tile[i][tx] = src[(i64)(k0 + i) * srcStride + n0 + tx];
  __syncthreads();
  for (int i = ty; i < 32; i += 8)
    dst[(i64)(n0 + i) * dstStride + k0 + tx] = f2bf(tile[tx][i]);
}

// tiled transpose-convert: in [2][K][P] f32 -> out [2*P][K] bf16
__global__ __launch_bounds__(256) void trans_cvt_k(const float* __restrict__ in,
    u16* __restrict__ out, int K, int P)
{
  __shared__ float tile[32][33];
  int p0 = blockIdx.x * 32, k0 = blockIdx.y * 32, b = blockIdx.z;
  int tx = threadIdx.x & 31, ty = threadIdx.x >> 5;
  const float* ib = in + (i64)b * K * P;
  for (int i = ty; i < 32; i += 8)
    tile[i][tx] = ib[(i64)(k0 + i) * P + p0 + tx];
  __syncthreads();
  for (int i = ty; i < 32; i += 8)
    out[((i64)b * P + p0 + i) * K + k0 + tx] = f2bf(tile[tx][i]);
}

__global__ void im2col_bf16_k(const float* __restrict__ in, u16* __restrict__ out,
    int Cin, int Hin, int Win, int Ho, int Wo)
{
  int Kk = Cin * 9;
  i64 total = (i64)2 * Ho * Wo * Kk;
  i64 o = (i64)blockIdx.x * 256 + threadIdx.x;
  if (o >= total) return;
  int k = (int)(o % Kk);
  int m = (int)(o / Kk);
  int hw = Ho * Wo;
  int b = m / hw, pix = m - b * hw;
  int oy = pix / Wo, ox = pix - oy * Wo;
  int ci = k / 9, r = k - ci * 9;
  int ky = r / 3, kx = r - ky * 3;
  int iy = oy * 2 - 1 + ky, ix = ox * 2 - 1 + kx;
  float v = 0.f;
  if (iy >= 0 && iy < Hin && ix >= 0 && ix < Win)
    v = in[(((i64)b * Cin + ci) * Hin + iy) * Win + ix];
  out[o] = f2bf(v);
}

__global__ void gn_relu_k(const float* __restrict__ feats, float* __restrict__ y,
    const float* __restrict__ g, const float* __restrict__ bt)
{
  int grp = blockIdx.x, b = blockIdx.y;
  int tid = threadIdx.x;
  const float* fb = feats + ((i64)b * NTOK + 5376) * 256 + grp * 32;
  float s = 0.f, ss = 0.f;
  for (int i = tid; i < 2048; i += 256) {
    int cl = i >> 6, p = i & 63;
    float v = fb[(i64)p * 256 + cl];
    s += v; ss += v * v;
  }
  __shared__ float sb[4], ssb[4];
#pragma unroll
  for (int o = 32; o > 0; o >>= 1) { s += __shfl_down(s, o); ss += __shfl_down(ss, o); }
  int wv = tid >> 6;
  if ((tid & 63) == 0) { sb[wv] = s; ssb[wv] = ss; }
  __syncthreads();
  float ts = sb[0] + sb[1] + sb[2] + sb[3];
  float tss = ssb[0] + ssb[1] + ssb[2] + ssb[3];
  float mean = ts * (1.f / 2048.f);
  float rs = rsqrtf(tss * (1.f / 2048.f) - mean * mean + 1e-5f);
  for (int i = tid; i < 2048; i += 256) {
    int cl = i >> 6, p = i & 63;
    int c = grp * 32 + cl;
    float v = (fb[(i64)p * 256 + cl] - mean) * rs * g[c] + bt[c];
    y[((i64)b * 256 + c) * 64 + p] = fmaxf(v, 0.f);
  }
}

__global__ __launch_bounds__(256) void ln_k(const float* __restrict__ x,
    u16* __restrict__ y, const float* __restrict__ g, const float* __restrict__ bt,
    int rows)
{
  int row = blockIdx.x * 4 + (threadIdx.x >> 6);
  if (row >= rows) return;
  int lane = threadIdx.x & 63;
  float4 v = ((const float4*)(x + (i64)row * 256))[lane];
  float s = v.x + v.y + v.z + v.w;
  float ss = v.x * v.x + v.y * v.y + v.z * v.z + v.w * v.w;
#pragma unroll
  for (int o = 32; o > 0; o >>= 1) { s += __shfl_down(s, o); ss += __shfl_down(ss, o); }
  s = __shfl(s, 0);
  ss = __shfl(ss, 0);
  float mean = s * (1.f / 256.f);
  float rs = rsqrtf(ss * (1.f / 256.f) - mean * mean + 1e-5f);
  float4 gg = ((const float4*)g)[lane];
  float4 bb = ((const float4*)bt)[lane];
  ushort4 o4;
  o4.x = f2bf((v.x - mean) * rs * gg.x + bb.x);
  o4.y = f2bf((v.y - mean) * rs * gg.y + bb.y);
  o4.z = f2bf((v.z - mean) * rs * gg.z + bb.z);
  o4.w = f2bf((v.w - mean) * rs * gg.w + bb.w);
  ((ushort4*)(y + (i64)row * 256))[lane] = o4;
}

// deformable sampling v5 (known-good)
__global__ __launch_bounds__(256) void dsample_k(
    const u16* __restrict__ val, const u16* __restrict__ off,
    const u16* __restrict__ att, u16* __restrict__ out)
{
  const int FH[5] = {64, 32, 16, 8, 4};
  const int ST[5] = {0, 4096, 5120, 5376, 5440};
  int bid = blockIdx.x;
  int chunk = (bid & 7) * 86 + (bid >> 3);
  if (chunk >= 682) return;
  int lane = threadIdx.x & 63;
  int half = lane >> 5;
  int l32 = lane & 31;
  int t = chunk * 8 + ((threadIdx.x >> 6) << 1) + half;
  int b = blockIdx.y;
  int h = l32 >> 2, d4 = l32 & 3;

  int lv;
  if (t < 4096)      lv = 0;
  else if (t < 5120) lv = 1;
  else if (t < 5376) lv = 2;
  else if (t < 5440) lv = 3;
  else               lv = 4;
  int loc = t - ST[lv];
  int sh = 6 - lv;
  int py = loc >> sh, px = loc - (py << sh);
  float inv = 1.f / (float)FH[lv];
  float prx = (px + 0.5f) * inv, pry = (py + 0.5f) * inv;
  i64 bt = (i64)b * NTOK + t;
  const u16* offp = off + bt * 320 + h * 40;
  const u16* attp = att + bt * 160 + h * 20;
  const u16* vbase = val + ((i64)b * NTOK) * 256 + h * 32 + d4 * 8;

  float own_a[5], own_fx[5], own_fy[5];
  int own_pk[5];
  float mx = -1e30f;
#pragma unroll
  for (int j = 0; j < 5; j++) {
    float lg = bf2f(attp[d4 + 4 * j]);
    own_a[j] = lg;
    mx = fmaxf(mx, lg);
  }
  mx = fmaxf(mx, __shfl_xor(mx, 1));
  mx = fmaxf(mx, __shfl_xor(mx, 2));
  float sum = 0.f;
#pragma unroll
  for (int j = 0; j < 5; j++) {
    float e = __expf(own_a[j] - mx);
    own_a[j] = e;
    sum += e;
  }
  sum += __shfl_xor(sum, 1);
  sum += __shfl_xor(sum, 2);
  float rinv = 1.f / sum;
#pragma unroll
  for (int j = 0; j < 5; j++) {
    int p = d4 + 4 * j;
    own_a[j] *= rinv;
    unsigned opk = *(const unsigned*)(offp + 2 * p);
    float ox = bf2f((u16)(opk & 0xFFFF));
    float oy = bf2f((u16)(opk >> 16));
    float sff = (float)(64 >> j);
    float xx = prx * sff + ox - 0.5f;
    float yy = pry * sff + oy - 0.5f;
    float xf = floorf(xx), yf = floorf(yy);
    own_fx[j] = xx - xf;
    own_fy[j] = yy - yf;
    own_pk[j] = (((int)yf) << 16) | (((int)xf) & 0xFFFF);
  }

  float acc[8] = {0.f, 0.f, 0.f, 0.f, 0.f, 0.f, 0.f, 0.f};
#pragma unroll
  for (int p = 0; p < 20; p++) {
    const int j = p >> 2;
    const int sf = FH[j], st = ST[j];
    int src = (half << 5) | (h << 2) | (p & 3);
    float wa = __shfl(own_a[j], src);
    float fx = __shfl(own_fx[j], src);
    float fy = __shfl(own_fy[j], src);
    int pk = __shfl(own_pk[j], src);
    int x0 = (pk << 16) >> 16;
    int y0 = pk >> 16;
    float gx0 = wa - wa * fx, gx1 = wa * fx;
    float w00 = gx0 - gx0 * fy, w01 = gx0 * fy;
    float w10 = gx1 - gx1 * fy, w11 = gx1 * fy;
    bool xin0 = (x0 >= 0) & (x0 < sf), xin1 = (x0 + 1 >= 0) & (x0 + 1 < sf);
    bool yin0 = (y0 >= 0) & (y0 < sf), yin1 = (y0 + 1 >= 0) & (y0 + 1 < sf);
    int ibase = st + y0 * sf + x0;
#define FMA8(W, IDX) { \
      us8 v = *(const us8*)(vbase + (i64)(IDX) * 256); \
      acc[0] = fmaf(W, bf2f(v[0]), acc[0]); acc[1] = fmaf(W, bf2f(v[1]), acc[1]); \
      acc[2] = fmaf(W, bf2f(v[2]), acc[2]); acc[3] = fmaf(W, bf2f(v[3]), acc[3]); \
      acc[4] = fmaf(W, bf2f(v[4]), acc[4]); acc[5] = fmaf(W, bf2f(v[5]), acc[5]); \
      acc[6] = fmaf(W, bf2f(v[6]), acc[6]); acc[7] = fmaf(W, bf2f(v[7]), acc[7]); }
    if (xin0 & yin0) FMA8(w00, ibase);
    if (xin1 & yin0) FMA8(w10, ibase + 1);
    if (xin0 & yin1) FMA8(w01, ibase + sf);
    if (xin1 & yin1) FMA8(w11, ibase + sf + 1);
#undef FMA8
  }
  us8 o;
#pragma unroll
  for (int i = 0; i < 8; i++) o[i] = f2bf(acc[i]);
  *(us8*)(out + ((bt * 8 + h) * 32 + d4 * 8)) = o;
}

// all 5 levels in one dispatch
__global__ __launch_bounds__(256) void untranspose_all_k(
    const float* __restrict__ feats, float* __restrict__ out)
{
  int u = blockIdx.x;
  int pt0, start, S; i64 ooff;
  if (u < 128)      { pt0 = u;       start = 0;    S = 4096; ooff = 0; }
  else if (u < 160) { pt0 = u - 128; start = 4096; S = 1024; ooff = 2097152; }
  else if (u < 168) { pt0 = u - 160; start = 5120; S = 256;  ooff = 2621440; }
  else if (u < 170) { pt0 = u - 168; start = 5376; S = 64;   ooff = 2752512; }
  else              { pt0 = 0;       start = 5440; S = 16;   ooff = 2785280; }
  __shared__ float tile[32][33];
  int pt = pt0 * 32, ct = blockIdx.y * 32, b = blockIdx.z;
  int tx = threadIdx.x & 31, ty = threadIdx.x >> 5;
  for (int i = ty; i < 32; i += 8) {
    int p = pt + i;
    tile[i][tx] = (p < S) ? feats[((i64)b * NTOK + start + p) * 256 + ct + tx] : 0.f;
  }
  __syncthreads();
  for (int i = ty; i < 32; i += 8) {
    int c = ct + i, p = pt + tx;
    if (p < S) out[ooff + ((i64)b * 256 + c) * S + p] = tile[tx][i];
  }
}

extern "C" void kernel_launch(void* const* d_in, const int* in_sizes, int n_in,
                              void* d_out, int out_size, void* d_ws, size_t ws_size,
                              hipStream_t stream)
{
  const float* in0  = (const float*)d_in[0];
  const float* in1  = (const float*)d_in[1];
  const float* in2  = (const float*)d_in[2];
  const float* pw0  = (const float*)d_in[3];
  const float* pb0  = (const float*)d_in[4];
  const float* pw1  = (const float*)d_in[5];
  const float* pb1  = (const float*)d_in[6];
  const float* pw2  = (const float*)d_in[7];
  const float* pb2  = (const float*)d_in[8];
  const float* buw0 = (const float*)d_in[9];
  const float* bub0 = (const float*)d_in[10];
  const float* gng  = (const float*)d_in[11];
  const float* gnb  = (const float*)d_in[12];
  const float* buw1 = (const float*)d_in[13];
  const float* bub1 = (const float*)d_in[14];
  const float* ln1g = (const float*)d_in[15];
  const float* ln1b = (const float*)d_in[16];
  const float* woff = (const float*)d_in[17];
  const float* boff = (const float*)d_in[18];
  const float* watt = (const float*)d_in[19];
  const float* batt = (const float*)d_in[20];
  const float* wval = (const float*)d_in[21];
  const float* bval = (const float*)d_in[22];
  const float* wout = (const float*)d_in[23];
  const float* bout = (const float*)d_in[24];
  const float* ln2g = (const float*)d_in[25];
  const float* ln2b = (const float*)d_in[26];
  const float* w1   = (const float*)d_in[27];
  const float* b1   = (const float*)d_in[28];
  const float* w2   = (const float*)d_in[29];
  const float* b2   = (const float*)d_in[30];
  float* out = (float*)d_out;

  const i64 TC = (i64)NTOK * 256;

  // ---- ws layout (f32 units) ----
  float* ws    = (float*)d_ws;
  float* feats = ws;                               // 2,793,472
  u16*   qb    = (u16*)(feats + 2793472);          // 11008x256 bf16
  u16*   valb  = qb + 2818048;
  u16*   sampb = valb + 2818048;
  float* U     = (float*)(sampb + 2818048);        // union region: 5,637,120 f32
  u16*   off16 = (u16*)U;                          // [10912][320] bf16
  u16*   att16 = off16 + 3491840;                  // [10912][160] bf16
  u16*   abuf  = (u16*)U;                          // prologue A
  float* part  = U + 2097152;                      // split-K partials
  u16*   wb    = (u16*)(U + 5637120);              // 10,944,512 bf16
  float* bqkv  = (float*)(wb + 10944512);          // 4,608 f32
  float* m4gn  = bqkv + 4608;                      // 32,768 f32

  auto mg64 = [&](dim3 grid, const u16* A, const u16* B, int K,
                  float* C, float* C2, u16* C16, i64 sCm, const float* bias,
                  int relu, int addres, int qkv, int M, int N, int mbsh, i64 bCz, int KS) {
    mgemm_k<64><<<grid, dim3(256), 0, stream>>>(A, B, K, C, C2, C16, sCm, bias,
        relu, addres, qkv, M, N, mbsh, bCz, KS, part);
  };

  // ---- weight conversion (2 dispatches) ----
  cvt_pro_k<<<dim3(24320), dim3(256), 0, stream>>>(pw0, pw1, pw2, buw0, buw1, wb);
  u16* wbL0 = wb + 6225920;
  cvt_layer_all_k<<<dim3(761, NLAYERS), dim3(256), 0, stream>>>(
      woff, watt, wval, wout, w1, w2, boff, batt, bval, wbL0, bqkv);

  // ---- projections (tiled transpose-convert, coalesced) ----
  trans_cvt_k<<<dim3(128, 16, 2), dim3(256), 0, stream>>>(in0, abuf, 512, 4096);
  mg64(dim3(64, 4, 1), abuf, wb, 512, feats, nullptr, nullptr, 256, pb0, 0, 0, 0,
       8192, 256, 12, TC, 1);
  trans_cvt_k<<<dim3(32, 32, 2), dim3(256), 0, stream>>>(in1, abuf, 1024, 1024);
  mg64(dim3(16, 4, 1), abuf, wb + 131072, 1024, feats + (i64)4096 * 256, nullptr,
       nullptr, 256, pb1, 0, 0, 0, 2048, 256, 10, TC, 1);
  trans_cvt_k<<<dim3(8, 64, 2), dim3(256), 0, stream>>>(in2, abuf, 2048, 256);
  mg64(dim3(4, 4, 4), abuf, wb + 393216, 2048, nullptr, nullptr, nullptr, 256,
       nullptr, 0, 0, 0, 512, 256, 8, 0, 4);
  reduce_k<<<dim3(512), dim3(256), 0, stream>>>(part, feats + (i64)5120 * 256, pb2,
      8, TC, 256, 512, 256, 4);

  // ---- bottom-up conv0 ----
  im2col_bf16_k<<<dim3(9216), dim3(256), 0, stream>>>(in2, abuf, 2048, 16, 16, 8, 8);
  mg64(dim3(1, 4, 16), abuf, wb + 917504, 18432, nullptr, nullptr, nullptr, 256,
       nullptr, 0, 0, 0, 128, 256, 6, 0, 16);
  reduce_k<<<dim3(128), dim3(256), 0, stream>>>(part, feats + (i64)5376 * 256, bub0,
      6, TC, 256, 128, 256, 16);

  // ---- GN+ReLU, bottom-up conv1 ----
  gn_relu_k<<<dim3(8, 2), dim3(256), 0, stream>>>(feats, m4gn, gng, gnb);
  im2col_bf16_k<<<dim3(288), dim3(256), 0, stream>>>(m4gn, abuf, 256, 8, 8, 4, 4);
  mg64(dim3(1, 4, 4), abuf, wb + 5636096, 2304, nullptr, nullptr, nullptr, 256,
       nullptr, 0, 0, 0, 32, 256, 4, 0, 4);
  reduce_k<<<dim3(32), dim3(256), 0, stream>>>(part, feats + (i64)5440 * 256, bub1,
      4, TC, 256, 32, 256, 4);

  // ---- 6 transformer layers ----
  for (int i = 0; i < NLAYERS; i++) {
    const u16* wbL = wb + 6225920 + (i64)i * 786432;
    ln_k<<<dim3(2728), dim3(256), 0, stream>>>(feats, qb,
        ln1g + (i64)i * 256, ln1b + (i64)i * 256, BNROWS);
    mg64(dim3(86, 12, 1), qb, wbL, 256, (float*)off16, (float*)att16, valb, 0,
         bqkv + (i64)i * 768, 0, 0, 1, BNROWS, 768, 14, 0, 1);
    dsample_k<<<dim3(688, 2), dim3(256), 0, stream>>>(valb, off16, att16, sampb);
    mg64(dim3(86, 4, 1), sampb, wbL + 196608, 256, feats, nullptr, nullptr, 256,
         bout + (i64)i * 256, 0, 1, 0, BNROWS, 256, 14, 0, 1);
    ffn_fused_k<<<dim3(171), dim3(512), 0, stream>>>(feats, wbL + 262144,
        wbL + 524288, b1 + (i64)i * 1024, b2 + (i64)i * 256,
        ln2g + (i64)i * 256, ln2b + (i64)i * 256, BNROWS);
  }

  // ---- split into 5 level maps (one dispatch) ----
  untranspose_all_k<<<dim3(171, 8, 2), dim3(256), 0, stream>>>(feats, out);
  (void)in_sizes; (void)n_in; (void)out_size; (void)ws_size;
}

// Round 22
// 858.312 us; speedup vs baseline: 1.0460x; 1.0086x over previous
//
#include <hip/hip_runtime.h>
#include <cstdint>

typedef long long i64;
typedef unsigned short u16;
typedef __attribute__((ext_vector_type(8))) short short8;
typedef __attribute__((ext_vector_type(8))) unsigned short us8;
typedef __attribute__((ext_vector_type(4))) float f32x4;

#define NTOK 5456
#define BNROWS 10912
#define NLAYERS 6

__device__ __forceinline__ u16 f2bf(float f) {
  unsigned u = __float_as_uint(f);
  return (u16)((u + 0x7FFFu + ((u >> 16) & 1u)) >> 16);
}
__device__ __forceinline__ float bf2f(u16 h) {
  return __uint_as_float(((unsigned)h) << 16);
}

// ---------------- bf16 MFMA GEMM, 2-phase double-buffered ----------------
template<int BNT>
__global__ __launch_bounds__(256) void mgemm_k(
    const u16* __restrict__ A, const u16* __restrict__ B, int K,
    float* __restrict__ C, float* __restrict__ C2, u16* __restrict__ C16, i64 sCm,
    const float* __restrict__ bias, int relu, int addres, int qkv,
    int M, int N, int mbsh, i64 bCz,
    int KS, float* __restrict__ part)
{
  constexpr int NW = BNT / 32;
  __shared__ u16 Asm[2][128 * 64];
  __shared__ u16 Bsm[2][BNT * 64];
  int tid = threadIdx.x;

  int bx = blockIdx.x, by = blockIdx.y;
  int gx = gridDim.x, gy = gridDim.y;
  int nwg = gx * gy;
  if (KS == 1 && nwg >= 16) {
    int lin = bx + gx * by;
    int xcd = lin & 7, k = lin >> 3;
    int q = nwg >> 3, r = nwg & 7;
    int f = (xcd < r) ? (xcd * (q + 1) + k) : (r * (q + 1) + (xcd - r) * q + k);
    bx = f / gy;
    by = f - bx * gy;
  }
  int m0 = bx * 128, n0 = by * BNT;

  int ks = blockIdx.z;
  int Kc = K / KS;
  int k0 = ks * Kc;
  int lane = tid & 63, w = tid >> 6;
  int wr = w >> 1, wc = w & 1;
  int r16 = lane & 15, g = lane >> 4;

  f32x4 acc[4][NW];
#pragma unroll
  for (int mi = 0; mi < 4; mi++)
#pragma unroll
    for (int nj = 0; nj < NW; nj++) acc[mi][nj] = (f32x4){0.f, 0.f, 0.f, 0.f};

  const u16* Ag = A + (i64)m0 * K + k0;
  const u16* Bg = B + (i64)n0 * K + k0;
  int nt = Kc >> 6;

  auto stage = [&](int buf, int kt) {
#pragma unroll
    for (int r = 0; r < 4; r++) {
      int s = r * 256 + tid;
      int row = s >> 3, c = s & 7;
      int cs = ((c ^ (row & 7)) << 3);
      __builtin_amdgcn_global_load_lds(
          (const __attribute__((address_space(1))) void*)(Ag + (i64)row * K + kt + cs),
          (__attribute__((address_space(3))) void*)(&Asm[buf][(r * 256 + (w << 6)) << 3]),
          16, 0, 0);
    }
#pragma unroll
    for (int r = 0; r < NW; r++) {
      int s = r * 256 + tid;
      int row = s >> 3, c = s & 7;
      int cs = ((c ^ (row & 7)) << 3);
      __builtin_amdgcn_global_load_lds(
          (const __attribute__((address_space(1))) void*)(Bg + (i64)row * K + kt + cs),
          (__attribute__((address_space(3))) void*)(&Bsm[buf][(r * 256 + (w << 6)) << 3]),
          16, 0, 0);
    }
  };

  stage(0, 0);
  __syncthreads();
  for (int t = 0; t < nt; t++) {
    int cur = t & 1;
    if (t + 1 < nt) stage(cur ^ 1, (t + 1) << 6);
#pragma unroll
    for (int h = 0; h < 2; h++) {
      short8 av[4], bv[NW];
#pragma unroll
      for (int mi = 0; mi < 4; mi++) {
        int row = wr * 64 + mi * 16 + r16;
        av[mi] = *(const short8*)&Asm[cur][row * 64 + ((((h << 2) + g) ^ (row & 7)) << 3)];
      }
#pragma unroll
      for (int nj = 0; nj < NW; nj++) {
        int row = wc * (NW * 16) + nj * 16 + r16;
        bv[nj] = *(const short8*)&Bsm[cur][row * 64 + ((((h << 2) + g) ^ (row & 7)) << 3)];
      }
#pragma unroll
      for (int mi = 0; mi < 4; mi++)
#pragma unroll
        for (int nj = 0; nj < NW; nj++)
          acc[mi][nj] = __builtin_amdgcn_mfma_f32_16x16x32_bf16(
              av[mi], bv[nj], acc[mi][nj], 0, 0, 0);
    }
    __syncthreads();
  }

  if (KS > 1) {
#pragma unroll
    for (int mi = 0; mi < 4; mi++)
#pragma unroll
      for (int nj = 0; nj < NW; nj++)
#pragma unroll
        for (int r = 0; r < 4; r++) {
          int grow = m0 + wr * 64 + mi * 16 + g * 4 + r;
          int gcol = n0 + wc * (NW * 16) + nj * 16 + r16;
          if (grow < M) part[((i64)ks * M + grow) * N + gcol] = acc[mi][nj][r];
        }
  } else if (qkv) {
    u16* off16 = (u16*)C;
    u16* att16 = (u16*)C2;
#pragma unroll
    for (int mi = 0; mi < 4; mi++)
#pragma unroll
      for (int nj = 0; nj < NW; nj++)
#pragma unroll
        for (int r = 0; r < 4; r++) {
          int grow = m0 + wr * 64 + mi * 16 + g * 4 + r;
          int gcol = n0 + wc * (NW * 16) + nj * 16 + r16;
          if (grow < M) {
            float v = acc[mi][nj][r] + bias[gcol];
            if (gcol < 320) off16[(i64)grow * 320 + gcol] = f2bf(v);
            else if (gcol < 480) att16[(i64)grow * 160 + (gcol - 320)] = f2bf(v);
            else if (gcol < 736) C16[(i64)grow * 256 + (gcol - 480)] = f2bf(v);
          }
        }
  } else {
    float bv[NW];
    int gc0 = n0 + wc * (NW * 16) + r16;
#pragma unroll
    for (int nj = 0; nj < NW; nj++)
      bv[nj] = bias ? bias[gc0 + nj * 16] : 0.f;
    int mask = (1 << mbsh) - 1;
#pragma unroll
    for (int mi = 0; mi < 4; mi++) {
#pragma unroll
      for (int r = 0; r < 4; r++) {
        int grow = m0 + wr * 64 + mi * 16 + g * 4 + r;
        if (grow >= M) continue;
        i64 rowb = (i64)(grow >> mbsh) * bCz + (i64)(grow & mask) * sCm;
#pragma unroll
        for (int nj = 0; nj < NW; nj++) {
          int gcol = gc0 + nj * 16;
          if (gcol >= N) continue;
          float v = acc[mi][nj][r] + bv[nj];
          if (relu) v = fmaxf(v, 0.f);
          i64 ci = rowb + gcol;
          if (C16) C16[ci] = f2bf(v);
          else {
            if (addres) v += C[ci];
            C[ci] = v;
          }
        }
      }
    }
  }
}

// ---------------- fused LN2+FFN v3 (known-good) ----------------------------
__global__ __launch_bounds__(512, 1) void ffn_fused_k(
    float* __restrict__ feats, const u16* __restrict__ w1n,
    const u16* __restrict__ w2n, const float* __restrict__ b1,
    const float* __restrict__ b2, const float* __restrict__ lng,
    const float* __restrict__ lnb, int M)
{
  __shared__ u16 B1s[2][64 * 256];
  __shared__ u16 B2s[2][256 * 64];
  __shared__ u16 Hs[64 * 88];
  __shared__ float b1s[1024];
  u16* As = &B1s[1][0];

  int tid = threadIdx.x;
  int lane = tid & 63, w = tid >> 6;
  int wr = w >> 1, wc = w & 1;
  int r16 = lane & 15, g = lane >> 4;
  int m0 = blockIdx.x * 64;

  auto stageW = [&](int buf, int ch) {
#pragma unroll
    for (int r = 0; r < 4; r++) {
      int s = r * 512 + tid;
      int row = s >> 5, c = s & 31;
      int cs = ((c ^ (row & 7)) << 3);
      __builtin_amdgcn_global_load_lds(
          (const __attribute__((address_space(1))) void*)(w1n + (i64)(ch * 64 + row) * 256 + cs),
          (__attribute__((address_space(3))) void*)(&B1s[buf][(r * 512 + (w << 6)) << 3]),
          16, 0, 0);
    }
#pragma unroll
    for (int r = 0; r < 4; r++) {
      int s = r * 512 + tid;
      int row = s >> 3, c = s & 7;
      int cs = ((c ^ (row & 7)) << 3);
      __builtin_amdgcn_global_load_lds(
          (const __attribute__((address_space(1))) void*)(w2n + (i64)row * 1024 + ch * 64 + cs),
          (__attribute__((address_space(3))) void*)(&B2s[buf][(r * 512 + (w << 6)) << 3]),
          16, 0, 0);
    }
  };

  stageW(0, 0);
  for (int i = tid; i < 1024; i += 512) b1s[i] = b1[i];

  // LN2 on rows m0..m0+63: 8 lanes per row, 32 cols each
  {
    int rw = tid >> 3, c0 = (tid & 7) * 32;
    const float* fr = feats + (i64)(m0 + rw) * 256 + c0;
    float4 x[8];
    float s = 0.f, ss = 0.f;
#pragma unroll
    for (int j = 0; j < 8; j++) {
      x[j] = ((const float4*)fr)[j];
      s += x[j].x + x[j].y + x[j].z + x[j].w;
      ss += x[j].x * x[j].x + x[j].y * x[j].y + x[j].z * x[j].z + x[j].w * x[j].w;
    }
#pragma unroll
    for (int o = 1; o <= 4; o <<= 1) { s += __shfl_xor(s, o); ss += __shfl_xor(ss, o); }
    float mean = s * (1.f / 256.f);
    float rs = rsqrtf(ss * (1.f / 256.f) - mean * mean + 1e-5f);
    const float4* gp = (const float4*)(lng + c0);
    const float4* bp = (const float4*)(lnb + c0);
#pragma unroll
    for (int j = 0; j < 8; j += 2) {
      float4 g0 = gp[j], g1 = gp[j + 1];
      float4 b0 = bp[j], b1_ = bp[j + 1];
      us8 o;
      o[0] = f2bf((x[j].x - mean) * rs * g0.x + b0.x);
      o[1] = f2bf((x[j].y - mean) * rs * g0.y + b0.y);
      o[2] = f2bf((x[j].z - mean) * rs * g0.z + b0.z);
      o[3] = f2bf((x[j].w - mean) * rs * g0.w + b0.w);
      o[4] = f2bf((x[j + 1].x - mean) * rs * g1.x + b1_.x);
      o[5] = f2bf((x[j + 1].y - mean) * rs * g1.y + b1_.y);
      o[6] = f2bf((x[j + 1].z - mean) * rs * g1.z + b1_.z);
      o[7] = f2bf((x[j + 1].w - mean) * rs * g1.w + b1_.w);
      int gr = (tid & 7) * 4 + (j >> 1);
      *(us8*)&As[rw * 256 + ((gr ^ (rw & 7)) << 3)] = o;
    }
  }
  __syncthreads();

  short8 av_all[8];
  {
    int row = wr * 16 + r16;
#pragma unroll
    for (int ks = 0; ks < 8; ks++)
      av_all[ks] = *(const short8*)&As[row * 256 + (((ks * 4 + g) ^ (row & 7)) << 3)];
  }
  __syncthreads();

  f32x4 acc2[8];
#pragma unroll
  for (int nj = 0; nj < 8; nj++) acc2[nj] = (f32x4){0.f, 0.f, 0.f, 0.f};

  int cur = 0;
  for (int ch = 0; ch < 16; ch++) {
    if (ch + 1 < 16) stageW(cur ^ 1, ch + 1);

    f32x4 acc1[2];
#pragma unroll
    for (int nj = 0; nj < 2; nj++) acc1[nj] = (f32x4){0.f, 0.f, 0.f, 0.f};
#pragma unroll
    for (int ks = 0; ks < 8; ks++) {
      short8 bv[2];
#pragma unroll
      for (int nj = 0; nj < 2; nj++) {
        int row = wc * 32 + nj * 16 + r16;
        bv[nj] = *(const short8*)&B1s[cur][row * 256 + (((ks * 4 + g) ^ (row & 7)) << 3)];
      }
#pragma unroll
      for (int nj = 0; nj < 2; nj++)
        acc1[nj] = __builtin_amdgcn_mfma_f32_16x16x32_bf16(
            av_all[ks], bv[nj], acc1[nj], 0, 0, 0);
    }
#pragma unroll
    for (int nj = 0; nj < 2; nj++)
#pragma unroll
      for (int r = 0; r < 4; r++) {
        int hr = wr * 16 + g * 4 + r;
        int hc = wc * 32 + nj * 16 + r16;
        float v = acc1[nj][r] + b1s[ch * 64 + hc];
        Hs[hr * 88 + hc] = f2bf(fmaxf(v, 0.f));
      }
    __syncthreads();

#pragma unroll
    for (int hh = 0; hh < 2; hh++) {
      short8 av2 = *(const short8*)&Hs[(wr * 16 + r16) * 88 + hh * 32 + g * 8];
      short8 bv2[8];
#pragma unroll
      for (int nj = 0; nj < 8; nj++) {
        int n = wc * 128 + nj * 16 + r16;
        bv2[nj] = *(const short8*)&B2s[cur][n * 64 + (((hh * 4 + g) ^ (n & 7)) << 3)];
      }
#pragma unroll
      for (int nj = 0; nj < 8; nj++)
        acc2[nj] = __builtin_amdgcn_mfma_f32_16x16x32_bf16(
            av2, bv2[nj], acc2[nj], 0, 0, 0);
    }
    __syncthreads();
    cur ^= 1;
  }

#pragma unroll
  for (int r = 0; r < 4; r++) {
    int grow = m0 + wr * 16 + g * 4 + r;
    if (grow >= M) continue;
#pragma unroll
    for (int nj = 0; nj < 8; nj++) {
      int col = wc * 128 + nj * 16 + r16;
      i64 ci = (i64)grow * 256 + col;
      feats[ci] += acc2[nj][r] + b2[col];
    }
  }
}

// reduce split-K fp32 partials (stride N); row map via shift/mask
__global__ void reduce_k(const float* __restrict__ part, float* __restrict__ C,
    const float* __restrict__ bias, int mbsh, i64 bCz, i64 sCm, int M, int N, int KS)
{
  int idx = blockIdx.x * 256 + threadIdx.x;
  if (idx >= M * N) return;
  int m = idx / N, n = idx - m * N;
  float v = bias ? bias[n] : 0.f;
  for (int ks = 0; ks < KS; ks++) v += part[((i64)ks * M + m) * N + n];
  C[(i64)(m >> mbsh) * bCz + (i64)(m & ((1 << mbsh) - 1)) * sCm + n] = v;
}

// ---------------- prologue weight conversion (linear, coalesced) -----------
__global__ void cvt_pro_k(const float* __restrict__ pw0, const float* __restrict__ pw1,
    const float* __restrict__ pw2, const float* __restrict__ buw0,
    const float* __restrict__ buw1, u16* __restrict__ dst)
{
  int idx = blockIdx.x * 256 + threadIdx.x;
  if (idx >= 6225920) return;
  float v;
  if (idx < 131072) v = pw0[idx];
  else if (idx < 393216) v = pw1[idx - 131072];
  else if (idx < 917504) v = pw2[idx - 393216];
  else if (idx < 5636096) v = buw0[idx - 917504];
  else v = buw1[idx - 5636096];
  dst[idx] = f2bf(v);
}

// ---------------- all layer-weight transposes + bias fill in ONE dispatch --
__global__ __launch_bounds__(256) void cvt_layer_all_k(
    const float* __restrict__ woff, const float* __restrict__ watt,
    const float* __restrict__ wval, const float* __restrict__ wout,
    const float* __restrict__ w1, const float* __restrict__ w2,
    const float* __restrict__ boff, const float* __restrict__ batt,
    const float* __restrict__ bval,
    u16* __restrict__ wb6, float* __restrict__ bq)
{
  int t = blockIdx.x, L = blockIdx.y;
  u16* wbL = wb6 + (i64)L * 786432;

  if (t == 760) {
    for (int idx = threadIdx.x; idx < 8192; idx += 256)
      wbL[736 * 256 + idx] = 0;
    for (int n = threadIdx.x; n < 768; n += 256) {
      float v;
      if (n < 320) v = boff[(i64)L * 320 + n];
      else if (n < 480) v = batt[(i64)L * 160 + (n - 320)];
      else if (n < 736) v = bval[(i64)L * 256 + (n - 480)];
      else v = 0.f;
      bq[(i64)L * 768 + n] = v;
    }
    return;
  }

  const float* src;
  u16* dst;
  int srcStride, dstStride, gxn, ti;
  if (t < 80)       { ti = t;       src = woff + (i64)L * 81920;  dst = wbL;            srcStride = 320;  dstStride = 256;  gxn = 10; }
  else if (t < 120) { ti = t - 80;  src = watt + (i64)L * 40960;  dst = wbL + 320 * 256; srcStride = 160;  dstStride = 256;  gxn = 5;  }
  else if (t < 184) { ti = t - 120; src = wval + (i64)L * 65536;  dst = wbL + 480 * 256; srcStride = 256;  dstStride = 256;  gxn = 8;  }
  else if (t < 248) { ti = t - 184; src = wout + (i64)L * 65536;  dst = wbL + 196608;   srcStride = 256;  dstStride = 256;  gxn = 8;  }
  else if (t < 504) { ti = t - 248; src = w1 + (i64)L * 262144;   dst = wbL + 262144;   srcStride = 1024; dstStride = 256;  gxn = 32; }
  else              { ti = t - 504; src = w2 + (i64)L * 262144;   dst = wbL + 524288;   srcStride = 256;  dstStride = 1024; gxn = 8;  }
  int n0 = (ti % gxn) * 32, k0 = (ti / gxn) * 32;

  __shared__ float tile[32][33];
  int tx = threadIdx.x & 31, ty = threadIdx.x >> 5;
  for (int i = ty; i < 32; i += 8)
    tile[i][tx] = src[(i64)(k0 + i) * srcStride + n0 + tx];
  __syncthreads();
  for (int i = ty; i < 32; i += 8)
    dst[(i64)(n0 + i) * dstStride + k0 + tx] = f2bf(tile[tx][i]);
}

// ---------------- all 3 input transposes in ONE dispatch -------------------
// in [2][K][P] f32 -> out [2*P][K] bf16; ranges: in0 4096 blk, in1 2048, in2 1024
__global__ __launch_bounds__(256) void trans_all_k(
    const float* __restrict__ in0, const float* __restrict__ in1,
    const float* __restrict__ in2, u16* __restrict__ a0,
    u16* __restrict__ a1, u16* __restrict__ a2)
{
  int t = blockIdx.x;
  const float* in;
  u16* out;
  int K, P, gx, ti;
  if (t < 4096)      { ti = t;        in = in0; out = a0; K = 512;  P = 4096; gx = 128; }
  else if (t < 6144) { ti = t - 4096; in = in1; out = a1; K = 1024; P = 1024; gx = 32;  }
  else               { ti = t - 6144; in = in2; out = a2; K = 2048; P = 256;  gx = 8;   }
  int gy = (K >> 5);
  int b = ti / (gx * gy);
  int rem = ti - b * gx * gy;
  int p0 = (rem % gx) * 32, k0 = (rem / gx) * 32;

  __shared__ float tile[32][33];
  int tx = threadIdx.x & 31, ty = threadIdx.x >> 5;
  const float* ib = in + (i64)b * K * P;
  for (int i = ty; i < 32; i += 8)
    tile[i][tx] = ib[(i64)(k0 + i) * P + p0 + tx];
  __syncthreads();
  for (int i = ty; i < 32; i += 8)
    out[((i64)b * P + p0 + i) * K + k0 + tx] = f2bf(tile[tx][i]);
}

__global__ void im2col_bf16_k(const float* __restrict__ in, u16* __restrict__ out,
    int Cin, int Hin, int Win, int Ho, int Wo)
{
  int Kk = Cin * 9;
  i64 total = (i64)2 * Ho * Wo * Kk;
  i64 o = (i64)blockIdx.x * 256 + threadIdx.x;
  if (o >= total) return;
  int k = (int)(o % Kk);
  int m = (int)(o / Kk);
  int hw = Ho * Wo;
  int b = m / hw, pix = m - b * hw;
  int oy = pix / Wo, ox = pix - oy * Wo;
  int ci = k / 9, r = k - ci * 9;
  int ky = r / 3, kx = r - ky * 3;
  int iy = oy * 2 - 1 + ky, ix = ox * 2 - 1 + kx;
  float v = 0.f;
  if (iy >= 0 && iy < Hin && ix >= 0 && ix < Win)
    v = in[(((i64)b * Cin + ci) * Hin + iy) * Win + ix];
  out[o] = f2bf(v);
}

__global__ void gn_relu_k(const float* __restrict__ feats, float* __restrict__ y,
    const float* __restrict__ g, const float* __restrict__ bt)
{
  int grp = blockIdx.x, b = blockIdx.y;
  int tid = threadIdx.x;
  const float* fb = feats + ((i64)b * NTOK + 5376) * 256 + grp * 32;
  float s = 0.f, ss = 0.f;
  for (int i = tid; i < 2048; i += 256) {
    int cl = i >> 6, p = i & 63;
    float v = fb[(i64)p * 256 + cl];
    s += v; ss += v * v;
  }
  __shared__ float sb[4], ssb[4];
#pragma unroll
  for (int o = 32; o > 0; o >>= 1) { s += __shfl_down(s, o); ss += __shfl_down(ss, o); }
  int wv = tid >> 6;
  if ((tid & 63) == 0) { sb[wv] = s; ssb[wv] = ss; }
  __syncthreads();
  float ts = sb[0] + sb[1] + sb[2] + sb[3];
  float tss = ssb[0] + ssb[1] + ssb[2] + ssb[3];
  float mean = ts * (1.f / 2048.f);
  float rs = rsqrtf(tss * (1.f / 2048.f) - mean * mean + 1e-5f);
  for (int i = tid; i < 2048; i += 256) {
    int cl = i >> 6, p = i & 63;
    int c = grp * 32 + cl;
    float v = (fb[(i64)p * 256 + cl] - mean) * rs * g[c] + bt[c];
    y[((i64)b * 256 + c) * 64 + p] = fmaxf(v, 0.f);
  }
}

__global__ __launch_bounds__(256) void ln_k(const float* __restrict__ x,
    u16* __restrict__ y, const float* __restrict__ g, const float* __restrict__ bt,
    int rows)
{
  int row = blockIdx.x * 4 + (threadIdx.x >> 6);
  if (row >= rows) return;
  int lane = threadIdx.x & 63;
  float4 v = ((const float4*)(x + (i64)row * 256))[lane];
  float s = v.x + v.y + v.z + v.w;
  float ss = v.x * v.x + v.y * v.y + v.z * v.z + v.w * v.w;
#pragma unroll
  for (int o = 32; o > 0; o >>= 1) { s += __shfl_down(s, o); ss += __shfl_down(ss, o); }
  s = __shfl(s, 0);
  ss = __shfl(ss, 0);
  float mean = s * (1.f / 256.f);
  float rs = rsqrtf(ss * (1.f / 256.f) - mean * mean + 1e-5f);
  float4 gg = ((const float4*)g)[lane];
  float4 bb = ((const float4*)bt)[lane];
  ushort4 o4;
  o4.x = f2bf((v.x - mean) * rs * gg.x + bb.x);
  o4.y = f2bf((v.y - mean) * rs * gg.y + bb.y);
  o4.z = f2bf((v.z - mean) * rs * gg.z + bb.z);
  o4.w = f2bf((v.w - mean) * rs * gg.w + bb.w);
  ((ushort4*)(y + (i64)row * 256))[lane] = o4;
}

// deformable sampling v5 (known-good)
__global__ __launch_bounds__(256) void dsample_k(
    const u16* __restrict__ val, const u16* __restrict__ off,
    const u16* __restrict__ att, u16* __restrict__ out)
{
  const int FH[5] = {64, 32, 16, 8, 4};
  const int ST[5] = {0, 4096, 5120, 5376, 5440};
  int bid = blockIdx.x;
  int chunk = (bid & 7) * 86 + (bid >> 3);
  if (chunk >= 682) return;
  int lane = threadIdx.x & 63;
  int half = lane >> 5;
  int l32 = lane & 31;
  int t = chunk * 8 + ((threadIdx.x >> 6) << 1) + half;
  int b = blockIdx.y;
  int h = l32 >> 2, d4 = l32 & 3;

  int lv;
  if (t < 4096)      lv = 0;
  else if (t < 5120) lv = 1;
  else if (t < 5376) lv = 2;
  else if (t < 5440) lv = 3;
  else               lv = 4;
  int loc = t - ST[lv];
  int sh = 6 - lv;
  int py = loc >> sh, px = loc - (py << sh);
  float inv = 1.f / (float)FH[lv];
  float prx = (px + 0.5f) * inv, pry = (py + 0.5f) * inv;
  i64 bt = (i64)b * NTOK + t;
  const u16* offp = off + bt * 320 + h * 40;
  const u16* attp = att + bt * 160 + h * 20;
  const u16* vbase = val + ((i64)b * NTOK) * 256 + h * 32 + d4 * 8;

  float own_a[5], own_fx[5], own_fy[5];
  int own_pk[5];
  float mx = -1e30f;
#pragma unroll
  for (int j = 0; j < 5; j++) {
    float lg = bf2f(attp[d4 + 4 * j]);
    own_a[j] = lg;
    mx = fmaxf(mx, lg);
  }
  mx = fmaxf(mx, __shfl_xor(mx, 1));
  mx = fmaxf(mx, __shfl_xor(mx, 2));
  float sum = 0.f;
#pragma unroll
  for (int j = 0; j < 5; j++) {
    float e = __expf(own_a[j] - mx);
    own_a[j] = e;
    sum += e;
  }
  sum += __shfl_xor(sum, 1);
  sum += __shfl_xor(sum, 2);
  float rinv = 1.f / sum;
#pragma unroll
  for (int j = 0; j < 5; j++) {
    int p = d4 + 4 * j;
    own_a[j] *= rinv;
    unsigned opk = *(const unsigned*)(offp + 2 * p);
    float ox = bf2f((u16)(opk & 0xFFFF));
    float oy = bf2f((u16)(opk >> 16));
    float sff = (float)(64 >> j);
    float xx = prx * sff + ox - 0.5f;
    float yy = pry * sff + oy - 0.5f;
    float xf = floorf(xx), yf = floorf(yy);
    own_fx[j] = xx - xf;
    own_fy[j] = yy - yf;
    own_pk[j] = (((int)yf) << 16) | (((int)xf) & 0xFFFF);
  }

  float acc[8] = {0.f, 0.f, 0.f, 0.f, 0.f, 0.f, 0.f, 0.f};
#pragma unroll
  for (int p = 0; p < 20; p++) {
    const int j = p >> 2;
    const int sf = FH[j], st = ST[j];
    int src = (half << 5) | (h << 2) | (p & 3);
    float wa = __shfl(own_a[j], src);
    float fx = __shfl(own_fx[j], src);
    float fy = __shfl(own_fy[j], src);
    int pk = __shfl(own_pk[j], src);
    int x0 = (pk << 16) >> 16;
    int y0 = pk >> 16;
    float gx0 = wa - wa * fx, gx1 = wa * fx;
    float w00 = gx0 - gx0 * fy, w01 = gx0 * fy;
    float w10 = gx1 - gx1 * fy, w11 = gx1 * fy;
    bool xin0 = (x0 >= 0) & (x0 < sf), xin1 = (x0 + 1 >= 0) & (x0 + 1 < sf);
    bool yin0 = (y0 >= 0) & (y0 < sf), yin1 = (y0 + 1 >= 0) & (y0 + 1 < sf);
    int ibase = st + y0 * sf + x0;
#define FMA8(W, IDX) { \
      us8 v = *(const us8*)(vbase + (i64)(IDX) * 256); \
      acc[0] = fmaf(W, bf2f(v[0]), acc[0]); acc[1] = fmaf(W, bf2f(v[1]), acc[1]); \
      acc[2] = fmaf(W, bf2f(v[2]), acc[2]); acc[3] = fmaf(W, bf2f(v[3]), acc[3]); \
      acc[4] = fmaf(W, bf2f(v[4]), acc[4]); acc[5] = fmaf(W, bf2f(v[5]), acc[5]); \
      acc[6] = fmaf(W, bf2f(v[6]), acc[6]); acc[7] = fmaf(W, bf2f(v[7]), acc[7]); }
    if (xin0 & yin0) FMA8(w00, ibase);
    if (xin1 & yin0) FMA8(w10, ibase + 1);
    if (xin0 & yin1) FMA8(w01, ibase + sf);
    if (xin1 & yin1) FMA8(w11, ibase + sf + 1);
#undef FMA8
  }
  us8 o;
#pragma unroll
  for (int i = 0; i < 8; i++) o[i] = f2bf(acc[i]);
  *(us8*)(out + ((bt * 8 + h) * 32 + d4 * 8)) = o;
}

// all 5 levels in one dispatch
__global__ __launch_bounds__(256) void untranspose_all_k(
    const float* __restrict__ feats, float* __restrict__ out)
{
  int u = blockIdx.x;
  int pt0, start, S; i64 ooff;
  if (u < 128)      { pt0 = u;       start = 0;    S = 4096; ooff = 0; }
  else if (u < 160) { pt0 = u - 128; start = 4096; S = 1024; ooff = 2097152; }
  else if (u < 168) { pt0 = u - 160; start = 5120; S = 256;  ooff = 2621440; }
  else if (u < 170) { pt0 = u - 168; start = 5376; S = 64;   ooff = 2752512; }
  else              { pt0 = 0;       start = 5440; S = 16;   ooff = 2785280; }
  __shared__ float tile[32][33];
  int pt = pt0 * 32, ct = blockIdx.y * 32, b = blockIdx.z;
  int tx = threadIdx.x & 31, ty = threadIdx.x >> 5;
  for (int i = ty; i < 32; i += 8) {
    int p = pt + i;
    tile[i][tx] = (p < S) ? feats[((i64)b * NTOK + start + p) * 256 + ct + tx] : 0.f;
  }
  __syncthreads();
  for (int i = ty; i < 32; i += 8) {
    int c = ct + i, p = pt + tx;
    if (p < S) out[ooff + ((i64)b * 256 + c) * S + p] = tile[tx][i];
  }
}

extern "C" void kernel_launch(void* const* d_in, const int* in_sizes, int n_in,
                              void* d_out, int out_size, void* d_ws, size_t ws_size,
                              hipStream_t stream)
{
  const float* in0  = (const float*)d_in[0];
  const float* in1  = (const float*)d_in[1];
  const float* in2  = (const float*)d_in[2];
  const float* pw0  = (const float*)d_in[3];
  const float* pb0  = (const float*)d_in[4];
  const float* pw1  = (const float*)d_in[5];
  const float* pb1  = (const float*)d_in[6];
  const float* pw2  = (const float*)d_in[7];
  const float* pb2  = (const float*)d_in[8];
  const float* buw0 = (const float*)d_in[9];
  const float* bub0 = (const float*)d_in[10];
  const float* gng  = (const float*)d_in[11];
  const float* gnb  = (const float*)d_in[12];
  const float* buw1 = (const float*)d_in[13];
  const float* bub1 = (const float*)d_in[14];
  const float* ln1g = (const float*)d_in[15];
  const float* ln1b = (const float*)d_in[16];
  const float* woff = (const float*)d_in[17];
  const float* boff = (const float*)d_in[18];
  const float* watt = (const float*)d_in[19];
  const float* batt = (const float*)d_in[20];
  const float* wval = (const float*)d_in[21];
  const float* bval = (const float*)d_in[22];
  const float* wout = (const float*)d_in[23];
  const float* bout = (const float*)d_in[24];
  const float* ln2g = (const float*)d_in[25];
  const float* ln2b = (const float*)d_in[26];
  const float* w1   = (const float*)d_in[27];
  const float* b1   = (const float*)d_in[28];
  const float* w2   = (const float*)d_in[29];
  const float* b2   = (const float*)d_in[30];
  float* out = (float*)d_out;

  const i64 TC = (i64)NTOK * 256;

  // ---- ws layout (f32 units) ----
  float* ws    = (float*)d_ws;
  float* feats = ws;                               // 2,793,472
  u16*   qb    = (u16*)(feats + 2793472);          // 11008x256 bf16
  u16*   valb  = qb + 2818048;
  u16*   sampb = valb + 2818048;
  float* U     = (float*)(sampb + 2818048);        // union region: 5,637,120 f32
  u16*   off16 = (u16*)U;                          // [10912][320] bf16
  u16*   att16 = off16 + 3491840;                  // [10912][160] bf16
  u16*   abuf0 = (u16*)U;                          // in0 A: 4,194,304 u16
  u16*   abuf1 = abuf0 + 4194304;                  // in1 A: 2,097,152 u16
  u16*   abuf2 = abuf1 + 2097152;                  // in2 A: 1,048,576 u16
  float* part  = U + 3670016;                      // split-K partials (<=524,288 f32)
  u16*   wb    = (u16*)(U + 5637120);              // 10,944,512 bf16
  float* bqkv  = (float*)(wb + 10944512);          // 4,608 f32
  float* m4gn  = bqkv + 4608;                      // 32,768 f32

  auto mg64 = [&](dim3 grid, const u16* A, const u16* B, int K,
                  float* C, float* C2, u16* C16, i64 sCm, const float* bias,
                  int relu, int addres, int qkv, int M, int N, int mbsh, i64 bCz, int KS) {
    mgemm_k<64><<<grid, dim3(256), 0, stream>>>(A, B, K, C, C2, C16, sCm, bias,
        relu, addres, qkv, M, N, mbsh, bCz, KS, part);
  };

  // ---- weight conversion (2 dispatches) ----
  cvt_pro_k<<<dim3(24320), dim3(256), 0, stream>>>(pw0, pw1, pw2, buw0, buw1, wb);
  u16* wbL0 = wb + 6225920;
  cvt_layer_all_k<<<dim3(761, NLAYERS), dim3(256), 0, stream>>>(
      woff, watt, wval, wout, w1, w2, boff, batt, bval, wbL0, bqkv);

  // ---- projections: all 3 transposes in one dispatch, then GEMMs ----
  trans_all_k<<<dim3(7168), dim3(256), 0, stream>>>(in0, in1, in2,
      abuf0, abuf1, abuf2);
  mg64(dim3(64, 4, 1), abuf0, wb, 512, feats, nullptr, nullptr, 256, pb0, 0, 0, 0,
       8192, 256, 12, TC, 1);
  mg64(dim3(16, 4, 1), abuf1, wb + 131072, 1024, feats + (i64)4096 * 256, nullptr,
       nullptr, 256, pb1, 0, 0, 0, 2048, 256, 10, TC, 1);
  mg64(dim3(4, 4, 4), abuf2, wb + 393216, 2048, nullptr, nullptr, nullptr, 256,
       nullptr, 0, 0, 0, 512, 256, 8, 0, 4);
  reduce_k<<<dim3(512), dim3(256), 0, stream>>>(part, feats + (i64)5120 * 256, pb2,
      8, TC, 256, 512, 256, 4);

  // ---- bottom-up conv0 (im2col reuses abuf0 region; proj GEMMs done) ----
  im2col_bf16_k<<<dim3(9216), dim3(256), 0, stream>>>(in2, abuf0, 2048, 16, 16, 8, 8);
  mg64(dim3(1, 4, 16), abuf0, wb + 917504, 18432, nullptr, nullptr, nullptr, 256,
       nullptr, 0, 0, 0, 128, 256, 6, 0, 16);
  reduce_k<<<dim3(128), dim3(256), 0, stream>>>(part, feats + (i64)5376 * 256, bub0,
      6, TC, 256, 128, 256, 16);

  // ---- GN+ReLU, bottom-up conv1 ----
  gn_relu_k<<<dim3(8, 2), dim3(256), 0, stream>>>(feats, m4gn, gng, gnb);
  im2col_bf16_k<<<dim3(288), dim3(256), 0, stream>>>(m4gn, abuf0, 256, 8, 8, 4, 4);
  mg64(dim3(1, 4, 4), abuf0, wb + 5636096, 2304, nullptr, nullptr, nullptr, 256,
       nullptr, 0, 0, 0, 32, 256, 4, 0, 4);
  reduce_k<<<dim3(32), dim3(256), 0, stream>>>(part, feats + (i64)5440 * 256, bub1,
      4, TC, 256, 32, 256, 4);

  // ---- 6 transformer layers ----
  for (int i = 0; i < NLAYERS; i++) {
    const u16* wbL = wb + 6225920 + (i64)i * 786432;
    ln_k<<<dim3(2728), dim3(256), 0, stream>>>(feats, qb,
        ln1g + (i64)i * 256, ln1b + (i64)i * 256, BNROWS);
    mg64(dim3(86, 12, 1), qb, wbL, 256, (float*)off16, (float*)att16, valb, 0,
         bqkv + (i64)i * 768, 0, 0, 1, BNROWS, 768, 14, 0, 1);
    dsample_k<<<dim3(688, 2), dim3(256), 0, stream>>>(valb, off16, att16, sampb);
    mg64(dim3(86, 4, 1), sampb, wbL + 196608, 256, feats, nullptr, nullptr, 256,
         bout + (i64)i * 256, 0, 1, 0, BNROWS, 256, 14, 0, 1);
    ffn_fused_k<<<dim3(171), dim3(512), 0, stream>>>(feats, wbL + 262144,
        wbL + 524288, b1 + (i64)i * 1024, b2 + (i64)i * 256,
        ln2g + (i64)i * 256, ln2b + (i64)i * 256, BNROWS);
  }

  // ---- split into 5 level maps (one dispatch) ----
  untranspose_all_k<<<dim3(171, 8, 2), dim3(256), 0, stream>>>(feats, out);
  (void)in_sizes; (void)n_in; (void)out_size; (void)ws_size;
}

// Round 23
// 847.805 us; speedup vs baseline: 1.0589x; 1.0124x over previous
//
#include <hip/hip_runtime.h>
#include <cstdint>

typedef long long i64;
typedef unsigned short u16;
typedef __attribute__((ext_vector_type(8))) short short8;
typedef __attribute__((ext_vector_type(8))) unsigned short us8;
typedef __attribute__((ext_vector_type(4))) float f32x4;

#define NTOK 5456
#define BNROWS 10912
#define NLAYERS 6

__device__ __forceinline__ u16 f2bf(float f) {
  unsigned u = __float_as_uint(f);
  return (u16)((u + 0x7FFFu + ((u >> 16) & 1u)) >> 16);
}
__device__ __forceinline__ float bf2f(u16 h) {
  return __uint_as_float(((unsigned)h) << 16);
}

// ---------------- bf16 MFMA GEMM, 2-phase double-buffered ----------------
template<int BNT>
__global__ __launch_bounds__(256) void mgemm_k(
    const u16* __restrict__ A, const u16* __restrict__ B, int K,
    float* __restrict__ C, float* __restrict__ C2, u16* __restrict__ C16, i64 sCm,
    const float* __restrict__ bias, int relu, int addres, int qkv,
    int M, int N, int mbsh, i64 bCz,
    int KS, float* __restrict__ part)
{
  constexpr int NW = BNT / 32;
  __shared__ u16 Asm[2][128 * 64];
  __shared__ u16 Bsm[2][BNT * 64];
  int tid = threadIdx.x;

  int bx = blockIdx.x, by = blockIdx.y;
  int gx = gridDim.x, gy = gridDim.y;
  int nwg = gx * gy;
  if (KS == 1 && nwg >= 16) {
    int lin = bx + gx * by;
    int xcd = lin & 7, k = lin >> 3;
    int q = nwg >> 3, r = nwg & 7;
    int f = (xcd < r) ? (xcd * (q + 1) + k) : (r * (q + 1) + (xcd - r) * q + k);
    bx = f / gy;
    by = f - bx * gy;
  }
  int m0 = bx * 128, n0 = by * BNT;

  int ks = blockIdx.z;
  int Kc = K / KS;
  int k0 = ks * Kc;
  int lane = tid & 63, w = tid >> 6;
  int wr = w >> 1, wc = w & 1;
  int r16 = lane & 15, g = lane >> 4;

  f32x4 acc[4][NW];
#pragma unroll
  for (int mi = 0; mi < 4; mi++)
#pragma unroll
    for (int nj = 0; nj < NW; nj++) acc[mi][nj] = (f32x4){0.f, 0.f, 0.f, 0.f};

  const u16* Ag = A + (i64)m0 * K + k0;
  const u16* Bg = B + (i64)n0 * K + k0;
  int nt = Kc >> 6;

  auto stage = [&](int buf, int kt) {
#pragma unroll
    for (int r = 0; r < 4; r++) {
      int s = r * 256 + tid;
      int row = s >> 3, c = s & 7;
      int cs = ((c ^ (row & 7)) << 3);
      __builtin_amdgcn_global_load_lds(
          (const __attribute__((address_space(1))) void*)(Ag + (i64)row * K + kt + cs),
          (__attribute__((address_space(3))) void*)(&Asm[buf][(r * 256 + (w << 6)) << 3]),
          16, 0, 0);
    }
#pragma unroll
    for (int r = 0; r < NW; r++) {
      int s = r * 256 + tid;
      int row = s >> 3, c = s & 7;
      int cs = ((c ^ (row & 7)) << 3);
      __builtin_amdgcn_global_load_lds(
          (const __attribute__((address_space(1))) void*)(Bg + (i64)row * K + kt + cs),
          (__attribute__((address_space(3))) void*)(&Bsm[buf][(r * 256 + (w << 6)) << 3]),
          16, 0, 0);
    }
  };

  stage(0, 0);
  __syncthreads();
  for (int t = 0; t < nt; t++) {
    int cur = t & 1;
    if (t + 1 < nt) stage(cur ^ 1, (t + 1) << 6);
#pragma unroll
    for (int h = 0; h < 2; h++) {
      short8 av[4], bv[NW];
#pragma unroll
      for (int mi = 0; mi < 4; mi++) {
        int row = wr * 64 + mi * 16 + r16;
        av[mi] = *(const short8*)&Asm[cur][row * 64 + ((((h << 2) + g) ^ (row & 7)) << 3)];
      }
#pragma unroll
      for (int nj = 0; nj < NW; nj++) {
        int row = wc * (NW * 16) + nj * 16 + r16;
        bv[nj] = *(const short8*)&Bsm[cur][row * 64 + ((((h << 2) + g) ^ (row & 7)) << 3)];
      }
#pragma unroll
      for (int mi = 0; mi < 4; mi++)
#pragma unroll
        for (int nj = 0; nj < NW; nj++)
          acc[mi][nj] = __builtin_amdgcn_mfma_f32_16x16x32_bf16(
              av[mi], bv[nj], acc[mi][nj], 0, 0, 0);
    }
    __syncthreads();
  }

  if (KS > 1) {
#pragma unroll
    for (int mi = 0; mi < 4; mi++)
#pragma unroll
      for (int nj = 0; nj < NW; nj++)
#pragma unroll
        for (int r = 0; r < 4; r++) {
          int grow = m0 + wr * 64 + mi * 16 + g * 4 + r;
          int gcol = n0 + wc * (NW * 16) + nj * 16 + r16;
          if (grow < M) part[((i64)ks * M + grow) * N + gcol] = acc[mi][nj][r];
        }
  } else if (qkv) {
    u16* off16 = (u16*)C;
    u16* att16 = (u16*)C2;
#pragma unroll
    for (int mi = 0; mi < 4; mi++)
#pragma unroll
      for (int nj = 0; nj < NW; nj++)
#pragma unroll
        for (int r = 0; r < 4; r++) {
          int grow = m0 + wr * 64 + mi * 16 + g * 4 + r;
          int gcol = n0 + wc * (NW * 16) + nj * 16 + r16;
          if (grow < M) {
            float v = acc[mi][nj][r] + bias[gcol];
            if (gcol < 320) off16[(i64)grow * 320 + gcol] = f2bf(v);
            else if (gcol < 480) att16[(i64)grow * 160 + (gcol - 320)] = f2bf(v);
            else if (gcol < 736) C16[(i64)grow * 256 + (gcol - 480)] = f2bf(v);
          }
        }
  } else {
    float bv[NW];
    int gc0 = n0 + wc * (NW * 16) + r16;
#pragma unroll
    for (int nj = 0; nj < NW; nj++)
      bv[nj] = bias ? bias[gc0 + nj * 16] : 0.f;
    int mask = (1 << mbsh) - 1;
#pragma unroll
    for (int mi = 0; mi < 4; mi++) {
#pragma unroll
      for (int r = 0; r < 4; r++) {
        int grow = m0 + wr * 64 + mi * 16 + g * 4 + r;
        if (grow >= M) continue;
        i64 rowb = (i64)(grow >> mbsh) * bCz + (i64)(grow & mask) * sCm;
#pragma unroll
        for (int nj = 0; nj < NW; nj++) {
          int gcol = gc0 + nj * 16;
          if (gcol >= N) continue;
          float v = acc[mi][nj][r] + bv[nj];
          if (relu) v = fmaxf(v, 0.f);
          i64 ci = rowb + gcol;
          if (C16) C16[ci] = f2bf(v);
          else {
            if (addres) v += C[ci];
            C[ci] = v;
          }
        }
      }
    }
  }
}

// ---------------- fused LN2+FFN v3 (known-good) ----------------------------
__global__ __launch_bounds__(512, 1) void ffn_fused_k(
    float* __restrict__ feats, const u16* __restrict__ w1n,
    const u16* __restrict__ w2n, const float* __restrict__ b1,
    const float* __restrict__ b2, const float* __restrict__ lng,
    const float* __restrict__ lnb, int M)
{
  __shared__ u16 B1s[2][64 * 256];
  __shared__ u16 B2s[2][256 * 64];
  __shared__ u16 Hs[64 * 88];
  __shared__ float b1s[1024];
  u16* As = &B1s[1][0];

  int tid = threadIdx.x;
  int lane = tid & 63, w = tid >> 6;
  int wr = w >> 1, wc = w & 1;
  int r16 = lane & 15, g = lane >> 4;
  int m0 = blockIdx.x * 64;

  auto stageW = [&](int buf, int ch) {
#pragma unroll
    for (int r = 0; r < 4; r++) {
      int s = r * 512 + tid;
      int row = s >> 5, c = s & 31;
      int cs = ((c ^ (row & 7)) << 3);
      __builtin_amdgcn_global_load_lds(
          (const __attribute__((address_space(1))) void*)(w1n + (i64)(ch * 64 + row) * 256 + cs),
          (__attribute__((address_space(3))) void*)(&B1s[buf][(r * 512 + (w << 6)) << 3]),
          16, 0, 0);
    }
#pragma unroll
    for (int r = 0; r < 4; r++) {
      int s = r * 512 + tid;
      int row = s >> 3, c = s & 7;
      int cs = ((c ^ (row & 7)) << 3);
      __builtin_amdgcn_global_load_lds(
          (const __attribute__((address_space(1))) void*)(w2n + (i64)row * 1024 + ch * 64 + cs),
          (__attribute__((address_space(3))) void*)(&B2s[buf][(r * 512 + (w << 6)) << 3]),
          16, 0, 0);
    }
  };

  stageW(0, 0);
  for (int i = tid; i < 1024; i += 512) b1s[i] = b1[i];

  // LN2 on rows m0..m0+63: 8 lanes per row, 32 cols each
  {
    int rw = tid >> 3, c0 = (tid & 7) * 32;
    const float* fr = feats + (i64)(m0 + rw) * 256 + c0;
    float4 x[8];
    float s = 0.f, ss = 0.f;
#pragma unroll
    for (int j = 0; j < 8; j++) {
      x[j] = ((const float4*)fr)[j];
      s += x[j].x + x[j].y + x[j].z + x[j].w;
      ss += x[j].x * x[j].x + x[j].y * x[j].y + x[j].z * x[j].z + x[j].w * x[j].w;
    }
#pragma unroll
    for (int o = 1; o <= 4; o <<= 1) { s += __shfl_xor(s, o); ss += __shfl_xor(ss, o); }
    float mean = s * (1.f / 256.f);
    float rs = rsqrtf(ss * (1.f / 256.f) - mean * mean + 1e-5f);
    const float4* gp = (const float4*)(lng + c0);
    const float4* bp = (const float4*)(lnb + c0);
#pragma unroll
    for (int j = 0; j < 8; j += 2) {
      float4 g0 = gp[j], g1 = gp[j + 1];
      float4 b0 = bp[j], b1_ = bp[j + 1];
      us8 o;
      o[0] = f2bf((x[j].x - mean) * rs * g0.x + b0.x);
      o[1] = f2bf((x[j].y - mean) * rs * g0.y + b0.y);
      o[2] = f2bf((x[j].z - mean) * rs * g0.z + b0.z);
      o[3] = f2bf((x[j].w - mean) * rs * g0.w + b0.w);
      o[4] = f2bf((x[j + 1].x - mean) * rs * g1.x + b1_.x);
      o[5] = f2bf((x[j + 1].y - mean) * rs * g1.y + b1_.y);
      o[6] = f2bf((x[j + 1].z - mean) * rs * g1.z + b1_.z);
      o[7] = f2bf((x[j + 1].w - mean) * rs * g1.w + b1_.w);
      int gr = (tid & 7) * 4 + (j >> 1);
      *(us8*)&As[rw * 256 + ((gr ^ (rw & 7)) << 3)] = o;
    }
  }
  __syncthreads();

  short8 av_all[8];
  {
    int row = wr * 16 + r16;
#pragma unroll
    for (int ks = 0; ks < 8; ks++)
      av_all[ks] = *(const short8*)&As[row * 256 + (((ks * 4 + g) ^ (row & 7)) << 3)];
  }
  __syncthreads();

  f32x4 acc2[8];
#pragma unroll
  for (int nj = 0; nj < 8; nj++) acc2[nj] = (f32x4){0.f, 0.f, 0.f, 0.f};

  int cur = 0;
  for (int ch = 0; ch < 16; ch++) {
    if (ch + 1 < 16) stageW(cur ^ 1, ch + 1);

    f32x4 acc1[2];
#pragma unroll
    for (int nj = 0; nj < 2; nj++) acc1[nj] = (f32x4){0.f, 0.f, 0.f, 0.f};
#pragma unroll
    for (int ks = 0; ks < 8; ks++) {
      short8 bv[2];
#pragma unroll
      for (int nj = 0; nj < 2; nj++) {
        int row = wc * 32 + nj * 16 + r16;
        bv[nj] = *(const short8*)&B1s[cur][row * 256 + (((ks * 4 + g) ^ (row & 7)) << 3)];
      }
#pragma unroll
      for (int nj = 0; nj < 2; nj++)
        acc1[nj] = __builtin_amdgcn_mfma_f32_16x16x32_bf16(
            av_all[ks], bv[nj], acc1[nj], 0, 0, 0);
    }
#pragma unroll
    for (int nj = 0; nj < 2; nj++)
#pragma unroll
      for (int r = 0; r < 4; r++) {
        int hr = wr * 16 + g * 4 + r;
        int hc = wc * 32 + nj * 16 + r16;
        float v = acc1[nj][r] + b1s[ch * 64 + hc];
        Hs[hr * 88 + hc] = f2bf(fmaxf(v, 0.f));
      }
    __syncthreads();

#pragma unroll
    for (int hh = 0; hh < 2; hh++) {
      short8 av2 = *(const short8*)&Hs[(wr * 16 + r16) * 88 + hh * 32 + g * 8];
      short8 bv2[8];
#pragma unroll
      for (int nj = 0; nj < 8; nj++) {
        int n = wc * 128 + nj * 16 + r16;
        bv2[nj] = *(const short8*)&B2s[cur][n * 64 + (((hh * 4 + g) ^ (n & 7)) << 3)];
      }
#pragma unroll
      for (int nj = 0; nj < 8; nj++)
        acc2[nj] = __builtin_amdgcn_mfma_f32_16x16x32_bf16(
            av2, bv2[nj], acc2[nj], 0, 0, 0);
    }
    __syncthreads();
    cur ^= 1;
  }

#pragma unroll
  for (int r = 0; r < 4; r++) {
    int grow = m0 + wr * 16 + g * 4 + r;
    if (grow >= M) continue;
#pragma unroll
    for (int nj = 0; nj < 8; nj++) {
      int col = wc * 128 + nj * 16 + r16;
      i64 ci = (i64)grow * 256 + col;
      feats[ci] += acc2[nj][r] + b2[col];
    }
  }
}

// reduce split-K fp32 partials (stride N); row map via shift/mask
__global__ void reduce_k(const float* __restrict__ part, float* __restrict__ C,
    const float* __restrict__ bias, int mbsh, i64 bCz, i64 sCm, int M, int N, int KS)
{
  int idx = blockIdx.x * 256 + threadIdx.x;
  if (idx >= M * N) return;
  int m = idx / N, n = idx - m * N;
  float v = bias ? bias[n] : 0.f;
  for (int ks = 0; ks < KS; ks++) v += part[((i64)ks * M + m) * N + n];
  C[(i64)(m >> mbsh) * bCz + (i64)(m & ((1 << mbsh) - 1)) * sCm + n] = v;
}

// ---------------- mega conversion: prologue cvt + layer transposes + input
// transposes, ONE dispatch. ranges: [0,24320) cvt_pro | [24320,28886) layer
// (761 x 6 flat) | [28886,36054) input transposes.
__global__ __launch_bounds__(256) void cvt_mega_k(
    const float* __restrict__ pw0, const float* __restrict__ pw1,
    const float* __restrict__ pw2, const float* __restrict__ buw0,
    const float* __restrict__ buw1,
    const float* __restrict__ woff, const float* __restrict__ watt,
    const float* __restrict__ wval, const float* __restrict__ wout,
    const float* __restrict__ w1, const float* __restrict__ w2,
    const float* __restrict__ boff, const float* __restrict__ batt,
    const float* __restrict__ bval,
    const float* __restrict__ in0, const float* __restrict__ in1,
    const float* __restrict__ in2,
    u16* __restrict__ wb, float* __restrict__ bq,
    u16* __restrict__ a0, u16* __restrict__ a1, u16* __restrict__ a2)
{
  __shared__ float tile[32][33];
  int blk = blockIdx.x;

  if (blk < 24320) {
    int idx = blk * 256 + threadIdx.x;
    if (idx >= 6225920) return;
    float v;
    if (idx < 131072) v = pw0[idx];
    else if (idx < 393216) v = pw1[idx - 131072];
    else if (idx < 917504) v = pw2[idx - 393216];
    else if (idx < 5636096) v = buw0[idx - 917504];
    else v = buw1[idx - 5636096];
    wb[idx] = f2bf(v);
    return;
  }

  if (blk < 28886) {
    int lb = blk - 24320;
    int L = lb / 761, t = lb - L * 761;
    u16* wbL = wb + 6225920 + (i64)L * 786432;

    if (t == 760) {
      for (int idx = threadIdx.x; idx < 8192; idx += 256)
        wbL[736 * 256 + idx] = 0;
      for (int n = threadIdx.x; n < 768; n += 256) {
        float v;
        if (n < 320) v = boff[(i64)L * 320 + n];
        else if (n < 480) v = batt[(i64)L * 160 + (n - 320)];
        else if (n < 736) v = bval[(i64)L * 256 + (n - 480)];
        else v = 0.f;
        bq[(i64)L * 768 + n] = v;
      }
      return;
    }

    const float* src;
    u16* dst;
    int srcStride, dstStride, gxn, ti;
    if (t < 80)       { ti = t;       src = woff + (i64)L * 81920;  dst = wbL;            srcStride = 320;  dstStride = 256;  gxn = 10; }
    else if (t < 120) { ti = t - 80;  src = watt + (i64)L * 40960;  dst = wbL + 320 * 256; srcStride = 160;  dstStride = 256;  gxn = 5;  }
    else if (t < 184) { ti = t - 120; src = wval + (i64)L * 65536;  dst = wbL + 480 * 256; srcStride = 256;  dstStride = 256;  gxn = 8;  }
    else if (t < 248) { ti = t - 184; src = wout + (i64)L * 65536;  dst = wbL + 196608;   srcStride = 256;  dstStride = 256;  gxn = 8;  }
    else if (t < 504) { ti = t - 248; src = w1 + (i64)L * 262144;   dst = wbL + 262144;   srcStride = 1024; dstStride = 256;  gxn = 32; }
    else              { ti = t - 504; src = w2 + (i64)L * 262144;   dst = wbL + 524288;   srcStride = 256;  dstStride = 1024; gxn = 8;  }
    int n0 = (ti % gxn) * 32, k0 = (ti / gxn) * 32;

    int tx = threadIdx.x & 31, ty = threadIdx.x >> 5;
    for (int i = ty; i < 32; i += 8)
      tile[i][tx] = src[(i64)(k0 + i) * srcStride + n0 + tx];
    __syncthreads();
    for (int i = ty; i < 32; i += 8)
      dst[(i64)(n0 + i) * dstStride + k0 + tx] = f2bf(tile[tx][i]);
    return;
  }

  // input transposes: in [2][K][P] f32 -> out [2*P][K] bf16
  {
    int t = blk - 28886;
    const float* in;
    u16* out;
    int K, P, gx, ti;
    if (t < 4096)      { ti = t;        in = in0; out = a0; K = 512;  P = 4096; gx = 128; }
    else if (t < 6144) { ti = t - 4096; in = in1; out = a1; K = 1024; P = 1024; gx = 32;  }
    else               { ti = t - 6144; in = in2; out = a2; K = 2048; P = 256;  gx = 8;   }
    int gy = (K >> 5);
    int b = ti / (gx * gy);
    int rem = ti - b * gx * gy;
    int p0 = (rem % gx) * 32, k0 = (rem / gx) * 32;

    int tx = threadIdx.x & 31, ty = threadIdx.x >> 5;
    const float* ib = in + (i64)b * K * P;
    for (int i = ty; i < 32; i += 8)
      tile[i][tx] = ib[(i64)(k0 + i) * P + p0 + tx];
    __syncthreads();
    for (int i = ty; i < 32; i += 8)
      out[((i64)b * P + p0 + i) * K + k0 + tx] = f2bf(tile[tx][i]);
  }
}

// ---------------- fused: level-2 split-K reduce (512 blk) + conv0 im2col ---
__global__ void red_im2col_k(const float* __restrict__ part,
    float* __restrict__ C, const float* __restrict__ bias, i64 bCz,
    const float* __restrict__ in2, u16* __restrict__ colout)
{
  int t = blockIdx.x;
  if (t < 512) {
    // reduce: M=512, N=256, KS=4, mbsh=8, sCm=256
    int idx = t * 256 + threadIdx.x;
    int m = idx >> 8, n = idx & 255;
    float v = bias[n];
    for (int ks = 0; ks < 4; ks++) v += part[((i64)ks * 512 + m) * 256 + n];
    C[(i64)(m >> 8) * bCz + (i64)(m & 255) * 256 + n] = v;
    return;
  }
  // im2col: Cin=2048, 16x16 -> 8x8, Kk=18432
  i64 o = (i64)(t - 512) * 256 + threadIdx.x;
  const int Kk = 18432, hw = 64;
  int k = (int)(o % Kk);
  int m = (int)(o / Kk);
  int b = m / hw, pix = m - b * hw;
  int oy = pix >> 3, ox = pix & 7;
  int ci = k / 9, r = k - ci * 9;
  int ky = r / 3, kx = r - ky * 3;
  int iy = oy * 2 - 1 + ky, ix = ox * 2 - 1 + kx;
  float v = 0.f;
  if (iy >= 0 && iy < 16 && ix >= 0 && ix < 16)
    v = in2[(((i64)b * 2048 + ci) * 16 + iy) * 16 + ix];
  colout[o] = f2bf(v);
}

__global__ void im2col_bf16_k(const float* __restrict__ in, u16* __restrict__ out,
    int Cin, int Hin, int Win, int Ho, int Wo)
{
  int Kk = Cin * 9;
  i64 total = (i64)2 * Ho * Wo * Kk;
  i64 o = (i64)blockIdx.x * 256 + threadIdx.x;
  if (o >= total) return;
  int k = (int)(o % Kk);
  int m = (int)(o / Kk);
  int hw = Ho * Wo;
  int b = m / hw, pix = m - b * hw;
  int oy = pix / Wo, ox = pix - oy * Wo;
  int ci = k / 9, r = k - ci * 9;
  int ky = r / 3, kx = r - ky * 3;
  int iy = oy * 2 - 1 + ky, ix = ox * 2 - 1 + kx;
  float v = 0.f;
  if (iy >= 0 && iy < Hin && ix >= 0 && ix < Win)
    v = in[(((i64)b * Cin + ci) * Hin + iy) * Win + ix];
  out[o] = f2bf(v);
}

__global__ void gn_relu_k(const float* __restrict__ feats, float* __restrict__ y,
    const float* __restrict__ g, const float* __restrict__ bt)
{
  int grp = blockIdx.x, b = blockIdx.y;
  int tid = threadIdx.x;
  const float* fb = feats + ((i64)b * NTOK + 5376) * 256 + grp * 32;
  float s = 0.f, ss = 0.f;
  for (int i = tid; i < 2048; i += 256) {
    int cl = i >> 6, p = i & 63;
    float v = fb[(i64)p * 256 + cl];
    s += v; ss += v * v;
  }
  __shared__ float sb[4], ssb[4];
#pragma unroll
  for (int o = 32; o > 0; o >>= 1) { s += __shfl_down(s, o); ss += __shfl_down(ss, o); }
  int wv = tid >> 6;
  if ((tid & 63) == 0) { sb[wv] = s; ssb[wv] = ss; }
  __syncthreads();
  float ts = sb[0] + sb[1] + sb[2] + sb[3];
  float tss = ssb[0] + ssb[1] + ssb[2] + ssb[3];
  float mean = ts * (1.f / 2048.f);
  float rs = rsqrtf(tss * (1.f / 2048.f) - mean * mean + 1e-5f);
  for (int i = tid; i < 2048; i += 256) {
    int cl = i >> 6, p = i & 63;
    int c = grp * 32 + cl;
    float v = (fb[(i64)p * 256 + cl] - mean) * rs * g[c] + bt[c];
    y[((i64)b * 256 + c) * 64 + p] = fmaxf(v, 0.f);
  }
}

__global__ __launch_bounds__(256) void ln_k(const float* __restrict__ x,
    u16* __restrict__ y, const float* __restrict__ g, const float* __restrict__ bt,
    int rows)
{
  int row = blockIdx.x * 4 + (threadIdx.x >> 6);
  if (row >= rows) return;
  int lane = threadIdx.x & 63;
  float4 v = ((const float4*)(x + (i64)row * 256))[lane];
  float s = v.x + v.y + v.z + v.w;
  float ss = v.x * v.x + v.y * v.y + v.z * v.z + v.w * v.w;
#pragma unroll
  for (int o = 32; o > 0; o >>= 1) { s += __shfl_down(s, o); ss += __shfl_down(ss, o); }
  s = __shfl(s, 0);
  ss = __shfl(ss, 0);
  float mean = s * (1.f / 256.f);
  float rs = rsqrtf(ss * (1.f / 256.f) - mean * mean + 1e-5f);
  float4 gg = ((const float4*)g)[lane];
  float4 bb = ((const float4*)bt)[lane];
  ushort4 o4;
  o4.x = f2bf((v.x - mean) * rs * gg.x + bb.x);
  o4.y = f2bf((v.y - mean) * rs * gg.y + bb.y);
  o4.z = f2bf((v.z - mean) * rs * gg.z + bb.z);
  o4.w = f2bf((v.w - mean) * rs * gg.w + bb.w);
  ((ushort4*)(y + (i64)row * 256))[lane] = o4;
}

// deformable sampling v5 (known-good)
__global__ __launch_bounds__(256) void dsample_k(
    const u16* __restrict__ val, const u16* __restrict__ off,
    const u16* __restrict__ att, u16* __restrict__ out)
{
  const int FH[5] = {64, 32, 16, 8, 4};
  const int ST[5] = {0, 4096, 5120, 5376, 5440};
  int bid = blockIdx.x;
  int chunk = (bid & 7) * 86 + (bid >> 3);
  if (chunk >= 682) return;
  int lane = threadIdx.x & 63;
  int half = lane >> 5;
  int l32 = lane & 31;
  int t = chunk * 8 + ((threadIdx.x >> 6) << 1) + half;
  int b = blockIdx.y;
  int h = l32 >> 2, d4 = l32 & 3;

  int lv;
  if (t < 4096)      lv = 0;
  else if (t < 5120) lv = 1;
  else if (t < 5376) lv = 2;
  else if (t < 5440) lv = 3;
  else               lv = 4;
  int loc = t - ST[lv];
  int sh = 6 - lv;
  int py = loc >> sh, px = loc - (py << sh);
  float inv = 1.f / (float)FH[lv];
  float prx = (px + 0.5f) * inv, pry = (py + 0.5f) * inv;
  i64 bt = (i64)b * NTOK + t;
  const u16* offp = off + bt * 320 + h * 40;
  const u16* attp = att + bt * 160 + h * 20;
  const u16* vbase = val + ((i64)b * NTOK) * 256 + h * 32 + d4 * 8;

  float own_a[5], own_fx[5], own_fy[5];
  int own_pk[5];
  float mx = -1e30f;
#pragma unroll
  for (int j = 0; j < 5; j++) {
    float lg = bf2f(attp[d4 + 4 * j]);
    own_a[j] = lg;
    mx = fmaxf(mx, lg);
  }
  mx = fmaxf(mx, __shfl_xor(mx, 1));
  mx = fmaxf(mx, __shfl_xor(mx, 2));
  float sum = 0.f;
#pragma unroll
  for (int j = 0; j < 5; j++) {
    float e = __expf(own_a[j] - mx);
    own_a[j] = e;
    sum += e;
  }
  sum += __shfl_xor(sum, 1);
  sum += __shfl_xor(sum, 2);
  float rinv = 1.f / sum;
#pragma unroll
  for (int j = 0; j < 5; j++) {
    int p = d4 + 4 * j;
    own_a[j] *= rinv;
    unsigned opk = *(const unsigned*)(offp + 2 * p);
    float ox = bf2f((u16)(opk & 0xFFFF));
    float oy = bf2f((u16)(opk >> 16));
    float sff = (float)(64 >> j);
    float xx = prx * sff + ox - 0.5f;
    float yy = pry * sff + oy - 0.5f;
    float xf = floorf(xx), yf = floorf(yy);
    own_fx[j] = xx - xf;
    own_fy[j] = yy - yf;
    own_pk[j] = (((int)yf) << 16) | (((int)xf) & 0xFFFF);
  }

  float acc[8] = {0.f, 0.f, 0.f, 0.f, 0.f, 0.f, 0.f, 0.f};
#pragma unroll
  for (int p = 0; p < 20; p++) {
    const int j = p >> 2;
    const int sf = FH[j], st = ST[j];
    int src = (half << 5) | (h << 2) | (p & 3);
    float wa = __shfl(own_a[j], src);
    float fx = __shfl(own_fx[j], src);
    float fy = __shfl(own_fy[j], src);
    int pk = __shfl(own_pk[j], src);
    int x0 = (pk << 16) >> 16;
    int y0 = pk >> 16;
    float gx0 = wa - wa * fx, gx1 = wa * fx;
    float w00 = gx0 - gx0 * fy, w01 = gx0 * fy;
    float w10 = gx1 - gx1 * fy, w11 = gx1 * fy;
    bool xin0 = (x0 >= 0) & (x0 < sf), xin1 = (x0 + 1 >= 0) & (x0 + 1 < sf);
    bool yin0 = (y0 >= 0) & (y0 < sf), yin1 = (y0 + 1 >= 0) & (y0 + 1 < sf);
    int ibase = st + y0 * sf + x0;
#define FMA8(W, IDX) { \
      us8 v = *(const us8*)(vbase + (i64)(IDX) * 256); \
      acc[0] = fmaf(W, bf2f(v[0]), acc[0]); acc[1] = fmaf(W, bf2f(v[1]), acc[1]); \
      acc[2] = fmaf(W, bf2f(v[2]), acc[2]); acc[3] = fmaf(W, bf2f(v[3]), acc[3]); \
      acc[4] = fmaf(W, bf2f(v[4]), acc[4]); acc[5] = fmaf(W, bf2f(v[5]), acc[5]); \
      acc[6] = fmaf(W, bf2f(v[6]), acc[6]); acc[7] = fmaf(W, bf2f(v[7]), acc[7]); }
    if (xin0 & yin0) FMA8(w00, ibase);
    if (xin1 & yin0) FMA8(w10, ibase + 1);
    if (xin0 & yin1) FMA8(w01, ibase + sf);
    if (xin1 & yin1) FMA8(w11, ibase + sf + 1);
#undef FMA8
  }
  us8 o;
#pragma unroll
  for (int i = 0; i < 8; i++) o[i] = f2bf(acc[i]);
  *(us8*)(out + ((bt * 8 + h) * 32 + d4 * 8)) = o;
}

// all 5 levels in one dispatch
__global__ __launch_bounds__(256) void untranspose_all_k(
    const float* __restrict__ feats, float* __restrict__ out)
{
  int u = blockIdx.x;
  int pt0, start, S; i64 ooff;
  if (u < 128)      { pt0 = u;       start = 0;    S = 4096; ooff = 0; }
  else if (u < 160) { pt0 = u - 128; start = 4096; S = 1024; ooff = 2097152; }
  else if (u < 168) { pt0 = u - 160; start = 5120; S = 256;  ooff = 2621440; }
  else if (u < 170) { pt0 = u - 168; start = 5376; S = 64;   ooff = 2752512; }
  else              { pt0 = 0;       start = 5440; S = 16;   ooff = 2785280; }
  __shared__ float tile[32][33];
  int pt = pt0 * 32, ct = blockIdx.y * 32, b = blockIdx.z;
  int tx = threadIdx.x & 31, ty = threadIdx.x >> 5;
  for (int i = ty; i < 32; i += 8) {
    int p = pt + i;
    tile[i][tx] = (p < S) ? feats[((i64)b * NTOK + start + p) * 256 + ct + tx] : 0.f;
  }
  __syncthreads();
  for (int i = ty; i < 32; i += 8) {
    int c = ct + i, p = pt + tx;
    if (p < S) out[ooff + ((i64)b * 256 + c) * S + p] = tile[tx][i];
  }
}

extern "C" void kernel_launch(void* const* d_in, const int* in_sizes, int n_in,
                              void* d_out, int out_size, void* d_ws, size_t ws_size,
                              hipStream_t stream)
{
  const float* in0  = (const float*)d_in[0];
  const float* in1  = (const float*)d_in[1];
  const float* in2  = (const float*)d_in[2];
  const float* pw0  = (const float*)d_in[3];
  const float* pb0  = (const float*)d_in[4];
  const float* pw1  = (const float*)d_in[5];
  const float* pb1  = (const float*)d_in[6];
  const float* pw2  = (const float*)d_in[7];
  const float* pb2  = (const float*)d_in[8];
  const float* buw0 = (const float*)d_in[9];
  const float* bub0 = (const float*)d_in[10];
  const float* gng  = (const float*)d_in[11];
  const float* gnb  = (const float*)d_in[12];
  const float* buw1 = (const float*)d_in[13];
  const float* bub1 = (const float*)d_in[14];
  const float* ln1g = (const float*)d_in[15];
  const float* ln1b = (const float*)d_in[16];
  const float* woff = (const float*)d_in[17];
  const float* boff = (const float*)d_in[18];
  const float* watt = (const float*)d_in[19];
  const float* batt = (const float*)d_in[20];
  const float* wval = (const float*)d_in[21];
  const float* bval = (const float*)d_in[22];
  const float* wout = (const float*)d_in[23];
  const float* bout = (const float*)d_in[24];
  const float* ln2g = (const float*)d_in[25];
  const float* ln2b = (const float*)d_in[26];
  const float* w1   = (const float*)d_in[27];
  const float* b1   = (const float*)d_in[28];
  const float* w2   = (const float*)d_in[29];
  const float* b2   = (const float*)d_in[30];
  float* out = (float*)d_out;

  const i64 TC = (i64)NTOK * 256;

  // ---- ws layout (f32 units) ----
  float* ws    = (float*)d_ws;
  float* feats = ws;                               // 2,793,472
  u16*   qb    = (u16*)(feats + 2793472);          // 11008x256 bf16
  u16*   valb  = qb + 2818048;
  u16*   sampb = valb + 2818048;
  float* U     = (float*)(sampb + 2818048);        // union region: 5,637,120 f32
  u16*   off16 = (u16*)U;                          // [10912][320] bf16
  u16*   att16 = off16 + 3491840;                  // [10912][160] bf16
  u16*   abuf0 = (u16*)U;                          // in0 A: 4,194,304 u16
  u16*   abuf1 = abuf0 + 4194304;                  // in1 A: 2,097,152 u16
  u16*   abuf2 = abuf1 + 2097152;                  // in2 A: 1,048,576 u16
  float* part  = U + 3670016;                      // split-K partials (<=524,288 f32)
  u16*   wb    = (u16*)(U + 5637120);              // 10,944,512 bf16
  float* bqkv  = (float*)(wb + 10944512);          // 4,608 f32
  float* m4gn  = bqkv + 4608;                      // 32,768 f32

  auto mg64 = [&](dim3 grid, const u16* A, const u16* B, int K,
                  float* C, float* C2, u16* C16, i64 sCm, const float* bias,
                  int relu, int addres, int qkv, int M, int N, int mbsh, i64 bCz, int KS) {
    mgemm_k<64><<<grid, dim3(256), 0, stream>>>(A, B, K, C, C2, C16, sCm, bias,
        relu, addres, qkv, M, N, mbsh, bCz, KS, part);
  };

  // ---- all conversions + input transposes in ONE dispatch ----
  u16* wbL0 = wb + 6225920;
  cvt_mega_k<<<dim3(36054), dim3(256), 0, stream>>>(
      pw0, pw1, pw2, buw0, buw1, woff, watt, wval, wout, w1, w2,
      boff, batt, bval, in0, in1, in2, wb, bqkv, abuf0, abuf1, abuf2);

  // ---- projection GEMMs ----
  mg64(dim3(64, 4, 1), abuf0, wb, 512, feats, nullptr, nullptr, 256, pb0, 0, 0, 0,
       8192, 256, 12, TC, 1);
  mg64(dim3(16, 4, 1), abuf1, wb + 131072, 1024, feats + (i64)4096 * 256, nullptr,
       nullptr, 256, pb1, 0, 0, 0, 2048, 256, 10, TC, 1);
  mg64(dim3(4, 4, 4), abuf2, wb + 393216, 2048, nullptr, nullptr, nullptr, 256,
       nullptr, 0, 0, 0, 512, 256, 8, 0, 4);
  // level-2 reduce + conv0 im2col fused (independent; im2col overwrites abuf0
  // only after proj GEMM for in0 is complete - stream order guarantees this)
  red_im2col_k<<<dim3(512 + 9216), dim3(256), 0, stream>>>(
      part, feats + (i64)5120 * 256, pb2, TC, in2, abuf0);

  // ---- bottom-up conv0 GEMM ----
  mg64(dim3(1, 4, 16), abuf0, wb + 917504, 18432, nullptr, nullptr, nullptr, 256,
       nullptr, 0, 0, 0, 128, 256, 6, 0, 16);
  reduce_k<<<dim3(128), dim3(256), 0, stream>>>(part, feats + (i64)5376 * 256, bub0,
      6, TC, 256, 128, 256, 16);

  // ---- GN+ReLU, bottom-up conv1 ----
  gn_relu_k<<<dim3(8, 2), dim3(256), 0, stream>>>(feats, m4gn, gng, gnb);
  im2col_bf16_k<<<dim3(288), dim3(256), 0, stream>>>(m4gn, abuf0, 256, 8, 8, 4, 4);
  mg64(dim3(1, 4, 4), abuf0, wb + 5636096, 2304, nullptr, nullptr, nullptr, 256,
       nullptr, 0, 0, 0, 32, 256, 4, 0, 4);
  reduce_k<<<dim3(32), dim3(256), 0, stream>>>(part, feats + (i64)5440 * 256, bub1,
      4, TC, 256, 32, 256, 4);

  // ---- 6 transformer layers ----
  for (int i = 0; i < NLAYERS; i++) {
    const u16* wbL = wb + 6225920 + (i64)i * 786432;
    ln_k<<<dim3(2728), dim3(256), 0, stream>>>(feats, qb,
        ln1g + (i64)i * 256, ln1b + (i64)i * 256, BNROWS);
    mg64(dim3(86, 12, 1), qb, wbL, 256, (float*)off16, (float*)att16, valb, 0,
         bqkv + (i64)i * 768, 0, 0, 1, BNROWS, 768, 14, 0, 1);
    dsample_k<<<dim3(688, 2), dim3(256), 0, stream>>>(valb, off16, att16, sampb);
    mg64(dim3(86, 4, 1), sampb, wbL + 196608, 256, feats, nullptr, nullptr, 256,
         bout + (i64)i * 256, 0, 1, 0, BNROWS, 256, 14, 0, 1);
    ffn_fused_k<<<dim3(171), dim3(512), 0, stream>>>(feats, wbL + 262144,
        wbL + 524288, b1 + (i64)i * 1024, b2 + (i64)i * 256,
        ln2g + (i64)i * 256, ln2b + (i64)i * 256, BNROWS);
  }

  // ---- split into 5 level maps (one dispatch) ----
  untranspose_all_k<<<dim3(171, 8, 2), dim3(256), 0, stream>>>(feats, out);
  (void)in_sizes; (void)n_in; (void)out_size; (void)ws_size;
}

// Round 24
// 844.442 us; speedup vs baseline: 1.0631x; 1.0040x over previous
//
#include <hip/hip_runtime.h>
#include <cstdint>

typedef long long i64;
typedef unsigned short u16;
typedef __attribute__((ext_vector_type(8))) short short8;
typedef __attribute__((ext_vector_type(8))) unsigned short us8;
typedef __attribute__((ext_vector_type(4))) float f32x4;

#define NTOK 5456
#define BNROWS 10912
#define NLAYERS 6

__device__ __forceinline__ u16 f2bf(float f) {
  unsigned u = __float_as_uint(f);
  return (u16)((u + 0x7FFFu + ((u >> 16) & 1u)) >> 16);
}
__device__ __forceinline__ float bf2f(u16 h) {
  return __uint_as_float(((unsigned)h) << 16);
}

// ---------------- bf16 MFMA GEMM, 2-phase double-buffered ----------------
template<int BNT>
__global__ __launch_bounds__(256) void mgemm_k(
    const u16* __restrict__ A, const u16* __restrict__ B, int K,
    float* __restrict__ C, float* __restrict__ C2, u16* __restrict__ C16, i64 sCm,
    const float* __restrict__ bias, int relu, int addres, int qkv,
    int M, int N, int mbsh, i64 bCz,
    int KS, float* __restrict__ part)
{
  constexpr int NW = BNT / 32;
  __shared__ u16 Asm[2][128 * 64];
  __shared__ u16 Bsm[2][BNT * 64];
  int tid = threadIdx.x;

  int bx = blockIdx.x, by = blockIdx.y;
  int gx = gridDim.x, gy = gridDim.y;
  int nwg = gx * gy;
  if (KS == 1 && nwg >= 16) {
    int lin = bx + gx * by;
    int xcd = lin & 7, k = lin >> 3;
    int q = nwg >> 3, r = nwg & 7;
    int f = (xcd < r) ? (xcd * (q + 1) + k) : (r * (q + 1) + (xcd - r) * q + k);
    bx = f / gy;
    by = f - bx * gy;
  }
  int m0 = bx * 128, n0 = by * BNT;

  int ks = blockIdx.z;
  int Kc = K / KS;
  int k0 = ks * Kc;
  int lane = tid & 63, w = tid >> 6;
  int wr = w >> 1, wc = w & 1;
  int r16 = lane & 15, g = lane >> 4;

  f32x4 acc[4][NW];
#pragma unroll
  for (int mi = 0; mi < 4; mi++)
#pragma unroll
    for (int nj = 0; nj < NW; nj++) acc[mi][nj] = (f32x4){0.f, 0.f, 0.f, 0.f};

  const u16* Ag = A + (i64)m0 * K + k0;
  const u16* Bg = B + (i64)n0 * K + k0;
  int nt = Kc >> 6;

  auto stage = [&](int buf, int kt) {
#pragma unroll
    for (int r = 0; r < 4; r++) {
      int s = r * 256 + tid;
      int row = s >> 3, c = s & 7;
      int cs = ((c ^ (row & 7)) << 3);
      __builtin_amdgcn_global_load_lds(
          (const __attribute__((address_space(1))) void*)(Ag + (i64)row * K + kt + cs),
          (__attribute__((address_space(3))) void*)(&Asm[buf][(r * 256 + (w << 6)) << 3]),
          16, 0, 0);
    }
#pragma unroll
    for (int r = 0; r < NW; r++) {
      int s = r * 256 + tid;
      int row = s >> 3, c = s & 7;
      int cs = ((c ^ (row & 7)) << 3);
      __builtin_amdgcn_global_load_lds(
          (const __attribute__((address_space(1))) void*)(Bg + (i64)row * K + kt + cs),
          (__attribute__((address_space(3))) void*)(&Bsm[buf][(r * 256 + (w << 6)) << 3]),
          16, 0, 0);
    }
  };

  stage(0, 0);
  __syncthreads();
  for (int t = 0; t < nt; t++) {
    int cur = t & 1;
    if (t + 1 < nt) stage(cur ^ 1, (t + 1) << 6);
#pragma unroll
    for (int h = 0; h < 2; h++) {
      short8 av[4], bv[NW];
#pragma unroll
      for (int mi = 0; mi < 4; mi++) {
        int row = wr * 64 + mi * 16 + r16;
        av[mi] = *(const short8*)&Asm[cur][row * 64 + ((((h << 2) + g) ^ (row & 7)) << 3)];
      }
#pragma unroll
      for (int nj = 0; nj < NW; nj++) {
        int row = wc * (NW * 16) + nj * 16 + r16;
        bv[nj] = *(const short8*)&Bsm[cur][row * 64 + ((((h << 2) + g) ^ (row & 7)) << 3)];
      }
#pragma unroll
      for (int mi = 0; mi < 4; mi++)
#pragma unroll
        for (int nj = 0; nj < NW; nj++)
          acc[mi][nj] = __builtin_amdgcn_mfma_f32_16x16x32_bf16(
              av[mi], bv[nj], acc[mi][nj], 0, 0, 0);
    }
    __syncthreads();
  }

  if (KS > 1) {
#pragma unroll
    for (int mi = 0; mi < 4; mi++)
#pragma unroll
      for (int nj = 0; nj < NW; nj++)
#pragma unroll
        for (int r = 0; r < 4; r++) {
          int grow = m0 + wr * 64 + mi * 16 + g * 4 + r;
          int gcol = n0 + wc * (NW * 16) + nj * 16 + r16;
          if (grow < M) part[((i64)ks * M + grow) * N + gcol] = acc[mi][nj][r];
        }
  } else if (qkv) {
    u16* off16 = (u16*)C;
    u16* att16 = (u16*)C2;
#pragma unroll
    for (int mi = 0; mi < 4; mi++)
#pragma unroll
      for (int nj = 0; nj < NW; nj++)
#pragma unroll
        for (int r = 0; r < 4; r++) {
          int grow = m0 + wr * 64 + mi * 16 + g * 4 + r;
          int gcol = n0 + wc * (NW * 16) + nj * 16 + r16;
          if (grow < M) {
            float v = acc[mi][nj][r] + bias[gcol];
            if (gcol < 320) off16[(i64)grow * 320 + gcol] = f2bf(v);
            else if (gcol < 480) att16[(i64)grow * 160 + (gcol - 320)] = f2bf(v);
            else if (gcol < 736) C16[(i64)grow * 256 + (gcol - 480)] = f2bf(v);
          }
        }
  } else {
    float bv[NW];
    int gc0 = n0 + wc * (NW * 16) + r16;
#pragma unroll
    for (int nj = 0; nj < NW; nj++)
      bv[nj] = bias ? bias[gc0 + nj * 16] : 0.f;
    int mask = (1 << mbsh) - 1;
#pragma unroll
    for (int mi = 0; mi < 4; mi++) {
#pragma unroll
      for (int r = 0; r < 4; r++) {
        int grow = m0 + wr * 64 + mi * 16 + g * 4 + r;
        if (grow >= M) continue;
        i64 rowb = (i64)(grow >> mbsh) * bCz + (i64)(grow & mask) * sCm;
#pragma unroll
        for (int nj = 0; nj < NW; nj++) {
          int gcol = gc0 + nj * 16;
          if (gcol >= N) continue;
          float v = acc[mi][nj][r] + bv[nj];
          if (relu) v = fmaxf(v, 0.f);
          i64 ci = rowb + gcol;
          if (C16) C16[ci] = f2bf(v);
          else {
            if (addres) v += C[ci];
            C[ci] = v;
          }
        }
      }
    }
  }
}

// ---------------- fused LN2+FFN v3 (known-good) ----------------------------
__global__ __launch_bounds__(512, 1) void ffn_fused_k(
    float* __restrict__ feats, const u16* __restrict__ w1n,
    const u16* __restrict__ w2n, const float* __restrict__ b1,
    const float* __restrict__ b2, const float* __restrict__ lng,
    const float* __restrict__ lnb, int M)
{
  __shared__ u16 B1s[2][64 * 256];
  __shared__ u16 B2s[2][256 * 64];
  __shared__ u16 Hs[64 * 88];
  __shared__ float b1s[1024];
  u16* As = &B1s[1][0];

  int tid = threadIdx.x;
  int lane = tid & 63, w = tid >> 6;
  int wr = w >> 1, wc = w & 1;
  int r16 = lane & 15, g = lane >> 4;
  int m0 = blockIdx.x * 64;

  auto stageW = [&](int buf, int ch) {
#pragma unroll
    for (int r = 0; r < 4; r++) {
      int s = r * 512 + tid;
      int row = s >> 5, c = s & 31;
      int cs = ((c ^ (row & 7)) << 3);
      __builtin_amdgcn_global_load_lds(
          (const __attribute__((address_space(1))) void*)(w1n + (i64)(ch * 64 + row) * 256 + cs),
          (__attribute__((address_space(3))) void*)(&B1s[buf][(r * 512 + (w << 6)) << 3]),
          16, 0, 0);
    }
#pragma unroll
    for (int r = 0; r < 4; r++) {
      int s = r * 512 + tid;
      int row = s >> 3, c = s & 7;
      int cs = ((c ^ (row & 7)) << 3);
      __builtin_amdgcn_global_load_lds(
          (const __attribute__((address_space(1))) void*)(w2n + (i64)row * 1024 + ch * 64 + cs),
          (__attribute__((address_space(3))) void*)(&B2s[buf][(r * 512 + (w << 6)) << 3]),
          16, 0, 0);
    }
  };

  stageW(0, 0);
  for (int i = tid; i < 1024; i += 512) b1s[i] = b1[i];

  // LN2 on rows m0..m0+63: 8 lanes per row, 32 cols each
  {
    int rw = tid >> 3, c0 = (tid & 7) * 32;
    const float* fr = feats + (i64)(m0 + rw) * 256 + c0;
    float4 x[8];
    float s = 0.f, ss = 0.f;
#pragma unroll
    for (int j = 0; j < 8; j++) {
      x[j] = ((const float4*)fr)[j];
      s += x[j].x + x[j].y + x[j].z + x[j].w;
      ss += x[j].x * x[j].x + x[j].y * x[j].y + x[j].z * x[j].z + x[j].w * x[j].w;
    }
#pragma unroll
    for (int o = 1; o <= 4; o <<= 1) { s += __shfl_xor(s, o); ss += __shfl_xor(ss, o); }
    float mean = s * (1.f / 256.f);
    float rs = rsqrtf(ss * (1.f / 256.f) - mean * mean + 1e-5f);
    const float4* gp = (const float4*)(lng + c0);
    const float4* bp = (const float4*)(lnb + c0);
#pragma unroll
    for (int j = 0; j < 8; j += 2) {
      float4 g0 = gp[j], g1 = gp[j + 1];
      float4 b0 = bp[j], b1_ = bp[j + 1];
      us8 o;
      o[0] = f2bf((x[j].x - mean) * rs * g0.x + b0.x);
      o[1] = f2bf((x[j].y - mean) * rs * g0.y + b0.y);
      o[2] = f2bf((x[j].z - mean) * rs * g0.z + b0.z);
      o[3] = f2bf((x[j].w - mean) * rs * g0.w + b0.w);
      o[4] = f2bf((x[j + 1].x - mean) * rs * g1.x + b1_.x);
      o[5] = f2bf((x[j + 1].y - mean) * rs * g1.y + b1_.y);
      o[6] = f2bf((x[j + 1].z - mean) * rs * g1.z + b1_.z);
      o[7] = f2bf((x[j + 1].w - mean) * rs * g1.w + b1_.w);
      int gr = (tid & 7) * 4 + (j >> 1);
      *(us8*)&As[rw * 256 + ((gr ^ (rw & 7)) << 3)] = o;
    }
  }
  __syncthreads();

  short8 av_all[8];
  {
    int row = wr * 16 + r16;
#pragma unroll
    for (int ks = 0; ks < 8; ks++)
      av_all[ks] = *(const short8*)&As[row * 256 + (((ks * 4 + g) ^ (row & 7)) << 3)];
  }
  __syncthreads();

  f32x4 acc2[8];
#pragma unroll
  for (int nj = 0; nj < 8; nj++) acc2[nj] = (f32x4){0.f, 0.f, 0.f, 0.f};

  int cur = 0;
  for (int ch = 0; ch < 16; ch++) {
    if (ch + 1 < 16) stageW(cur ^ 1, ch + 1);

    f32x4 acc1[2];
#pragma unroll
    for (int nj = 0; nj < 2; nj++) acc1[nj] = (f32x4){0.f, 0.f, 0.f, 0.f};
#pragma unroll
    for (int ks = 0; ks < 8; ks++) {
      short8 bv[2];
#pragma unroll
      for (int nj = 0; nj < 2; nj++) {
        int row = wc * 32 + nj * 16 + r16;
        bv[nj] = *(const short8*)&B1s[cur][row * 256 + (((ks * 4 + g) ^ (row & 7)) << 3)];
      }
#pragma unroll
      for (int nj = 0; nj < 2; nj++)
        acc1[nj] = __builtin_amdgcn_mfma_f32_16x16x32_bf16(
            av_all[ks], bv[nj], acc1[nj], 0, 0, 0);
    }
#pragma unroll
    for (int nj = 0; nj < 2; nj++)
#pragma unroll
      for (int r = 0; r < 4; r++) {
        int hr = wr * 16 + g * 4 + r;
        int hc = wc * 32 + nj * 16 + r16;
        float v = acc1[nj][r] + b1s[ch * 64 + hc];
        Hs[hr * 88 + hc] = f2bf(fmaxf(v, 0.f));
      }
    __syncthreads();

#pragma unroll
    for (int hh = 0; hh < 2; hh++) {
      short8 av2 = *(const short8*)&Hs[(wr * 16 + r16) * 88 + hh * 32 + g * 8];
      short8 bv2[8];
#pragma unroll
      for (int nj = 0; nj < 8; nj++) {
        int n = wc * 128 + nj * 16 + r16;
        bv2[nj] = *(const short8*)&B2s[cur][n * 64 + (((hh * 4 + g) ^ (n & 7)) << 3)];
      }
#pragma unroll
      for (int nj = 0; nj < 8; nj++)
        acc2[nj] = __builtin_amdgcn_mfma_f32_16x16x32_bf16(
            av2, bv2[nj], acc2[nj], 0, 0, 0);
    }
    __syncthreads();
    cur ^= 1;
  }

#pragma unroll
  for (int r = 0; r < 4; r++) {
    int grow = m0 + wr * 16 + g * 4 + r;
    if (grow >= M) continue;
#pragma unroll
    for (int nj = 0; nj < 8; nj++) {
      int col = wc * 128 + nj * 16 + r16;
      i64 ci = (i64)grow * 256 + col;
      feats[ci] += acc2[nj][r] + b2[col];
    }
  }
}

// reduce split-K fp32 partials (stride N); row map via shift/mask
__global__ void reduce_k(const float* __restrict__ part, float* __restrict__ C,
    const float* __restrict__ bias, int mbsh, i64 bCz, i64 sCm, int M, int N, int KS)
{
  int idx = blockIdx.x * 256 + threadIdx.x;
  if (idx >= M * N) return;
  int m = idx / N, n = idx - m * N;
  float v = bias ? bias[n] : 0.f;
  for (int ks = 0; ks < KS; ks++) v += part[((i64)ks * M + m) * N + n];
  C[(i64)(m >> mbsh) * bCz + (i64)(m & ((1 << mbsh) - 1)) * sCm + n] = v;
}

// ---------------- mega conversion (vectorized), ONE dispatch ---------------
// ranges: [0,6080) prologue float4 cvt | [6080,10646) layer transposes
// (761 x 6 flat) | [10646,12438) input transposes 32k x 128p tiles.
__global__ __launch_bounds__(256) void cvt_mega_k(
    const float* __restrict__ pw0, const float* __restrict__ pw1,
    const float* __restrict__ pw2, const float* __restrict__ buw0,
    const float* __restrict__ buw1,
    const float* __restrict__ woff, const float* __restrict__ watt,
    const float* __restrict__ wval, const float* __restrict__ wout,
    const float* __restrict__ w1, const float* __restrict__ w2,
    const float* __restrict__ boff, const float* __restrict__ batt,
    const float* __restrict__ bval,
    const float* __restrict__ in0, const float* __restrict__ in1,
    const float* __restrict__ in2,
    u16* __restrict__ wb, float* __restrict__ bq,
    u16* __restrict__ a0, u16* __restrict__ a1, u16* __restrict__ a2)
{
  __shared__ float tile[32][129];
  int blk = blockIdx.x;

  if (blk < 6080) {
    int idx = (blk * 256 + threadIdx.x) * 4;
    float4 v;
    if (idx < 131072) v = *(const float4*)(pw0 + idx);
    else if (idx < 393216) v = *(const float4*)(pw1 + idx - 131072);
    else if (idx < 917504) v = *(const float4*)(pw2 + idx - 393216);
    else if (idx < 5636096) v = *(const float4*)(buw0 + idx - 917504);
    else v = *(const float4*)(buw1 + idx - 5636096);
    ushort4 o;
    o.x = f2bf(v.x); o.y = f2bf(v.y); o.z = f2bf(v.z); o.w = f2bf(v.w);
    *(ushort4*)(wb + idx) = o;
    return;
  }

  if (blk < 10646) {
    int lb = blk - 6080;
    int L = lb / 761, t = lb - L * 761;
    u16* wbL = wb + 6225920 + (i64)L * 786432;

    if (t == 760) {
      for (int idx = threadIdx.x; idx < 8192; idx += 256)
        wbL[736 * 256 + idx] = 0;
      for (int n = threadIdx.x; n < 768; n += 256) {
        float v;
        if (n < 320) v = boff[(i64)L * 320 + n];
        else if (n < 480) v = batt[(i64)L * 160 + (n - 320)];
        else if (n < 736) v = bval[(i64)L * 256 + (n - 480)];
        else v = 0.f;
        bq[(i64)L * 768 + n] = v;
      }
      return;
    }

    const float* src;
    u16* dst;
    int srcStride, dstStride, gxn, ti;
    if (t < 80)       { ti = t;       src = woff + (i64)L * 81920;  dst = wbL;            srcStride = 320;  dstStride = 256;  gxn = 10; }
    else if (t < 120) { ti = t - 80;  src = watt + (i64)L * 40960;  dst = wbL + 320 * 256; srcStride = 160;  dstStride = 256;  gxn = 5;  }
    else if (t < 184) { ti = t - 120; src = wval + (i64)L * 65536;  dst = wbL + 480 * 256; srcStride = 256;  dstStride = 256;  gxn = 8;  }
    else if (t < 248) { ti = t - 184; src = wout + (i64)L * 65536;  dst = wbL + 196608;   srcStride = 256;  dstStride = 256;  gxn = 8;  }
    else if (t < 504) { ti = t - 248; src = w1 + (i64)L * 262144;   dst = wbL + 262144;   srcStride = 1024; dstStride = 256;  gxn = 32; }
    else              { ti = t - 504; src = w2 + (i64)L * 262144;   dst = wbL + 524288;   srcStride = 256;  dstStride = 1024; gxn = 8;  }
    int n0 = (ti % gxn) * 32, k0 = (ti / gxn) * 32;

    int tx = threadIdx.x & 31, ty = threadIdx.x >> 5;
    for (int i = ty; i < 32; i += 8)
      tile[i][tx] = src[(i64)(k0 + i) * srcStride + n0 + tx];
    __syncthreads();
    for (int i = ty; i < 32; i += 8)
      dst[(i64)(n0 + i) * dstStride + k0 + tx] = f2bf(tile[tx][i]);
    return;
  }

  // input transposes: 32 k-rows x 128 p-cols per tile; float4 reads
  {
    int t = blk - 10646;
    const float* in;
    u16* outp;
    int K, P, gx, ti;
    if (t < 1024)      { ti = t;        in = in0; outp = a0; K = 512;  P = 4096; gx = 32; }
    else if (t < 1536) { ti = t - 1024; in = in1; outp = a1; K = 1024; P = 1024; gx = 8;  }
    else               { ti = t - 1536; in = in2; outp = a2; K = 2048; P = 256;  gx = 2;  }
    int gy = K >> 5;
    int b = ti / (gx * gy);
    int rem = ti - b * gx * gy;
    int p0 = (rem % gx) * 128, k0 = (rem / gx) * 32;
    const float* ib = in + (i64)b * K * P;

    int tx = threadIdx.x & 31, ty = threadIdx.x >> 5;
    for (int i = ty; i < 32; i += 8) {
      float4 v = *(const float4*)(ib + (i64)(k0 + i) * P + p0 + tx * 4);
      tile[i][tx * 4 + 0] = v.x;
      tile[i][tx * 4 + 1] = v.y;
      tile[i][tx * 4 + 2] = v.z;
      tile[i][tx * 4 + 3] = v.w;
    }
    __syncthreads();
    int tk = threadIdx.x & 7, pr = threadIdx.x >> 3;
    for (int it = 0; it < 4; it++) {
      int p = pr + it * 32;
      ushort4 o;
      o.x = f2bf(tile[tk * 4 + 0][p]);
      o.y = f2bf(tile[tk * 4 + 1][p]);
      o.z = f2bf(tile[tk * 4 + 2][p]);
      o.w = f2bf(tile[tk * 4 + 3][p]);
      *(ushort4*)(outp + ((i64)b * P + p0 + p) * K + k0 + tk * 4) = o;
    }
  }
}

// ---------------- fused: level-2 split-K reduce (512 blk) + conv0 im2col ---
__global__ void red_im2col_k(const float* __restrict__ part,
    float* __restrict__ C, const float* __restrict__ bias, i64 bCz,
    const float* __restrict__ in2, u16* __restrict__ colout)
{
  int t = blockIdx.x;
  if (t < 512) {
    int idx = t * 256 + threadIdx.x;
    int m = idx >> 8, n = idx & 255;
    float v = bias[n];
    for (int ks = 0; ks < 4; ks++) v += part[((i64)ks * 512 + m) * 256 + n];
    C[(i64)(m >> 8) * bCz + (i64)(m & 255) * 256 + n] = v;
    return;
  }
  i64 o = (i64)(t - 512) * 256 + threadIdx.x;
  const int Kk = 18432, hw = 64;
  int k = (int)(o % Kk);
  int m = (int)(o / Kk);
  int b = m / hw, pix = m - b * hw;
  int oy = pix >> 3, ox = pix & 7;
  int ci = k / 9, r = k - ci * 9;
  int ky = r / 3, kx = r - ky * 3;
  int iy = oy * 2 - 1 + ky, ix = ox * 2 - 1 + kx;
  float v = 0.f;
  if (iy >= 0 && iy < 16 && ix >= 0 && ix < 16)
    v = in2[(((i64)b * 2048 + ci) * 16 + iy) * 16 + ix];
  colout[o] = f2bf(v);
}

__global__ void im2col_bf16_k(const float* __restrict__ in, u16* __restrict__ out,
    int Cin, int Hin, int Win, int Ho, int Wo)
{
  int Kk = Cin * 9;
  i64 total = (i64)2 * Ho * Wo * Kk;
  i64 o = (i64)blockIdx.x * 256 + threadIdx.x;
  if (o >= total) return;
  int k = (int)(o % Kk);
  int m = (int)(o / Kk);
  int hw = Ho * Wo;
  int b = m / hw, pix = m - b * hw;
  int oy = pix / Wo, ox = pix - oy * Wo;
  int ci = k / 9, r = k - ci * 9;
  int ky = r / 3, kx = r - ky * 3;
  int iy = oy * 2 - 1 + ky, ix = ox * 2 - 1 + kx;
  float v = 0.f;
  if (iy >= 0 && iy < Hin && ix >= 0 && ix < Win)
    v = in[(((i64)b * Cin + ci) * Hin + iy) * Win + ix];
  out[o] = f2bf(v);
}

__global__ void gn_relu_k(const float* __restrict__ feats, float* __restrict__ y,
    const float* __restrict__ g, const float* __restrict__ bt)
{
  int grp = blockIdx.x, b = blockIdx.y;
  int tid = threadIdx.x;
  const float* fb = feats + ((i64)b * NTOK + 5376) * 256 + grp * 32;
  float s = 0.f, ss = 0.f;
  for (int i = tid; i < 2048; i += 256) {
    int cl = i >> 6, p = i & 63;
    float v = fb[(i64)p * 256 + cl];
    s += v; ss += v * v;
  }
  __shared__ float sb[4], ssb[4];
#pragma unroll
  for (int o = 32; o > 0; o >>= 1) { s += __shfl_down(s, o); ss += __shfl_down(ss, o); }
  int wv = tid >> 6;
  if ((tid & 63) == 0) { sb[wv] = s; ssb[wv] = ss; }
  __syncthreads();
  float ts = sb[0] + sb[1] + sb[2] + sb[3];
  float tss = ssb[0] + ssb[1] + ssb[2] + ssb[3];
  float mean = ts * (1.f / 2048.f);
  float rs = rsqrtf(tss * (1.f / 2048.f) - mean * mean + 1e-5f);
  for (int i = tid; i < 2048; i += 256) {
    int cl = i >> 6, p = i & 63;
    int c = grp * 32 + cl;
    float v = (fb[(i64)p * 256 + cl] - mean) * rs * g[c] + bt[c];
    y[((i64)b * 256 + c) * 64 + p] = fmaxf(v, 0.f);
  }
}

__global__ __launch_bounds__(256) void ln_k(const float* __restrict__ x,
    u16* __restrict__ y, const float* __restrict__ g, const float* __restrict__ bt,
    int rows)
{
  int row = blockIdx.x * 4 + (threadIdx.x >> 6);
  if (row >= rows) return;
  int lane = threadIdx.x & 63;
  float4 v = ((const float4*)(x + (i64)row * 256))[lane];
  float s = v.x + v.y + v.z + v.w;
  float ss = v.x * v.x + v.y * v.y + v.z * v.z + v.w * v.w;
#pragma unroll
  for (int o = 32; o > 0; o >>= 1) { s += __shfl_down(s, o); ss += __shfl_down(ss, o); }
  s = __shfl(s, 0);
  ss = __shfl(ss, 0);
  float mean = s * (1.f / 256.f);
  float rs = rsqrtf(ss * (1.f / 256.f) - mean * mean + 1e-5f);
  float4 gg = ((const float4*)g)[lane];
  float4 bb = ((const float4*)bt)[lane];
  ushort4 o4;
  o4.x = f2bf((v.x - mean) * rs * gg.x + bb.x);
  o4.y = f2bf((v.y - mean) * rs * gg.y + bb.y);
  o4.z = f2bf((v.z - mean) * rs * gg.z + bb.z);
  o4.w = f2bf((v.w - mean) * rs * gg.w + bb.w);
  ((ushort4*)(y + (i64)row * 256))[lane] = o4;
}

// deformable sampling v5 (known-good)
__global__ __launch_bounds__(256) void dsample_k(
    const u16* __restrict__ val, const u16* __restrict__ off,
    const u16* __restrict__ att, u16* __restrict__ out)
{
  const int FH[5] = {64, 32, 16, 8, 4};
  const int ST[5] = {0, 4096, 5120, 5376, 5440};
  int bid = blockIdx.x;
  int chunk = (bid & 7) * 86 + (bid >> 3);
  if (chunk >= 682) return;
  int lane = threadIdx.x & 63;
  int half = lane >> 5;
  int l32 = lane & 31;
  int t = chunk * 8 + ((threadIdx.x >> 6) << 1) + half;
  int b = blockIdx.y;
  int h = l32 >> 2, d4 = l32 & 3;

  int lv;
  if (t < 4096)      lv = 0;
  else if (t < 5120) lv = 1;
  else if (t < 5376) lv = 2;
  else if (t < 5440) lv = 3;
  else               lv = 4;
  int loc = t - ST[lv];
  int sh = 6 - lv;
  int py = loc >> sh, px = loc - (py << sh);
  float inv = 1.f / (float)FH[lv];
  float prx = (px + 0.5f) * inv, pry = (py + 0.5f) * inv;
  i64 bt = (i64)b * NTOK + t;
  const u16* offp = off + bt * 320 + h * 40;
  const u16* attp = att + bt * 160 + h * 20;
  const u16* vbase = val + ((i64)b * NTOK) * 256 + h * 32 + d4 * 8;

  float own_a[5], own_fx[5], own_fy[5];
  int own_pk[5];
  float mx = -1e30f;
#pragma unroll
  for (int j = 0; j < 5; j++) {
    float lg = bf2f(attp[d4 + 4 * j]);
    own_a[j] = lg;
    mx = fmaxf(mx, lg);
  }
  mx = fmaxf(mx, __shfl_xor(mx, 1));
  mx = fmaxf(mx, __shfl_xor(mx, 2));
  float sum = 0.f;
#pragma unroll
  for (int j = 0; j < 5; j++) {
    float e = __expf(own_a[j] - mx);
    own_a[j] = e;
    sum += e;
  }
  sum += __shfl_xor(sum, 1);
  sum += __shfl_xor(sum, 2);
  float rinv = 1.f / sum;
#pragma unroll
  for (int j = 0; j < 5; j++) {
    int p = d4 + 4 * j;
    own_a[j] *= rinv;
    unsigned opk = *(const unsigned*)(offp + 2 * p);
    float ox = bf2f((u16)(opk & 0xFFFF));
    float oy = bf2f((u16)(opk >> 16));
    float sff = (float)(64 >> j);
    float xx = prx * sff + ox - 0.5f;
    float yy = pry * sff + oy - 0.5f;
    float xf = floorf(xx), yf = floorf(yy);
    own_fx[j] = xx - xf;
    own_fy[j] = yy - yf;
    own_pk[j] = (((int)yf) << 16) | (((int)xf) & 0xFFFF);
  }

  float acc[8] = {0.f, 0.f, 0.f, 0.f, 0.f, 0.f, 0.f, 0.f};
#pragma unroll
  for (int p = 0; p < 20; p++) {
    const int j = p >> 2;
    const int sf = FH[j], st = ST[j];
    int src = (half << 5) | (h << 2) | (p & 3);
    float wa = __shfl(own_a[j], src);
    float fx = __shfl(own_fx[j], src);
    float fy = __shfl(own_fy[j], src);
    int pk = __shfl(own_pk[j], src);
    int x0 = (pk << 16) >> 16;
    int y0 = pk >> 16;
    float gx0 = wa - wa * fx, gx1 = wa * fx;
    float w00 = gx0 - gx0 * fy, w01 = gx0 * fy;
    float w10 = gx1 - gx1 * fy, w11 = gx1 * fy;
    bool xin0 = (x0 >= 0) & (x0 < sf), xin1 = (x0 + 1 >= 0) & (x0 + 1 < sf);
    bool yin0 = (y0 >= 0) & (y0 < sf), yin1 = (y0 + 1 >= 0) & (y0 + 1 < sf);
    int ibase = st + y0 * sf + x0;
#define FMA8(W, IDX) { \
      us8 v = *(const us8*)(vbase + (i64)(IDX) * 256); \
      acc[0] = fmaf(W, bf2f(v[0]), acc[0]); acc[1] = fmaf(W, bf2f(v[1]), acc[1]); \
      acc[2] = fmaf(W, bf2f(v[2]), acc[2]); acc[3] = fmaf(W, bf2f(v[3]), acc[3]); \
      acc[4] = fmaf(W, bf2f(v[4]), acc[4]); acc[5] = fmaf(W, bf2f(v[5]), acc[5]); \
      acc[6] = fmaf(W, bf2f(v[6]), acc[6]); acc[7] = fmaf(W, bf2f(v[7]), acc[7]); }
    if (xin0 & yin0) FMA8(w00, ibase);
    if (xin1 & yin0) FMA8(w10, ibase + 1);
    if (xin0 & yin1) FMA8(w01, ibase + sf);
    if (xin1 & yin1) FMA8(w11, ibase + sf + 1);
#undef FMA8
  }
  us8 o;
#pragma unroll
  for (int i = 0; i < 8; i++) o[i] = f2bf(acc[i]);
  *(us8*)(out + ((bt * 8 + h) * 32 + d4 * 8)) = o;
}

// all 5 levels in one dispatch
__global__ __launch_bounds__(256) void untranspose_all_k(
    const float* __restrict__ feats, float* __restrict__ out)
{
  int u = blockIdx.x;
  int pt0, start, S; i64 ooff;
  if (u < 128)      { pt0 = u;       start = 0;    S = 4096; ooff = 0; }
  else if (u < 160) { pt0 = u - 128; start = 4096; S = 1024; ooff = 2097152; }
  else if (u < 168) { pt0 = u - 160; start = 5120; S = 256;  ooff = 2621440; }
  else if (u < 170) { pt0 = u - 168; start = 5376; S = 64;   ooff = 2752512; }
  else              { pt0 = 0;       start = 5440; S = 16;   ooff = 2785280; }
  __shared__ float tile[32][33];
  int pt = pt0 * 32, ct = blockIdx.y * 32, b = blockIdx.z;
  int tx = threadIdx.x & 31, ty = threadIdx.x >> 5;
  for (int i = ty; i < 32; i += 8) {
    int p = pt + i;
    tile[i][tx] = (p < S) ? feats[((i64)b * NTOK + start + p) * 256 + ct + tx] : 0.f;
  }
  __syncthreads();
  for (int i = ty; i < 32; i += 8) {
    int c = ct + i, p = pt + tx;
    if (p < S) out[ooff + ((i64)b * 256 + c) * S + p] = tile[tx][i];
  }
}

extern "C" void kernel_launch(void* const* d_in, const int* in_sizes, int n_in,
                              void* d_out, int out_size, void* d_ws, size_t ws_size,
                              hipStream_t stream)
{
  const float* in0  = (const float*)d_in[0];
  const float* in1  = (const float*)d_in[1];
  const float* in2  = (const float*)d_in[2];
  const float* pw0  = (const float*)d_in[3];
  const float* pb0  = (const float*)d_in[4];
  const float* pw1  = (const float*)d_in[5];
  const float* pb1  = (const float*)d_in[6];
  const float* pw2  = (const float*)d_in[7];
  const float* pb2  = (const float*)d_in[8];
  const float* buw0 = (const float*)d_in[9];
  const float* bub0 = (const float*)d_in[10];
  const float* gng  = (const float*)d_in[11];
  const float* gnb  = (const float*)d_in[12];
  const float* buw1 = (const float*)d_in[13];
  const float* bub1 = (const float*)d_in[14];
  const float* ln1g = (const float*)d_in[15];
  const float* ln1b = (const float*)d_in[16];
  const float* woff = (const float*)d_in[17];
  const float* boff = (const float*)d_in[18];
  const float* watt = (const float*)d_in[19];
  const float* batt = (const float*)d_in[20];
  const float* wval = (const float*)d_in[21];
  const float* bval = (const float*)d_in[22];
  const float* wout = (const float*)d_in[23];
  const float* bout = (const float*)d_in[24];
  const float* ln2g = (const float*)d_in[25];
  const float* ln2b = (const float*)d_in[26];
  const float* w1   = (const float*)d_in[27];
  const float* b1   = (const float*)d_in[28];
  const float* w2   = (const float*)d_in[29];
  const float* b2   = (const float*)d_in[30];
  float* out = (float*)d_out;

  const i64 TC = (i64)NTOK * 256;

  // ---- ws layout (f32 units) ----
  float* ws    = (float*)d_ws;
  float* feats = ws;                               // 2,793,472
  u16*   qb    = (u16*)(feats + 2793472);          // 11008x256 bf16
  u16*   valb  = qb + 2818048;
  u16*   sampb = valb + 2818048;
  float* U     = (float*)(sampb + 2818048);        // union region: 5,637,120 f32
  u16*   off16 = (u16*)U;                          // [10912][320] bf16
  u16*   att16 = off16 + 3491840;                  // [10912][160] bf16
  u16*   abuf0 = (u16*)U;                          // in0 A: 4,194,304 u16
  u16*   abuf1 = abuf0 + 4194304;                  // in1 A: 2,097,152 u16
  u16*   abuf2 = abuf1 + 2097152;                  // in2 A: 1,048,576 u16
  float* part  = U + 3670016;                      // split-K partials (<=524,288 f32)
  u16*   wb    = (u16*)(U + 5637120);              // 10,944,512 bf16
  float* bqkv  = (float*)(wb + 10944512);          // 4,608 f32
  float* m4gn  = bqkv + 4608;                      // 32,768 f32

  auto mg64 = [&](dim3 grid, const u16* A, const u16* B, int K,
                  float* C, float* C2, u16* C16, i64 sCm, const float* bias,
                  int relu, int addres, int qkv, int M, int N, int mbsh, i64 bCz, int KS) {
    mgemm_k<64><<<grid, dim3(256), 0, stream>>>(A, B, K, C, C2, C16, sCm, bias,
        relu, addres, qkv, M, N, mbsh, bCz, KS, part);
  };

  // ---- all conversions + input transposes in ONE dispatch ----
  cvt_mega_k<<<dim3(12438), dim3(256), 0, stream>>>(
      pw0, pw1, pw2, buw0, buw1, woff, watt, wval, wout, w1, w2,
      boff, batt, bval, in0, in1, in2, wb, bqkv, abuf0, abuf1, abuf2);

  // ---- projection GEMMs ----
  mg64(dim3(64, 4, 1), abuf0, wb, 512, feats, nullptr, nullptr, 256, pb0, 0, 0, 0,
       8192, 256, 12, TC, 1);
  mg64(dim3(16, 4, 1), abuf1, wb + 131072, 1024, feats + (i64)4096 * 256, nullptr,
       nullptr, 256, pb1, 0, 0, 0, 2048, 256, 10, TC, 1);
  mg64(dim3(4, 4, 4), abuf2, wb + 393216, 2048, nullptr, nullptr, nullptr, 256,
       nullptr, 0, 0, 0, 512, 256, 8, 0, 4);
  red_im2col_k<<<dim3(512 + 9216), dim3(256), 0, stream>>>(
      part, feats + (i64)5120 * 256, pb2, TC, in2, abuf0);

  // ---- bottom-up conv0 GEMM ----
  mg64(dim3(1, 4, 16), abuf0, wb + 917504, 18432, nullptr, nullptr, nullptr, 256,
       nullptr, 0, 0, 0, 128, 256, 6, 0, 16);
  reduce_k<<<dim3(128), dim3(256), 0, stream>>>(part, feats + (i64)5376 * 256, bub0,
      6, TC, 256, 128, 256, 16);

  // ---- GN+ReLU, bottom-up conv1 ----
  gn_relu_k<<<dim3(8, 2), dim3(256), 0, stream>>>(feats, m4gn, gng, gnb);
  im2col_bf16_k<<<dim3(288), dim3(256), 0, stream>>>(m4gn, abuf0, 256, 8, 8, 4, 4);
  mg64(dim3(1, 4, 4), abuf0, wb + 5636096, 2304, nullptr, nullptr, nullptr, 256,
       nullptr, 0, 0, 0, 32, 256, 4, 0, 4);
  reduce_k<<<dim3(32), dim3(256), 0, stream>>>(part, feats + (i64)5440 * 256, bub1,
      4, TC, 256, 32, 256, 4);

  // ---- 6 transformer layers ----
  for (int i = 0; i < NLAYERS; i++) {
    const u16* wbL = wb + 6225920 + (i64)i * 786432;
    ln_k<<<dim3(2728), dim3(256), 0, stream>>>(feats, qb,
        ln1g + (i64)i * 256, ln1b + (i64)i * 256, BNROWS);
    mg64(dim3(86, 12, 1), qb, wbL, 256, (float*)off16, (float*)att16, valb, 0,
         bqkv + (i64)i * 768, 0, 0, 1, BNROWS, 768, 14, 0, 1);
    dsample_k<<<dim3(688, 2), dim3(256), 0, stream>>>(valb, off16, att16, sampb);
    mg64(dim3(86, 4, 1), sampb, wbL + 196608, 256, feats, nullptr, nullptr, 256,
         bout + (i64)i * 256, 0, 1, 0, BNROWS, 256, 14, 0, 1);
    ffn_fused_k<<<dim3(171), dim3(512), 0, stream>>>(feats, wbL + 262144,
        wbL + 524288, b1 + (i64)i * 1024, b2 + (i64)i * 256,
        ln2g + (i64)i * 256, ln2b + (i64)i * 256, BNROWS);
  }

  // ---- split into 5 level maps (one dispatch) ----
  untranspose_all_k<<<dim3(171, 8, 2), dim3(256), 0, stream>>>(feats, out);
  (void)in_sizes; (void)n_in; (void)out_size; (void)ws_size;
}

// Round 25
// 831.959 us; speedup vs baseline: 1.0791x; 1.0150x over previous
//
#include <hip/hip_runtime.h>
#include <cstdint>

typedef long long i64;
typedef unsigned short u16;
typedef __attribute__((ext_vector_type(8))) short short8;
typedef __attribute__((ext_vector_type(8))) unsigned short us8;
typedef __attribute__((ext_vector_type(4))) float f32x4;

#define NTOK 5456
#define BNROWS 10912
#define NLAYERS 6

__device__ __forceinline__ u16 f2bf(float f) {
  unsigned u = __float_as_uint(f);
  return (u16)((u + 0x7FFFu + ((u >> 16) & 1u)) >> 16);
}
__device__ __forceinline__ float bf2f(u16 h) {
  return __uint_as_float(((unsigned)h) << 16);
}

// ---------------- bf16 MFMA GEMM, 2-phase double-buffered ----------------
template<int BNT>
__global__ __launch_bounds__(256) void mgemm_k(
    const u16* __restrict__ A, const u16* __restrict__ B, int K,
    float* __restrict__ C, float* __restrict__ C2, u16* __restrict__ C16, i64 sCm,
    const float* __restrict__ bias, int relu, int addres, int qkv,
    int M, int N, int mbsh, i64 bCz,
    int KS, float* __restrict__ part)
{
  constexpr int NW = BNT / 32;
  __shared__ u16 Asm[2][128 * 64];
  __shared__ u16 Bsm[2][BNT * 64];
  int tid = threadIdx.x;

  int bx = blockIdx.x, by = blockIdx.y;
  int gx = gridDim.x, gy = gridDim.y;
  int nwg = gx * gy;
  if (KS == 1 && nwg >= 16) {
    int lin = bx + gx * by;
    int xcd = lin & 7, k = lin >> 3;
    int q = nwg >> 3, r = nwg & 7;
    int f = (xcd < r) ? (xcd * (q + 1) + k) : (r * (q + 1) + (xcd - r) * q + k);
    bx = f / gy;
    by = f - bx * gy;
  }
  int m0 = bx * 128, n0 = by * BNT;

  int ks = blockIdx.z;
  int Kc = K / KS;
  int k0 = ks * Kc;
  int lane = tid & 63, w = tid >> 6;
  int wr = w >> 1, wc = w & 1;
  int r16 = lane & 15, g = lane >> 4;

  f32x4 acc[4][NW];
#pragma unroll
  for (int mi = 0; mi < 4; mi++)
#pragma unroll
    for (int nj = 0; nj < NW; nj++) acc[mi][nj] = (f32x4){0.f, 0.f, 0.f, 0.f};

  const u16* Ag = A + (i64)m0 * K + k0;
  const u16* Bg = B + (i64)n0 * K + k0;
  int nt = Kc >> 6;

  auto stage = [&](int buf, int kt) {
#pragma unroll
    for (int r = 0; r < 4; r++) {
      int s = r * 256 + tid;
      int row = s >> 3, c = s & 7;
      int cs = ((c ^ (row & 7)) << 3);
      __builtin_amdgcn_global_load_lds(
          (const __attribute__((address_space(1))) void*)(Ag + (i64)row * K + kt + cs),
          (__attribute__((address_space(3))) void*)(&Asm[buf][(r * 256 + (w << 6)) << 3]),
          16, 0, 0);
    }
#pragma unroll
    for (int r = 0; r < NW; r++) {
      int s = r * 256 + tid;
      int row = s >> 3, c = s & 7;
      int cs = ((c ^ (row & 7)) << 3);
      __builtin_amdgcn_global_load_lds(
          (const __attribute__((address_space(1))) void*)(Bg + (i64)row * K + kt + cs),
          (__attribute__((address_space(3))) void*)(&Bsm[buf][(r * 256 + (w << 6)) << 3]),
          16, 0, 0);
    }
  };

  stage(0, 0);
  __syncthreads();
  for (int t = 0; t < nt; t++) {
    int cur = t & 1;
    if (t + 1 < nt) stage(cur ^ 1, (t + 1) << 6);
#pragma unroll
    for (int h = 0; h < 2; h++) {
      short8 av[4], bv[NW];
#pragma unroll
      for (int mi = 0; mi < 4; mi++) {
        int row = wr * 64 + mi * 16 + r16;
        av[mi] = *(const short8*)&Asm[cur][row * 64 + ((((h << 2) + g) ^ (row & 7)) << 3)];
      }
#pragma unroll
      for (int nj = 0; nj < NW; nj++) {
        int row = wc * (NW * 16) + nj * 16 + r16;
        bv[nj] = *(const short8*)&Bsm[cur][row * 64 + ((((h << 2) + g) ^ (row & 7)) << 3)];
      }
#pragma unroll
      for (int mi = 0; mi < 4; mi++)
#pragma unroll
        for (int nj = 0; nj < NW; nj++)
          acc[mi][nj] = __builtin_amdgcn_mfma_f32_16x16x32_bf16(
              av[mi], bv[nj], acc[mi][nj], 0, 0, 0);
    }
    __syncthreads();
  }

  if (KS > 1) {
#pragma unroll
    for (int mi = 0; mi < 4; mi++)
#pragma unroll
      for (int nj = 0; nj < NW; nj++)
#pragma unroll
        for (int r = 0; r < 4; r++) {
          int grow = m0 + wr * 64 + mi * 16 + g * 4 + r;
          int gcol = n0 + wc * (NW * 16) + nj * 16 + r16;
          if (grow < M) part[((i64)ks * M + grow) * N + gcol] = acc[mi][nj][r];
        }
  } else if (qkv) {
    u16* off16 = (u16*)C;
    u16* att16 = (u16*)C2;
#pragma unroll
    for (int mi = 0; mi < 4; mi++)
#pragma unroll
      for (int nj = 0; nj < NW; nj++)
#pragma unroll
        for (int r = 0; r < 4; r++) {
          int grow = m0 + wr * 64 + mi * 16 + g * 4 + r;
          int gcol = n0 + wc * (NW * 16) + nj * 16 + r16;
          if (grow < M) {
            float v = acc[mi][nj][r] + bias[gcol];
            if (gcol < 320) off16[(i64)grow * 320 + gcol] = f2bf(v);
            else if (gcol < 480) att16[(i64)grow * 160 + (gcol - 320)] = f2bf(v);
            else if (gcol < 736) C16[(i64)grow * 256 + (gcol - 480)] = f2bf(v);
          }
        }
  } else {
    float bv[NW];
    int gc0 = n0 + wc * (NW * 16) + r16;
#pragma unroll
    for (int nj = 0; nj < NW; nj++)
      bv[nj] = bias ? bias[gc0 + nj * 16] : 0.f;
    int mask = (1 << mbsh) - 1;
#pragma unroll
    for (int mi = 0; mi < 4; mi++) {
#pragma unroll
      for (int r = 0; r < 4; r++) {
        int grow = m0 + wr * 64 + mi * 16 + g * 4 + r;
        if (grow >= M) continue;
        i64 rowb = (i64)(grow >> mbsh) * bCz + (i64)(grow & mask) * sCm;
#pragma unroll
        for (int nj = 0; nj < NW; nj++) {
          int gcol = gc0 + nj * 16;
          if (gcol >= N) continue;
          float v = acc[mi][nj][r] + bv[nj];
          if (relu) v = fmaxf(v, 0.f);
          i64 ci = rowb + gcol;
          if (C16) C16[ci] = f2bf(v);
          else {
            if (addres) v += C[ci];
            C[ci] = v;
          }
        }
      }
    }
  }
}

// ---------------- fused LN2+FFN v3 + next-layer LN1 epilogue ---------------
__global__ __launch_bounds__(512, 1) void ffn_fused_k(
    float* __restrict__ feats, const u16* __restrict__ w1n,
    const u16* __restrict__ w2n, const float* __restrict__ b1,
    const float* __restrict__ b2, const float* __restrict__ lng,
    const float* __restrict__ lnb, int M,
    u16* __restrict__ qbo, const float* __restrict__ nlg,
    const float* __restrict__ nlb)
{
  __shared__ u16 B1s[2][64 * 256];
  __shared__ u16 B2s[2][256 * 64];
  __shared__ u16 Hs[64 * 88];
  __shared__ float b1s[1024];
  u16* As = &B1s[1][0];

  int tid = threadIdx.x;
  int lane = tid & 63, w = tid >> 6;
  int wr = w >> 1, wc = w & 1;
  int r16 = lane & 15, g = lane >> 4;
  int m0 = blockIdx.x * 64;

  auto stageW = [&](int buf, int ch) {
#pragma unroll
    for (int r = 0; r < 4; r++) {
      int s = r * 512 + tid;
      int row = s >> 5, c = s & 31;
      int cs = ((c ^ (row & 7)) << 3);
      __builtin_amdgcn_global_load_lds(
          (const __attribute__((address_space(1))) void*)(w1n + (i64)(ch * 64 + row) * 256 + cs),
          (__attribute__((address_space(3))) void*)(&B1s[buf][(r * 512 + (w << 6)) << 3]),
          16, 0, 0);
    }
#pragma unroll
    for (int r = 0; r < 4; r++) {
      int s = r * 512 + tid;
      int row = s >> 3, c = s & 7;
      int cs = ((c ^ (row & 7)) << 3);
      __builtin_amdgcn_global_load_lds(
          (const __attribute__((address_space(1))) void*)(w2n + (i64)row * 1024 + ch * 64 + cs),
          (__attribute__((address_space(3))) void*)(&B2s[buf][(r * 512 + (w << 6)) << 3]),
          16, 0, 0);
    }
  };

  stageW(0, 0);
  for (int i = tid; i < 1024; i += 512) b1s[i] = b1[i];

  // LN2 on rows m0..m0+63: 8 lanes per row, 32 cols each
  {
    int rw = tid >> 3, c0 = (tid & 7) * 32;
    const float* fr = feats + (i64)(m0 + rw) * 256 + c0;
    float4 x[8];
    float s = 0.f, ss = 0.f;
#pragma unroll
    for (int j = 0; j < 8; j++) {
      x[j] = ((const float4*)fr)[j];
      s += x[j].x + x[j].y + x[j].z + x[j].w;
      ss += x[j].x * x[j].x + x[j].y * x[j].y + x[j].z * x[j].z + x[j].w * x[j].w;
    }
#pragma unroll
    for (int o = 1; o <= 4; o <<= 1) { s += __shfl_xor(s, o); ss += __shfl_xor(ss, o); }
    float mean = s * (1.f / 256.f);
    float rs = rsqrtf(ss * (1.f / 256.f) - mean * mean + 1e-5f);
    const float4* gp = (const float4*)(lng + c0);
    const float4* bp = (const float4*)(lnb + c0);
#pragma unroll
    for (int j = 0; j < 8; j += 2) {
      float4 g0 = gp[j], g1 = gp[j + 1];
      float4 b0 = bp[j], b1_ = bp[j + 1];
      us8 o;
      o[0] = f2bf((x[j].x - mean) * rs * g0.x + b0.x);
      o[1] = f2bf((x[j].y - mean) * rs * g0.y + b0.y);
      o[2] = f2bf((x[j].z - mean) * rs * g0.z + b0.z);
      o[3] = f2bf((x[j].w - mean) * rs * g0.w + b0.w);
      o[4] = f2bf((x[j + 1].x - mean) * rs * g1.x + b1_.x);
      o[5] = f2bf((x[j + 1].y - mean) * rs * g1.y + b1_.y);
      o[6] = f2bf((x[j + 1].z - mean) * rs * g1.z + b1_.z);
      o[7] = f2bf((x[j + 1].w - mean) * rs * g1.w + b1_.w);
      int gr = (tid & 7) * 4 + (j >> 1);
      *(us8*)&As[rw * 256 + ((gr ^ (rw & 7)) << 3)] = o;
    }
  }
  __syncthreads();

  short8 av_all[8];
  {
    int row = wr * 16 + r16;
#pragma unroll
    for (int ks = 0; ks < 8; ks++)
      av_all[ks] = *(const short8*)&As[row * 256 + (((ks * 4 + g) ^ (row & 7)) << 3)];
  }
  __syncthreads();

  f32x4 acc2[8];
#pragma unroll
  for (int nj = 0; nj < 8; nj++) acc2[nj] = (f32x4){0.f, 0.f, 0.f, 0.f};

  int cur = 0;
  for (int ch = 0; ch < 16; ch++) {
    if (ch + 1 < 16) stageW(cur ^ 1, ch + 1);

    f32x4 acc1[2];
#pragma unroll
    for (int nj = 0; nj < 2; nj++) acc1[nj] = (f32x4){0.f, 0.f, 0.f, 0.f};
#pragma unroll
    for (int ks = 0; ks < 8; ks++) {
      short8 bv[2];
#pragma unroll
      for (int nj = 0; nj < 2; nj++) {
        int row = wc * 32 + nj * 16 + r16;
        bv[nj] = *(const short8*)&B1s[cur][row * 256 + (((ks * 4 + g) ^ (row & 7)) << 3)];
      }
#pragma unroll
      for (int nj = 0; nj < 2; nj++)
        acc1[nj] = __builtin_amdgcn_mfma_f32_16x16x32_bf16(
            av_all[ks], bv[nj], acc1[nj], 0, 0, 0);
    }
#pragma unroll
    for (int nj = 0; nj < 2; nj++)
#pragma unroll
      for (int r = 0; r < 4; r++) {
        int hr = wr * 16 + g * 4 + r;
        int hc = wc * 32 + nj * 16 + r16;
        float v = acc1[nj][r] + b1s[ch * 64 + hc];
        Hs[hr * 88 + hc] = f2bf(fmaxf(v, 0.f));
      }
    __syncthreads();

#pragma unroll
    for (int hh = 0; hh < 2; hh++) {
      short8 av2 = *(const short8*)&Hs[(wr * 16 + r16) * 88 + hh * 32 + g * 8];
      short8 bv2[8];
#pragma unroll
      for (int nj = 0; nj < 8; nj++) {
        int n = wc * 128 + nj * 16 + r16;
        bv2[nj] = *(const short8*)&B2s[cur][n * 64 + (((hh * 4 + g) ^ (n & 7)) << 3)];
      }
#pragma unroll
      for (int nj = 0; nj < 8; nj++)
        acc2[nj] = __builtin_amdgcn_mfma_f32_16x16x32_bf16(
            av2, bv2[nj], acc2[nj], 0, 0, 0);
    }
    __syncthreads();
    cur ^= 1;
  }

  // epilogue: write feats; optionally compute next-layer LN1 -> qbo (bf16).
  // b1s reused as reduction buffer red[64][4] = {sum0,ssq0,sum1,ssq1} per row.
  float* red = b1s;
  float vv[4][8];
#pragma unroll
  for (int r = 0; r < 4; r++) {
    int grow = m0 + wr * 16 + g * 4 + r;
    float s = 0.f, ss = 0.f;
    if (grow < M) {
#pragma unroll
      for (int nj = 0; nj < 8; nj++) {
        int col = wc * 128 + nj * 16 + r16;
        i64 ci = (i64)grow * 256 + col;
        float v = feats[ci] + acc2[nj][r] + b2[col];
        feats[ci] = v;
        vv[r][nj] = v;
        s += v;
        ss += v * v;
      }
    }
    if (qbo) {
#pragma unroll
      for (int o = 1; o <= 8; o <<= 1) { s += __shfl_xor(s, o); ss += __shfl_xor(ss, o); }
      if (r16 == 0) {
        int lr = wr * 16 + g * 4 + r;
        red[lr * 4 + wc * 2 + 0] = s;
        red[lr * 4 + wc * 2 + 1] = ss;
      }
    }
  }
  if (qbo) {
    __syncthreads();
#pragma unroll
    for (int r = 0; r < 4; r++) {
      int grow = m0 + wr * 16 + g * 4 + r;
      if (grow >= M) continue;
      int lr = wr * 16 + g * 4 + r;
      float s = red[lr * 4 + 0] + red[lr * 4 + 2];
      float ss = red[lr * 4 + 1] + red[lr * 4 + 3];
      float mean = s * (1.f / 256.f);
      float rs = rsqrtf(ss * (1.f / 256.f) - mean * mean + 1e-5f);
#pragma unroll
      for (int nj = 0; nj < 8; nj++) {
        int col = wc * 128 + nj * 16 + r16;
        qbo[(i64)grow * 256 + col] =
            f2bf((vv[r][nj] - mean) * rs * nlg[col] + nlb[col]);
      }
    }
  }
}

// reduce split-K fp32 partials (stride N); row map via shift/mask
__global__ void reduce_k(const float* __restrict__ part, float* __restrict__ C,
    const float* __restrict__ bias, int mbsh, i64 bCz, i64 sCm, int M, int N, int KS)
{
  int idx = blockIdx.x * 256 + threadIdx.x;
  if (idx >= M * N) return;
  int m = idx / N, n = idx - m * N;
  float v = bias ? bias[n] : 0.f;
  for (int ks = 0; ks < KS; ks++) v += part[((i64)ks * M + m) * N + n];
  C[(i64)(m >> mbsh) * bCz + (i64)(m & ((1 << mbsh) - 1)) * sCm + n] = v;
}

// ---------------- mega conversion (vectorized), ONE dispatch ---------------
// ranges: [0,6080) prologue float4 cvt | [6080,10646) layer transposes
// (761 x 6 flat) | [10646,12438) input transposes 32k x 128p tiles.
__global__ __launch_bounds__(256) void cvt_mega_k(
    const float* __restrict__ pw0, const float* __restrict__ pw1,
    const float* __restrict__ pw2, const float* __restrict__ buw0,
    const float* __restrict__ buw1,
    const float* __restrict__ woff, const float* __restrict__ watt,
    const float* __restrict__ wval, const float* __restrict__ wout,
    const float* __restrict__ w1, const float* __restrict__ w2,
    const float* __restrict__ boff, const float* __restrict__ batt,
    const float* __restrict__ bval,
    const float* __restrict__ in0, const float* __restrict__ in1,
    const float* __restrict__ in2,
    u16* __restrict__ wb, float* __restrict__ bq,
    u16* __restrict__ a0, u16* __restrict__ a1, u16* __restrict__ a2)
{
  __shared__ float tile[32][129];
  int blk = blockIdx.x;

  if (blk < 6080) {
    int idx = (blk * 256 + threadIdx.x) * 4;
    float4 v;
    if (idx < 131072) v = *(const float4*)(pw0 + idx);
    else if (idx < 393216) v = *(const float4*)(pw1 + idx - 131072);
    else if (idx < 917504) v = *(const float4*)(pw2 + idx - 393216);
    else if (idx < 5636096) v = *(const float4*)(buw0 + idx - 917504);
    else v = *(const float4*)(buw1 + idx - 5636096);
    ushort4 o;
    o.x = f2bf(v.x); o.y = f2bf(v.y); o.z = f2bf(v.z); o.w = f2bf(v.w);
    *(ushort4*)(wb + idx) = o;
    return;
  }

  if (blk < 10646) {
    int lb = blk - 6080;
    int L = lb / 761, t = lb - L * 761;
    u16* wbL = wb + 6225920 + (i64)L * 786432;

    if (t == 760) {
      for (int idx = threadIdx.x; idx < 8192; idx += 256)
        wbL[736 * 256 + idx] = 0;
      for (int n = threadIdx.x; n < 768; n += 256) {
        float v;
        if (n < 320) v = boff[(i64)L * 320 + n];
        else if (n < 480) v = batt[(i64)L * 160 + (n - 320)];
        else if (n < 736) v = bval[(i64)L * 256 + (n - 480)];
        else v = 0.f;
        bq[(i64)L * 768 + n] = v;
      }
      return;
    }

    const float* src;
    u16* dst;
    int srcStride, dstStride, gxn, ti;
    if (t < 80)       { ti = t;       src = woff + (i64)L * 81920;  dst = wbL;            srcStride = 320;  dstStride = 256;  gxn = 10; }
    else if (t < 120) { ti = t - 80;  src = watt + (i64)L * 40960;  dst = wbL + 320 * 256; srcStride = 160;  dstStride = 256;  gxn = 5;  }
    else if (t < 184) { ti = t - 120; src = wval + (i64)L * 65536;  dst = wbL + 480 * 256; srcStride = 256;  dstStride = 256;  gxn = 8;  }
    else if (t < 248) { ti = t - 184; src = wout + (i64)L * 65536;  dst = wbL + 196608;   srcStride = 256;  dstStride = 256;  gxn = 8;  }
    else if (t < 504) { ti = t - 248; src = w1 + (i64)L * 262144;   dst = wbL + 262144;   srcStride = 1024; dstStride = 256;  gxn = 32; }
    else              { ti = t - 504; src = w2 + (i64)L * 262144;   dst = wbL + 524288;   srcStride = 256;  dstStride = 1024; gxn = 8;  }
    int n0 = (ti % gxn) * 32, k0 = (ti / gxn) * 32;

    int tx = threadIdx.x & 31, ty = threadIdx.x >> 5;
    for (int i = ty; i < 32; i += 8)
      tile[i][tx] = src[(i64)(k0 + i) * srcStride + n0 + tx];
    __syncthreads();
    for (int i = ty; i < 32; i += 8)
      dst[(i64)(n0 + i) * dstStride + k0 + tx] = f2bf(tile[tx][i]);
    return;
  }

  // input transposes: 32 k-rows x 128 p-cols per tile; float4 reads
  {
    int t = blk - 10646;
    const float* in;
    u16* outp;
    int K, P, gx, ti;
    if (t < 1024)      { ti = t;        in = in0; outp = a0; K = 512;  P = 4096; gx = 32; }
    else if (t < 1536) { ti = t - 1024; in = in1; outp = a1; K = 1024; P = 1024; gx = 8;  }
    else               { ti = t - 1536; in = in2; outp = a2; K = 2048; P = 256;  gx = 2;  }
    int gy = K >> 5;
    int b = ti / (gx * gy);
    int rem = ti - b * gx * gy;
    int p0 = (rem % gx) * 128, k0 = (rem / gx) * 32;
    const float* ib = in + (i64)b * K * P;

    int tx = threadIdx.x & 31, ty = threadIdx.x >> 5;
    for (int i = ty; i < 32; i += 8) {
      float4 v = *(const float4*)(ib + (i64)(k0 + i) * P + p0 + tx * 4);
      tile[i][tx * 4 + 0] = v.x;
      tile[i][tx * 4 + 1] = v.y;
      tile[i][tx * 4 + 2] = v.z;
      tile[i][tx * 4 + 3] = v.w;
    }
    __syncthreads();
    int tk = threadIdx.x & 7, pr = threadIdx.x >> 3;
    for (int it = 0; it < 4; it++) {
      int p = pr + it * 32;
      ushort4 o;
      o.x = f2bf(tile[tk * 4 + 0][p]);
      o.y = f2bf(tile[tk * 4 + 1][p]);
      o.z = f2bf(tile[tk * 4 + 2][p]);
      o.w = f2bf(tile[tk * 4 + 3][p]);
      *(ushort4*)(outp + ((i64)b * P + p0 + p) * K + k0 + tk * 4) = o;
    }
  }
}

// ---------------- fused: level-2 split-K reduce (512 blk) + conv0 im2col ---
__global__ void red_im2col_k(const float* __restrict__ part,
    float* __restrict__ C, const float* __restrict__ bias, i64 bCz,
    const float* __restrict__ in2, u16* __restrict__ colout)
{
  int t = blockIdx.x;
  if (t < 512) {
    int idx = t * 256 + threadIdx.x;
    int m = idx >> 8, n = idx & 255;
    float v = bias[n];
    for (int ks = 0; ks < 4; ks++) v += part[((i64)ks * 512 + m) * 256 + n];
    C[(i64)(m >> 8) * bCz + (i64)(m & 255) * 256 + n] = v;
    return;
  }
  i64 o = (i64)(t - 512) * 256 + threadIdx.x;
  const int Kk = 18432, hw = 64;
  int k = (int)(o % Kk);
  int m = (int)(o / Kk);
  int b = m / hw, pix = m - b * hw;
  int oy = pix >> 3, ox = pix & 7;
  int ci = k / 9, r = k - ci * 9;
  int ky = r / 3, kx = r - ky * 3;
  int iy = oy * 2 - 1 + ky, ix = ox * 2 - 1 + kx;
  float v = 0.f;
  if (iy >= 0 && iy < 16 && ix >= 0 && ix < 16)
    v = in2[(((i64)b * 2048 + ci) * 16 + iy) * 16 + ix];
  colout[o] = f2bf(v);
}

__global__ void im2col_bf16_k(const float* __restrict__ in, u16* __restrict__ out,
    int Cin, int Hin, int Win, int Ho, int Wo)
{
  int Kk = Cin * 9;
  i64 total = (i64)2 * Ho * Wo * Kk;
  i64 o = (i64)blockIdx.x * 256 + threadIdx.x;
  if (o >= total) return;
  int k = (int)(o % Kk);
  int m = (int)(o / Kk);
  int hw = Ho * Wo;
  int b = m / hw, pix = m - b * hw;
  int oy = pix / Wo, ox = pix - oy * Wo;
  int ci = k / 9, r = k - ci * 9;
  int ky = r / 3, kx = r - ky * 3;
  int iy = oy * 2 - 1 + ky, ix = ox * 2 - 1 + kx;
  float v = 0.f;
  if (iy >= 0 && iy < Hin && ix >= 0 && ix < Win)
    v = in[(((i64)b * Cin + ci) * Hin + iy) * Win + ix];
  out[o] = f2bf(v);
}

__global__ void gn_relu_k(const float* __restrict__ feats, float* __restrict__ y,
    const float* __restrict__ g, const float* __restrict__ bt)
{
  int grp = blockIdx.x, b = blockIdx.y;
  int tid = threadIdx.x;
  const float* fb = feats + ((i64)b * NTOK + 5376) * 256 + grp * 32;
  float s = 0.f, ss = 0.f;
  for (int i = tid; i < 2048; i += 256) {
    int cl = i >> 6, p = i & 63;
    float v = fb[(i64)p * 256 + cl];
    s += v; ss += v * v;
  }
  __shared__ float sb[4], ssb[4];
#pragma unroll
  for (int o = 32; o > 0; o >>= 1) { s += __shfl_down(s, o); ss += __shfl_down(ss, o); }
  int wv = tid >> 6;
  if ((tid & 63) == 0) { sb[wv] = s; ssb[wv] = ss; }
  __syncthreads();
  float ts = sb[0] + sb[1] + sb[2] + sb[3];
  float tss = ssb[0] + ssb[1] + ssb[2] + ssb[3];
  float mean = ts * (1.f / 2048.f);
  float rs = rsqrtf(tss * (1.f / 2048.f) - mean * mean + 1e-5f);
  for (int i = tid; i < 2048; i += 256) {
    int cl = i >> 6, p = i & 63;
    int c = grp * 32 + cl;
    float v = (fb[(i64)p * 256 + cl] - mean) * rs * g[c] + bt[c];
    y[((i64)b * 256 + c) * 64 + p] = fmaxf(v, 0.f);
  }
}

__global__ __launch_bounds__(256) void ln_k(const float* __restrict__ x,
    u16* __restrict__ y, const float* __restrict__ g, const float* __restrict__ bt,
    int rows)
{
  int row = blockIdx.x * 4 + (threadIdx.x >> 6);
  if (row >= rows) return;
  int lane = threadIdx.x & 63;
  float4 v = ((const float4*)(x + (i64)row * 256))[lane];
  float s = v.x + v.y + v.z + v.w;
  float ss = v.x * v.x + v.y * v.y + v.z * v.z + v.w * v.w;
#pragma unroll
  for (int o = 32; o > 0; o >>= 1) { s += __shfl_down(s, o); ss += __shfl_down(ss, o); }
  s = __shfl(s, 0);
  ss = __shfl(ss, 0);
  float mean = s * (1.f / 256.f);
  float rs = rsqrtf(ss * (1.f / 256.f) - mean * mean + 1e-5f);
  float4 gg = ((const float4*)g)[lane];
  float4 bb = ((const float4*)bt)[lane];
  ushort4 o4;
  o4.x = f2bf((v.x - mean) * rs * gg.x + bb.x);
  o4.y = f2bf((v.y - mean) * rs * gg.y + bb.y);
  o4.z = f2bf((v.z - mean) * rs * gg.z + bb.z);
  o4.w = f2bf((v.w - mean) * rs * gg.w + bb.w);
  ((ushort4*)(y + (i64)row * 256))[lane] = o4;
}

// deformable sampling v5 (known-good)
__global__ __launch_bounds__(256) void dsample_k(
    const u16* __restrict__ val, const u16* __restrict__ off,
    const u16* __restrict__ att, u16* __restrict__ out)
{
  const int FH[5] = {64, 32, 16, 8, 4};
  const int ST[5] = {0, 4096, 5120, 5376, 5440};
  int bid = blockIdx.x;
  int chunk = (bid & 7) * 86 + (bid >> 3);
  if (chunk >= 682) return;
  int lane = threadIdx.x & 63;
  int half = lane >> 5;
  int l32 = lane & 31;
  int t = chunk * 8 + ((threadIdx.x >> 6) << 1) + half;
  int b = blockIdx.y;
  int h = l32 >> 2, d4 = l32 & 3;

  int lv;
  if (t < 4096)      lv = 0;
  else if (t < 5120) lv = 1;
  else if (t < 5376) lv = 2;
  else if (t < 5440) lv = 3;
  else               lv = 4;
  int loc = t - ST[lv];
  int sh = 6 - lv;
  int py = loc >> sh, px = loc - (py << sh);
  float inv = 1.f / (float)FH[lv];
  float prx = (px + 0.5f) * inv, pry = (py + 0.5f) * inv;
  i64 bt = (i64)b * NTOK + t;
  const u16* offp = off + bt * 320 + h * 40;
  const u16* attp = att + bt * 160 + h * 20;
  const u16* vbase = val + ((i64)b * NTOK) * 256 + h * 32 + d4 * 8;

  float own_a[5], own_fx[5], own_fy[5];
  int own_pk[5];
  float mx = -1e30f;
#pragma unroll
  for (int j = 0; j < 5; j++) {
    float lg = bf2f(attp[d4 + 4 * j]);
    own_a[j] = lg;
    mx = fmaxf(mx, lg);
  }
  mx = fmaxf(mx, __shfl_xor(mx, 1));
  mx = fmaxf(mx, __shfl_xor(mx, 2));
  float sum = 0.f;
#pragma unroll
  for (int j = 0; j < 5; j++) {
    float e = __expf(own_a[j] - mx);
    own_a[j] = e;
    sum += e;
  }
  sum += __shfl_xor(sum, 1);
  sum += __shfl_xor(sum, 2);
  float rinv = 1.f / sum;
#pragma unroll
  for (int j = 0; j < 5; j++) {
    int p = d4 + 4 * j;
    own_a[j] *= rinv;
    unsigned opk = *(const unsigned*)(offp + 2 * p);
    float ox = bf2f((u16)(opk & 0xFFFF));
    float oy = bf2f((u16)(opk >> 16));
    float sff = (float)(64 >> j);
    float xx = prx * sff + ox - 0.5f;
    float yy = pry * sff + oy - 0.5f;
    float xf = floorf(xx), yf = floorf(yy);
    own_fx[j] = xx - xf;
    own_fy[j] = yy - yf;
    own_pk[j] = (((int)yf) << 16) | (((int)xf) & 0xFFFF);
  }

  float acc[8] = {0.f, 0.f, 0.f, 0.f, 0.f, 0.f, 0.f, 0.f};
#pragma unroll
  for (int p = 0; p < 20; p++) {
    const int j = p >> 2;
    const int sf = FH[j], st = ST[j];
    int src = (half << 5) | (h << 2) | (p & 3);
    float wa = __shfl(own_a[j], src);
    float fx = __shfl(own_fx[j], src);
    float fy = __shfl(own_fy[j], src);
    int pk = __shfl(own_pk[j], src);
    int x0 = (pk << 16) >> 16;
    int y0 = pk >> 16;
    float gx0 = wa - wa * fx, gx1 = wa * fx;
    float w00 = gx0 - gx0 * fy, w01 = gx0 * fy;
    float w10 = gx1 - gx1 * fy, w11 = gx1 * fy;
    bool xin0 = (x0 >= 0) & (x0 < sf), xin1 = (x0 + 1 >= 0) & (x0 + 1 < sf);
    bool yin0 = (y0 >= 0) & (y0 < sf), yin1 = (y0 + 1 >= 0) & (y0 + 1 < sf);
    int ibase = st + y0 * sf + x0;
#define FMA8(W, IDX) { \
      us8 v = *(const us8*)(vbase + (i64)(IDX) * 256); \
      acc[0] = fmaf(W, bf2f(v[0]), acc[0]); acc[1] = fmaf(W, bf2f(v[1]), acc[1]); \
      acc[2] = fmaf(W, bf2f(v[2]), acc[2]); acc[3] = fmaf(W, bf2f(v[3]), acc[3]); \
      acc[4] = fmaf(W, bf2f(v[4]), acc[4]); acc[5] = fmaf(W, bf2f(v[5]), acc[5]); \
      acc[6] = fmaf(W, bf2f(v[6]), acc[6]); acc[7] = fmaf(W, bf2f(v[7]), acc[7]); }
    if (xin0 & yin0) FMA8(w00, ibase);
    if (xin1 & yin0) FMA8(w10, ibase + 1);
    if (xin0 & yin1) FMA8(w01, ibase + sf);
    if (xin1 & yin1) FMA8(w11, ibase + sf + 1);
#undef FMA8
  }
  us8 o;
#pragma unroll
  for (int i = 0; i < 8; i++) o[i] = f2bf(acc[i]);
  *(us8*)(out + ((bt * 8 + h) * 32 + d4 * 8)) = o;
}

// all 5 levels in one dispatch
__global__ __launch_bounds__(256) void untranspose_all_k(
    const float* __restrict__ feats, float* __restrict__ out)
{
  int u = blockIdx.x;
  int pt0, start, S; i64 ooff;
  if (u < 128)      { pt0 = u;       start = 0;    S = 4096; ooff = 0; }
  else if (u < 160) { pt0 = u - 128; start = 4096; S = 1024; ooff = 2097152; }
  else if (u < 168) { pt0 = u - 160; start = 5120; S = 256;  ooff = 2621440; }
  else if (u < 170) { pt0 = u - 168; start = 5376; S = 64;   ooff = 2752512; }
  else              { pt0 = 0;       start = 5440; S = 16;   ooff = 2785280; }
  __shared__ float tile[32][33];
  int pt = pt0 * 32, ct = blockIdx.y * 32, b = blockIdx.z;
  int tx = threadIdx.x & 31, ty = threadIdx.x >> 5;
  for (int i = ty; i < 32; i += 8) {
    int p = pt + i;
    tile[i][tx] = (p < S) ? feats[((i64)b * NTOK + start + p) * 256 + ct + tx] : 0.f;
  }
  __syncthreads();
  for (int i = ty; i < 32; i += 8) {
    int c = ct + i, p = pt + tx;
    if (p < S) out[ooff + ((i64)b * 256 + c) * S + p] = tile[tx][i];
  }
}

extern "C" void kernel_launch(void* const* d_in, const int* in_sizes, int n_in,
                              void* d_out, int out_size, void* d_ws, size_t ws_size,
                              hipStream_t stream)
{
  const float* in0  = (const float*)d_in[0];
  const float* in1  = (const float*)d_in[1];
  const float* in2  = (const float*)d_in[2];
  const float* pw0  = (const float*)d_in[3];
  const float* pb0  = (const float*)d_in[4];
  const float* pw1  = (const float*)d_in[5];
  const float* pb1  = (const float*)d_in[6];
  const float* pw2  = (const float*)d_in[7];
  const float* pb2  = (const float*)d_in[8];
  const float* buw0 = (const float*)d_in[9];
  const float* bub0 = (const float*)d_in[10];
  const float* gng  = (const float*)d_in[11];
  const float* gnb  = (const float*)d_in[12];
  const float* buw1 = (const float*)d_in[13];
  const float* bub1 = (const float*)d_in[14];
  const float* ln1g = (const float*)d_in[15];
  const float* ln1b = (const float*)d_in[16];
  const float* woff = (const float*)d_in[17];
  const float* boff = (const float*)d_in[18];
  const float* watt = (const float*)d_in[19];
  const float* batt = (const float*)d_in[20];
  const float* wval = (const float*)d_in[21];
  const float* bval = (const float*)d_in[22];
  const float* wout = (const float*)d_in[23];
  const float* bout = (const float*)d_in[24];
  const float* ln2g = (const float*)d_in[25];
  const float* ln2b = (const float*)d_in[26];
  const float* w1   = (const float*)d_in[27];
  const float* b1   = (const float*)d_in[28];
  const float* w2   = (const float*)d_in[29];
  const float* b2   = (const float*)d_in[30];
  float* out = (float*)d_out;

  const i64 TC = (i64)NTOK * 256;

  // ---- ws layout (f32 units) ----
  float* ws    = (float*)d_ws;
  float* feats = ws;                               // 2,793,472
  u16*   qb    = (u16*)(feats + 2793472);          // 11008x256 bf16
  u16*   valb  = qb + 2818048;
  u16*   sampb = valb + 2818048;
  float* U     = (float*)(sampb + 2818048);        // union region: 5,637,120 f32
  u16*   off16 = (u16*)U;                          // [10912][320] bf16
  u16*   att16 = off16 + 3491840;                  // [10912][160] bf16
  u16*   abuf0 = (u16*)U;                          // in0 A: 4,194,304 u16
  u16*   abuf1 = abuf0 + 4194304;                  // in1 A: 2,097,152 u16
  u16*   abuf2 = abuf1 + 2097152;                  // in2 A: 1,048,576 u16
  float* part  = U + 3670016;                      // split-K partials (<=524,288 f32)
  u16*   wb    = (u16*)(U + 5637120);              // 10,944,512 bf16
  float* bqkv  = (float*)(wb + 10944512);          // 4,608 f32
  float* m4gn  = bqkv + 4608;                      // 32,768 f32

  auto mg64 = [&](dim3 grid, const u16* A, const u16* B, int K,
                  float* C, float* C2, u16* C16, i64 sCm, const float* bias,
                  int relu, int addres, int qkv, int M, int N, int mbsh, i64 bCz, int KS) {
    mgemm_k<64><<<grid, dim3(256), 0, stream>>>(A, B, K, C, C2, C16, sCm, bias,
        relu, addres, qkv, M, N, mbsh, bCz, KS, part);
  };

  // ---- all conversions + input transposes in ONE dispatch ----
  cvt_mega_k<<<dim3(12438), dim3(256), 0, stream>>>(
      pw0, pw1, pw2, buw0, buw1, woff, watt, wval, wout, w1, w2,
      boff, batt, bval, in0, in1, in2, wb, bqkv, abuf0, abuf1, abuf2);

  // ---- projection GEMMs ----
  mg64(dim3(64, 4, 1), abuf0, wb, 512, feats, nullptr, nullptr, 256, pb0, 0, 0, 0,
       8192, 256, 12, TC, 1);
  mg64(dim3(16, 4, 1), abuf1, wb + 131072, 1024, feats + (i64)4096 * 256, nullptr,
       nullptr, 256, pb1, 0, 0, 0, 2048, 256, 10, TC, 1);
  mg64(dim3(4, 4, 4), abuf2, wb + 393216, 2048, nullptr, nullptr, nullptr, 256,
       nullptr, 0, 0, 0, 512, 256, 8, 0, 4);
  red_im2col_k<<<dim3(512 + 9216), dim3(256), 0, stream>>>(
      part, feats + (i64)5120 * 256, pb2, TC, in2, abuf0);

  // ---- bottom-up conv0 GEMM ----
  mg64(dim3(1, 4, 16), abuf0, wb + 917504, 18432, nullptr, nullptr, nullptr, 256,
       nullptr, 0, 0, 0, 128, 256, 6, 0, 16);
  reduce_k<<<dim3(128), dim3(256), 0, stream>>>(part, feats + (i64)5376 * 256, bub0,
      6, TC, 256, 128, 256, 16);

  // ---- GN+ReLU, bottom-up conv1 ----
  gn_relu_k<<<dim3(8, 2), dim3(256), 0, stream>>>(feats, m4gn, gng, gnb);
  im2col_bf16_k<<<dim3(288), dim3(256), 0, stream>>>(m4gn, abuf0, 256, 8, 8, 4, 4);
  mg64(dim3(1, 4, 4), abuf0, wb + 5636096, 2304, nullptr, nullptr, nullptr, 256,
       nullptr, 0, 0, 0, 32, 256, 4, 0, 4);
  reduce_k<<<dim3(32), dim3(256), 0, stream>>>(part, feats + (i64)5440 * 256, bub1,
      4, TC, 256, 32, 256, 4);

  // ---- 6 transformer layers (LN1 of layers 1..5 fused into prior ffn) ----
  ln_k<<<dim3(2728), dim3(256), 0, stream>>>(feats, qb, ln1g, ln1b, BNROWS);
  for (int i = 0; i < NLAYERS; i++) {
    const u16* wbL = wb + 6225920 + (i64)i * 786432;
    mg64(dim3(86, 12, 1), qb, wbL, 256, (float*)off16, (float*)att16, valb, 0,
         bqkv + (i64)i * 768, 0, 0, 1, BNROWS, 768, 14, 0, 1);
    dsample_k<<<dim3(688, 2), dim3(256), 0, stream>>>(valb, off16, att16, sampb);
    mg64(dim3(86, 4, 1), sampb, wbL + 196608, 256, feats, nullptr, nullptr, 256,
         bout + (i64)i * 256, 0, 1, 0, BNROWS, 256, 14, 0, 1);
    int last = (i + 1 >= NLAYERS);
    ffn_fused_k<<<dim3(171), dim3(512), 0, stream>>>(feats, wbL + 262144,
        wbL + 524288, b1 + (i64)i * 1024, b2 + (i64)i * 256,
        ln2g + (i64)i * 256, ln2b + (i64)i * 256, BNROWS,
        last ? nullptr : qb,
        ln1g + (i64)(last ? 0 : i + 1) * 256,
        ln1b + (i64)(last ? 0 : i + 1) * 256);
  }

  // ---- split into 5 level maps (one dispatch) ----
  untranspose_all_k<<<dim3(171, 8, 2), dim3(256), 0, stream>>>(feats, out);
  (void)in_sizes; (void)n_in; (void)out_size; (void)ws_size;
}

// Round 26
// 831.338 us; speedup vs baseline: 1.0799x; 1.0007x over previous
//
#include <hip/hip_runtime.h>
#include <cstdint>

typedef long long i64;
typedef unsigned short u16;
typedef __attribute__((ext_vector_type(8))) short short8;
typedef __attribute__((ext_vector_type(8))) unsigned short us8;
typedef __attribute__((ext_vector_type(4))) float f32x4;

#define NTOK 5456
#define BNROWS 10912
#define NLAYERS 6

__device__ __forceinline__ u16 f2bf(float f) {
  unsigned u = __float_as_uint(f);
  return (u16)((u + 0x7FFFu + ((u >> 16) & 1u)) >> 16);
}
__device__ __forceinline__ float bf2f(u16 h) {
  return __uint_as_float(((unsigned)h) << 16);
}

// ---------------- bf16 MFMA GEMM, 2-phase double-buffered ----------------
template<int BNT>
__global__ __launch_bounds__(256) void mgemm_k(
    const u16* __restrict__ A, const u16* __restrict__ B, int K,
    float* __restrict__ C, float* __restrict__ C2, u16* __restrict__ C16, i64 sCm,
    const float* __restrict__ bias, int relu, int addres, int qkv,
    int M, int N, int mbsh, i64 bCz,
    int KS, float* __restrict__ part)
{
  constexpr int NW = BNT / 32;
  __shared__ u16 Asm[2][128 * 64];
  __shared__ u16 Bsm[2][BNT * 64];
  int tid = threadIdx.x;

  int bx = blockIdx.x, by = blockIdx.y;
  int gx = gridDim.x, gy = gridDim.y;
  int nwg = gx * gy;
  if (KS == 1 && nwg >= 16) {
    int lin = bx + gx * by;
    int xcd = lin & 7, k = lin >> 3;
    int q = nwg >> 3, r = nwg & 7;
    int f = (xcd < r) ? (xcd * (q + 1) + k) : (r * (q + 1) + (xcd - r) * q + k);
    bx = f / gy;
    by = f - bx * gy;
  }
  int m0 = bx * 128, n0 = by * BNT;

  int ks = blockIdx.z;
  int Kc = K / KS;
  int k0 = ks * Kc;
  int lane = tid & 63, w = tid >> 6;
  int wr = w >> 1, wc = w & 1;
  int r16 = lane & 15, g = lane >> 4;

  f32x4 acc[4][NW];
#pragma unroll
  for (int mi = 0; mi < 4; mi++)
#pragma unroll
    for (int nj = 0; nj < NW; nj++) acc[mi][nj] = (f32x4){0.f, 0.f, 0.f, 0.f};

  const u16* Ag = A + (i64)m0 * K + k0;
  const u16* Bg = B + (i64)n0 * K + k0;
  int nt = Kc >> 6;

  auto stage = [&](int buf, int kt) {
#pragma unroll
    for (int r = 0; r < 4; r++) {
      int s = r * 256 + tid;
      int row = s >> 3, c = s & 7;
      int cs = ((c ^ (row & 7)) << 3);
      __builtin_amdgcn_global_load_lds(
          (const __attribute__((address_space(1))) void*)(Ag + (i64)row * K + kt + cs),
          (__attribute__((address_space(3))) void*)(&Asm[buf][(r * 256 + (w << 6)) << 3]),
          16, 0, 0);
    }
#pragma unroll
    for (int r = 0; r < NW; r++) {
      int s = r * 256 + tid;
      int row = s >> 3, c = s & 7;
      int cs = ((c ^ (row & 7)) << 3);
      __builtin_amdgcn_global_load_lds(
          (const __attribute__((address_space(1))) void*)(Bg + (i64)row * K + kt + cs),
          (__attribute__((address_space(3))) void*)(&Bsm[buf][(r * 256 + (w << 6)) << 3]),
          16, 0, 0);
    }
  };

  stage(0, 0);
  __syncthreads();
  for (int t = 0; t < nt; t++) {
    int cur = t & 1;
    if (t + 1 < nt) stage(cur ^ 1, (t + 1) << 6);
#pragma unroll
    for (int h = 0; h < 2; h++) {
      short8 av[4], bv[NW];
#pragma unroll
      for (int mi = 0; mi < 4; mi++) {
        int row = wr * 64 + mi * 16 + r16;
        av[mi] = *(const short8*)&Asm[cur][row * 64 + ((((h << 2) + g) ^ (row & 7)) << 3)];
      }
#pragma unroll
      for (int nj = 0; nj < NW; nj++) {
        int row = wc * (NW * 16) + nj * 16 + r16;
        bv[nj] = *(const short8*)&Bsm[cur][row * 64 + ((((h << 2) + g) ^ (row & 7)) << 3)];
      }
#pragma unroll
      for (int mi = 0; mi < 4; mi++)
#pragma unroll
        for (int nj = 0; nj < NW; nj++)
          acc[mi][nj] = __builtin_amdgcn_mfma_f32_16x16x32_bf16(
              av[mi], bv[nj], acc[mi][nj], 0, 0, 0);
    }
    __syncthreads();
  }

  if (KS > 1) {
#pragma unroll
    for (int mi = 0; mi < 4; mi++)
#pragma unroll
      for (int nj = 0; nj < NW; nj++)
#pragma unroll
        for (int r = 0; r < 4; r++) {
          int grow = m0 + wr * 64 + mi * 16 + g * 4 + r;
          int gcol = n0 + wc * (NW * 16) + nj * 16 + r16;
          if (grow < M) part[((i64)ks * M + grow) * N + gcol] = acc[mi][nj][r];
        }
  } else if (qkv) {
    u16* off16 = (u16*)C;
    u16* att16 = (u16*)C2;
#pragma unroll
    for (int mi = 0; mi < 4; mi++)
#pragma unroll
      for (int nj = 0; nj < NW; nj++)
#pragma unroll
        for (int r = 0; r < 4; r++) {
          int grow = m0 + wr * 64 + mi * 16 + g * 4 + r;
          int gcol = n0 + wc * (NW * 16) + nj * 16 + r16;
          if (grow < M) {
            float v = acc[mi][nj][r] + bias[gcol];
            if (gcol < 320) off16[(i64)grow * 320 + gcol] = f2bf(v);
            else if (gcol < 480) att16[(i64)grow * 160 + (gcol - 320)] = f2bf(v);
            else if (gcol < 736) C16[(i64)grow * 256 + (gcol - 480)] = f2bf(v);
          }
        }
  } else {
    float bv[NW];
    int gc0 = n0 + wc * (NW * 16) + r16;
#pragma unroll
    for (int nj = 0; nj < NW; nj++)
      bv[nj] = bias ? bias[gc0 + nj * 16] : 0.f;
    int mask = (1 << mbsh) - 1;
#pragma unroll
    for (int mi = 0; mi < 4; mi++) {
#pragma unroll
      for (int r = 0; r < 4; r++) {
        int grow = m0 + wr * 64 + mi * 16 + g * 4 + r;
        if (grow >= M) continue;
        i64 rowb = (i64)(grow >> mbsh) * bCz + (i64)(grow & mask) * sCm;
#pragma unroll
        for (int nj = 0; nj < NW; nj++) {
          int gcol = gc0 + nj * 16;
          if (gcol >= N) continue;
          float v = acc[mi][nj][r] + bv[nj];
          if (relu) v = fmaxf(v, 0.f);
          i64 ci = rowb + gcol;
          if (C16) C16[ci] = f2bf(v);
          else {
            if (addres) v += C[ci];
            C[ci] = v;
          }
        }
      }
    }
  }
}

// ------ fused LN2+FFN v3 + next-layer LN1 epilogue / final output scatter --
__global__ __launch_bounds__(512, 1) void ffn_fused_k(
    float* __restrict__ feats, const u16* __restrict__ w1n,
    const u16* __restrict__ w2n, const float* __restrict__ b1,
    const float* __restrict__ b2, const float* __restrict__ lng,
    const float* __restrict__ lnb, int M,
    u16* __restrict__ qbo, const float* __restrict__ nlg,
    const float* __restrict__ nlb, float* __restrict__ outp)
{
  __shared__ u16 B1s[2][64 * 256];
  __shared__ u16 B2s[2][256 * 64];
  __shared__ u16 Hs[64 * 88];
  __shared__ float b1s[1024];
  u16* As = &B1s[1][0];

  int tid = threadIdx.x;
  int lane = tid & 63, w = tid >> 6;
  int wr = w >> 1, wc = w & 1;
  int r16 = lane & 15, g = lane >> 4;
  int m0 = blockIdx.x * 64;

  auto stageW = [&](int buf, int ch) {
#pragma unroll
    for (int r = 0; r < 4; r++) {
      int s = r * 512 + tid;
      int row = s >> 5, c = s & 31;
      int cs = ((c ^ (row & 7)) << 3);
      __builtin_amdgcn_global_load_lds(
          (const __attribute__((address_space(1))) void*)(w1n + (i64)(ch * 64 + row) * 256 + cs),
          (__attribute__((address_space(3))) void*)(&B1s[buf][(r * 512 + (w << 6)) << 3]),
          16, 0, 0);
    }
#pragma unroll
    for (int r = 0; r < 4; r++) {
      int s = r * 512 + tid;
      int row = s >> 3, c = s & 7;
      int cs = ((c ^ (row & 7)) << 3);
      __builtin_amdgcn_global_load_lds(
          (const __attribute__((address_space(1))) void*)(w2n + (i64)row * 1024 + ch * 64 + cs),
          (__attribute__((address_space(3))) void*)(&B2s[buf][(r * 512 + (w << 6)) << 3]),
          16, 0, 0);
    }
  };

  stageW(0, 0);
  for (int i = tid; i < 1024; i += 512) b1s[i] = b1[i];

  // LN2 on rows m0..m0+63: 8 lanes per row, 32 cols each
  {
    int rw = tid >> 3, c0 = (tid & 7) * 32;
    const float* fr = feats + (i64)(m0 + rw) * 256 + c0;
    float4 x[8];
    float s = 0.f, ss = 0.f;
#pragma unroll
    for (int j = 0; j < 8; j++) {
      x[j] = ((const float4*)fr)[j];
      s += x[j].x + x[j].y + x[j].z + x[j].w;
      ss += x[j].x * x[j].x + x[j].y * x[j].y + x[j].z * x[j].z + x[j].w * x[j].w;
    }
#pragma unroll
    for (int o = 1; o <= 4; o <<= 1) { s += __shfl_xor(s, o); ss += __shfl_xor(ss, o); }
    float mean = s * (1.f / 256.f);
    float rs = rsqrtf(ss * (1.f / 256.f) - mean * mean + 1e-5f);
    const float4* gp = (const float4*)(lng + c0);
    const float4* bp = (const float4*)(lnb + c0);
#pragma unroll
    for (int j = 0; j < 8; j += 2) {
      float4 g0 = gp[j], g1 = gp[j + 1];
      float4 b0 = bp[j], b1_ = bp[j + 1];
      us8 o;
      o[0] = f2bf((x[j].x - mean) * rs * g0.x + b0.x);
      o[1] = f2bf((x[j].y - mean) * rs * g0.y + b0.y);
      o[2] = f2bf((x[j].z - mean) * rs * g0.z + b0.z);
      o[3] = f2bf((x[j].w - mean) * rs * g0.w + b0.w);
      o[4] = f2bf((x[j + 1].x - mean) * rs * g1.x + b1_.x);
      o[5] = f2bf((x[j + 1].y - mean) * rs * g1.y + b1_.y);
      o[6] = f2bf((x[j + 1].z - mean) * rs * g1.z + b1_.z);
      o[7] = f2bf((x[j + 1].w - mean) * rs * g1.w + b1_.w);
      int gr = (tid & 7) * 4 + (j >> 1);
      *(us8*)&As[rw * 256 + ((gr ^ (rw & 7)) << 3)] = o;
    }
  }
  __syncthreads();

  short8 av_all[8];
  {
    int row = wr * 16 + r16;
#pragma unroll
    for (int ks = 0; ks < 8; ks++)
      av_all[ks] = *(const short8*)&As[row * 256 + (((ks * 4 + g) ^ (row & 7)) << 3)];
  }
  __syncthreads();

  f32x4 acc2[8];
#pragma unroll
  for (int nj = 0; nj < 8; nj++) acc2[nj] = (f32x4){0.f, 0.f, 0.f, 0.f};

  int cur = 0;
  for (int ch = 0; ch < 16; ch++) {
    if (ch + 1 < 16) stageW(cur ^ 1, ch + 1);

    f32x4 acc1[2];
#pragma unroll
    for (int nj = 0; nj < 2; nj++) acc1[nj] = (f32x4){0.f, 0.f, 0.f, 0.f};
#pragma unroll
    for (int ks = 0; ks < 8; ks++) {
      short8 bv[2];
#pragma unroll
      for (int nj = 0; nj < 2; nj++) {
        int row = wc * 32 + nj * 16 + r16;
        bv[nj] = *(const short8*)&B1s[cur][row * 256 + (((ks * 4 + g) ^ (row & 7)) << 3)];
      }
#pragma unroll
      for (int nj = 0; nj < 2; nj++)
        acc1[nj] = __builtin_amdgcn_mfma_f32_16x16x32_bf16(
            av_all[ks], bv[nj], acc1[nj], 0, 0, 0);
    }
#pragma unroll
    for (int nj = 0; nj < 2; nj++)
#pragma unroll
      for (int r = 0; r < 4; r++) {
        int hr = wr * 16 + g * 4 + r;
        int hc = wc * 32 + nj * 16 + r16;
        float v = acc1[nj][r] + b1s[ch * 64 + hc];
        Hs[hr * 88 + hc] = f2bf(fmaxf(v, 0.f));
      }
    __syncthreads();

#pragma unroll
    for (int hh = 0; hh < 2; hh++) {
      short8 av2 = *(const short8*)&Hs[(wr * 16 + r16) * 88 + hh * 32 + g * 8];
      short8 bv2[8];
#pragma unroll
      for (int nj = 0; nj < 8; nj++) {
        int n = wc * 128 + nj * 16 + r16;
        bv2[nj] = *(const short8*)&B2s[cur][n * 64 + (((hh * 4 + g) ^ (n & 7)) << 3)];
      }
#pragma unroll
      for (int nj = 0; nj < 8; nj++)
        acc2[nj] = __builtin_amdgcn_mfma_f32_16x16x32_bf16(
            av2, bv2[nj], acc2[nj], 0, 0, 0);
    }
    __syncthreads();
    cur ^= 1;
  }

  // epilogue: write feats (or final output maps); optional next-layer LN1.
  float* red = b1s;
  float vv[4][8];
#pragma unroll
  for (int r = 0; r < 4; r++) {
    int grow = m0 + wr * 16 + g * 4 + r;
    float s = 0.f, ss = 0.f;
    if (grow < M) {
      if (outp) {
        // final layer: scatter directly into the 5 level maps (skip feats)
        int bb = grow >= NTOK;
        int t = grow - bb * NTOK;
        int S, start; i64 ooff;
        if (t < 4096)      { S = 4096; start = 0;    ooff = 0; }
        else if (t < 5120) { S = 1024; start = 4096; ooff = 2097152; }
        else if (t < 5376) { S = 256;  start = 5120; ooff = 2621440; }
        else if (t < 5440) { S = 64;   start = 5376; ooff = 2752512; }
        else               { S = 16;   start = 5440; ooff = 2785280; }
        i64 base = ooff + ((i64)bb * 256) * (i64)S + (t - start);
#pragma unroll
        for (int nj = 0; nj < 8; nj++) {
          int col = wc * 128 + nj * 16 + r16;
          i64 ci = (i64)grow * 256 + col;
          outp[base + (i64)col * S] = feats[ci] + acc2[nj][r] + b2[col];
        }
      } else {
#pragma unroll
        for (int nj = 0; nj < 8; nj++) {
          int col = wc * 128 + nj * 16 + r16;
          i64 ci = (i64)grow * 256 + col;
          float v = feats[ci] + acc2[nj][r] + b2[col];
          feats[ci] = v;
          vv[r][nj] = v;
          s += v;
          ss += v * v;
        }
      }
    }
    if (qbo) {
#pragma unroll
      for (int o = 1; o <= 8; o <<= 1) { s += __shfl_xor(s, o); ss += __shfl_xor(ss, o); }
      if (r16 == 0) {
        int lr = wr * 16 + g * 4 + r;
        red[lr * 4 + wc * 2 + 0] = s;
        red[lr * 4 + wc * 2 + 1] = ss;
      }
    }
  }
  if (qbo) {
    __syncthreads();
#pragma unroll
    for (int r = 0; r < 4; r++) {
      int grow = m0 + wr * 16 + g * 4 + r;
      if (grow >= M) continue;
      int lr = wr * 16 + g * 4 + r;
      float s = red[lr * 4 + 0] + red[lr * 4 + 2];
      float ss = red[lr * 4 + 1] + red[lr * 4 + 3];
      float mean = s * (1.f / 256.f);
      float rs = rsqrtf(ss * (1.f / 256.f) - mean * mean + 1e-5f);
#pragma unroll
      for (int nj = 0; nj < 8; nj++) {
        int col = wc * 128 + nj * 16 + r16;
        qbo[(i64)grow * 256 + col] =
            f2bf((vv[r][nj] - mean) * rs * nlg[col] + nlb[col]);
      }
    }
  }
}

// reduce split-K fp32 partials (stride N); row map via shift/mask
__global__ void reduce_k(const float* __restrict__ part, float* __restrict__ C,
    const float* __restrict__ bias, int mbsh, i64 bCz, i64 sCm, int M, int N, int KS)
{
  int idx = blockIdx.x * 256 + threadIdx.x;
  if (idx >= M * N) return;
  int m = idx / N, n = idx - m * N;
  float v = bias ? bias[n] : 0.f;
  for (int ks = 0; ks < KS; ks++) v += part[((i64)ks * M + m) * N + n];
  C[(i64)(m >> mbsh) * bCz + (i64)(m & ((1 << mbsh) - 1)) * sCm + n] = v;
}

// ---------------- mega conversion (vectorized), ONE dispatch ---------------
__global__ __launch_bounds__(256) void cvt_mega_k(
    const float* __restrict__ pw0, const float* __restrict__ pw1,
    const float* __restrict__ pw2, const float* __restrict__ buw0,
    const float* __restrict__ buw1,
    const float* __restrict__ woff, const float* __restrict__ watt,
    const float* __restrict__ wval, const float* __restrict__ wout,
    const float* __restrict__ w1, const float* __restrict__ w2,
    const float* __restrict__ boff, const float* __restrict__ batt,
    const float* __restrict__ bval,
    const float* __restrict__ in0, const float* __restrict__ in1,
    const float* __restrict__ in2,
    u16* __restrict__ wb, float* __restrict__ bq,
    u16* __restrict__ a0, u16* __restrict__ a1, u16* __restrict__ a2)
{
  __shared__ float tile[32][129];
  int blk = blockIdx.x;

  if (blk < 6080) {
    int idx = (blk * 256 + threadIdx.x) * 4;
    float4 v;
    if (idx < 131072) v = *(const float4*)(pw0 + idx);
    else if (idx < 393216) v = *(const float4*)(pw1 + idx - 131072);
    else if (idx < 917504) v = *(const float4*)(pw2 + idx - 393216);
    else if (idx < 5636096) v = *(const float4*)(buw0 + idx - 917504);
    else v = *(const float4*)(buw1 + idx - 5636096);
    ushort4 o;
    o.x = f2bf(v.x); o.y = f2bf(v.y); o.z = f2bf(v.z); o.w = f2bf(v.w);
    *(ushort4*)(wb + idx) = o;
    return;
  }

  if (blk < 10646) {
    int lb = blk - 6080;
    int L = lb / 761, t = lb - L * 761;
    u16* wbL = wb + 6225920 + (i64)L * 786432;

    if (t == 760) {
      for (int idx = threadIdx.x; idx < 8192; idx += 256)
        wbL[736 * 256 + idx] = 0;
      for (int n = threadIdx.x; n < 768; n += 256) {
        float v;
        if (n < 320) v = boff[(i64)L * 320 + n];
        else if (n < 480) v = batt[(i64)L * 160 + (n - 320)];
        else if (n < 736) v = bval[(i64)L * 256 + (n - 480)];
        else v = 0.f;
        bq[(i64)L * 768 + n] = v;
      }
      return;
    }

    const float* src;
    u16* dst;
    int srcStride, dstStride, gxn, ti;
    if (t < 80)       { ti = t;       src = woff + (i64)L * 81920;  dst = wbL;            srcStride = 320;  dstStride = 256;  gxn = 10; }
    else if (t < 120) { ti = t - 80;  src = watt + (i64)L * 40960;  dst = wbL + 320 * 256; srcStride = 160;  dstStride = 256;  gxn = 5;  }
    else if (t < 184) { ti = t - 120; src = wval + (i64)L * 65536;  dst = wbL + 480 * 256; srcStride = 256;  dstStride = 256;  gxn = 8;  }
    else if (t < 248) { ti = t - 184; src = wout + (i64)L * 65536;  dst = wbL + 196608;   srcStride = 256;  dstStride = 256;  gxn = 8;  }
    else if (t < 504) { ti = t - 248; src = w1 + (i64)L * 262144;   dst = wbL + 262144;   srcStride = 1024; dstStride = 256;  gxn = 32; }
    else              { ti = t - 504; src = w2 + (i64)L * 262144;   dst = wbL + 524288;   srcStride = 256;  dstStride = 1024; gxn = 8;  }
    int n0 = (ti % gxn) * 32, k0 = (ti / gxn) * 32;

    int tx = threadIdx.x & 31, ty = threadIdx.x >> 5;
    for (int i = ty; i < 32; i += 8)
      tile[i][tx] = src[(i64)(k0 + i) * srcStride + n0 + tx];
    __syncthreads();
    for (int i = ty; i < 32; i += 8)
      dst[(i64)(n0 + i) * dstStride + k0 + tx] = f2bf(tile[tx][i]);
    return;
  }

  // input transposes: 32 k-rows x 128 p-cols per tile; float4 reads
  {
    int t = blk - 10646;
    const float* in;
    u16* outp;
    int K, P, gx, ti;
    if (t < 1024)      { ti = t;        in = in0; outp = a0; K = 512;  P = 4096; gx = 32; }
    else if (t < 1536) { ti = t - 1024; in = in1; outp = a1; K = 1024; P = 1024; gx = 8;  }
    else               { ti = t - 1536; in = in2; outp = a2; K = 2048; P = 256;  gx = 2;  }
    int gy = K >> 5;
    int b = ti / (gx * gy);
    int rem = ti - b * gx * gy;
    int p0 = (rem % gx) * 128, k0 = (rem / gx) * 32;
    const float* ib = in + (i64)b * K * P;

    int tx = threadIdx.x & 31, ty = threadIdx.x >> 5;
    for (int i = ty; i < 32; i += 8) {
      float4 v = *(const float4*)(ib + (i64)(k0 + i) * P + p0 + tx * 4);
      tile[i][tx * 4 + 0] = v.x;
      tile[i][tx * 4 + 1] = v.y;
      tile[i][tx * 4 + 2] = v.z;
      tile[i][tx * 4 + 3] = v.w;
    }
    __syncthreads();
    int tk = threadIdx.x & 7, pr = threadIdx.x >> 3;
    for (int it = 0; it < 4; it++) {
      int p = pr + it * 32;
      ushort4 o;
      o.x = f2bf(tile[tk * 4 + 0][p]);
      o.y = f2bf(tile[tk * 4 + 1][p]);
      o.z = f2bf(tile[tk * 4 + 2][p]);
      o.w = f2bf(tile[tk * 4 + 3][p]);
      *(ushort4*)(outp + ((i64)b * P + p0 + p) * K + k0 + tk * 4) = o;
    }
  }
}

// ---------------- fused: level-2 split-K reduce (512 blk) + conv0 im2col ---
__global__ void red_im2col_k(const float* __restrict__ part,
    float* __restrict__ C, const float* __restrict__ bias, i64 bCz,
    const float* __restrict__ in2, u16* __restrict__ colout)
{
  int t = blockIdx.x;
  if (t < 512) {
    int idx = t * 256 + threadIdx.x;
    int m = idx >> 8, n = idx & 255;
    float v = bias[n];
    for (int ks = 0; ks < 4; ks++) v += part[((i64)ks * 512 + m) * 256 + n];
    C[(i64)(m >> 8) * bCz + (i64)(m & 255) * 256 + n] = v;
    return;
  }
  i64 o = (i64)(t - 512) * 256 + threadIdx.x;
  const int Kk = 18432, hw = 64;
  int k = (int)(o % Kk);
  int m = (int)(o / Kk);
  int b = m / hw, pix = m - b * hw;
  int oy = pix >> 3, ox = pix & 7;
  int ci = k / 9, r = k - ci * 9;
  int ky = r / 3, kx = r - ky * 3;
  int iy = oy * 2 - 1 + ky, ix = ox * 2 - 1 + kx;
  float v = 0.f;
  if (iy >= 0 && iy < 16 && ix >= 0 && ix < 16)
    v = in2[(((i64)b * 2048 + ci) * 16 + iy) * 16 + ix];
  colout[o] = f2bf(v);
}

__global__ void im2col_bf16_k(const float* __restrict__ in, u16* __restrict__ out,
    int Cin, int Hin, int Win, int Ho, int Wo)
{
  int Kk = Cin * 9;
  i64 total = (i64)2 * Ho * Wo * Kk;
  i64 o = (i64)blockIdx.x * 256 + threadIdx.x;
  if (o >= total) return;
  int k = (int)(o % Kk);
  int m = (int)(o / Kk);
  int hw = Ho * Wo;
  int b = m / hw, pix = m - b * hw;
  int oy = pix / Wo, ox = pix - oy * Wo;
  int ci = k / 9, r = k - ci * 9;
  int ky = r / 3, kx = r - ky * 3;
  int iy = oy * 2 - 1 + ky, ix = ox * 2 - 1 + kx;
  float v = 0.f;
  if (iy >= 0 && iy < Hin && ix >= 0 && ix < Win)
    v = in[(((i64)b * Cin + ci) * Hin + iy) * Win + ix];
  out[o] = f2bf(v);
}

__global__ void gn_relu_k(const float* __restrict__ feats, float* __restrict__ y,
    const float* __restrict__ g, const float* __restrict__ bt)
{
  int grp = blockIdx.x, b = blockIdx.y;
  int tid = threadIdx.x;
  const float* fb = feats + ((i64)b * NTOK + 5376) * 256 + grp * 32;
  float s = 0.f, ss = 0.f;
  for (int i = tid; i < 2048; i += 256) {
    int cl = i >> 6, p = i & 63;
    float v = fb[(i64)p * 256 + cl];
    s += v; ss += v * v;
  }
  __shared__ float sb[4], ssb[4];
#pragma unroll
  for (int o = 32; o > 0; o >>= 1) { s += __shfl_down(s, o); ss += __shfl_down(ss, o); }
  int wv = tid >> 6;
  if ((tid & 63) == 0) { sb[wv] = s; ssb[wv] = ss; }
  __syncthreads();
  float ts = sb[0] + sb[1] + sb[2] + sb[3];
  float tss = ssb[0] + ssb[1] + ssb[2] + ssb[3];
  float mean = ts * (1.f / 2048.f);
  float rs = rsqrtf(tss * (1.f / 2048.f) - mean * mean + 1e-5f);
  for (int i = tid; i < 2048; i += 256) {
    int cl = i >> 6, p = i & 63;
    int c = grp * 32 + cl;
    float v = (fb[(i64)p * 256 + cl] - mean) * rs * g[c] + bt[c];
    y[((i64)b * 256 + c) * 64 + p] = fmaxf(v, 0.f);
  }
}

__global__ __launch_bounds__(256) void ln_k(const float* __restrict__ x,
    u16* __restrict__ y, const float* __restrict__ g, const float* __restrict__ bt,
    int rows)
{
  int row = blockIdx.x * 4 + (threadIdx.x >> 6);
  if (row >= rows) return;
  int lane = threadIdx.x & 63;
  float4 v = ((const float4*)(x + (i64)row * 256))[lane];
  float s = v.x + v.y + v.z + v.w;
  float ss = v.x * v.x + v.y * v.y + v.z * v.z + v.w * v.w;
#pragma unroll
  for (int o = 32; o > 0; o >>= 1) { s += __shfl_down(s, o); ss += __shfl_down(ss, o); }
  s = __shfl(s, 0);
  ss = __shfl(ss, 0);
  float mean = s * (1.f / 256.f);
  float rs = rsqrtf(ss * (1.f / 256.f) - mean * mean + 1e-5f);
  float4 gg = ((const float4*)g)[lane];
  float4 bb = ((const float4*)bt)[lane];
  ushort4 o4;
  o4.x = f2bf((v.x - mean) * rs * gg.x + bb.x);
  o4.y = f2bf((v.y - mean) * rs * gg.y + bb.y);
  o4.z = f2bf((v.z - mean) * rs * gg.z + bb.z);
  o4.w = f2bf((v.w - mean) * rs * gg.w + bb.w);
  ((ushort4*)(y + (i64)row * 256))[lane] = o4;
}

// deformable sampling v5 (known-good)
__global__ __launch_bounds__(256) void dsample_k(
    const u16* __restrict__ val, const u16* __restrict__ off,
    const u16* __restrict__ att, u16* __restrict__ out)
{
  const int FH[5] = {64, 32, 16, 8, 4};
  const int ST[5] = {0, 4096, 5120, 5376, 5440};
  int bid = blockIdx.x;
  int chunk = (bid & 7) * 86 + (bid >> 3);
  if (chunk >= 682) return;
  int lane = threadIdx.x & 63;
  int half = lane >> 5;
  int l32 = lane & 31;
  int t = chunk * 8 + ((threadIdx.x >> 6) << 1) + half;
  int b = blockIdx.y;
  int h = l32 >> 2, d4 = l32 & 3;

  int lv;
  if (t < 4096)      lv = 0;
  else if (t < 5120) lv = 1;
  else if (t < 5376) lv = 2;
  else if (t < 5440) lv = 3;
  else               lv = 4;
  int loc = t - ST[lv];
  int sh = 6 - lv;
  int py = loc >> sh, px = loc - (py << sh);
  float inv = 1.f / (float)FH[lv];
  float prx = (px + 0.5f) * inv, pry = (py + 0.5f) * inv;
  i64 bt = (i64)b * NTOK + t;
  const u16* offp = off + bt * 320 + h * 40;
  const u16* attp = att + bt * 160 + h * 20;
  const u16* vbase = val + ((i64)b * NTOK) * 256 + h * 32 + d4 * 8;

  float own_a[5], own_fx[5], own_fy[5];
  int own_pk[5];
  float mx = -1e30f;
#pragma unroll
  for (int j = 0; j < 5; j++) {
    float lg = bf2f(attp[d4 + 4 * j]);
    own_a[j] = lg;
    mx = fmaxf(mx, lg);
  }
  mx = fmaxf(mx, __shfl_xor(mx, 1));
  mx = fmaxf(mx, __shfl_xor(mx, 2));
  float sum = 0.f;
#pragma unroll
  for (int j = 0; j < 5; j++) {
    float e = __expf(own_a[j] - mx);
    own_a[j] = e;
    sum += e;
  }
  sum += __shfl_xor(sum, 1);
  sum += __shfl_xor(sum, 2);
  float rinv = 1.f / sum;
#pragma unroll
  for (int j = 0; j < 5; j++) {
    int p = d4 + 4 * j;
    own_a[j] *= rinv;
    unsigned opk = *(const unsigned*)(offp + 2 * p);
    float ox = bf2f((u16)(opk & 0xFFFF));
    float oy = bf2f((u16)(opk >> 16));
    float sff = (float)(64 >> j);
    float xx = prx * sff + ox - 0.5f;
    float yy = pry * sff + oy - 0.5f;
    float xf = floorf(xx), yf = floorf(yy);
    own_fx[j] = xx - xf;
    own_fy[j] = yy - yf;
    own_pk[j] = (((int)yf) << 16) | (((int)xf) & 0xFFFF);
  }

  float acc[8] = {0.f, 0.f, 0.f, 0.f, 0.f, 0.f, 0.f, 0.f};
#pragma unroll
  for (int p = 0; p < 20; p++) {
    const int j = p >> 2;
    const int sf = FH[j], st = ST[j];
    int src = (half << 5) | (h << 2) | (p & 3);
    float wa = __shfl(own_a[j], src);
    float fx = __shfl(own_fx[j], src);
    float fy = __shfl(own_fy[j], src);
    int pk = __shfl(own_pk[j], src);
    int x0 = (pk << 16) >> 16;
    int y0 = pk >> 16;
    float gx0 = wa - wa * fx, gx1 = wa * fx;
    float w00 = gx0 - gx0 * fy, w01 = gx0 * fy;
    float w10 = gx1 - gx1 * fy, w11 = gx1 * fy;
    bool xin0 = (x0 >= 0) & (x0 < sf), xin1 = (x0 + 1 >= 0) & (x0 + 1 < sf);
    bool yin0 = (y0 >= 0) & (y0 < sf), yin1 = (y0 + 1 >= 0) & (y0 + 1 < sf);
    int ibase = st + y0 * sf + x0;
#define FMA8(W, IDX) { \
      us8 v = *(const us8*)(vbase + (i64)(IDX) * 256); \
      acc[0] = fmaf(W, bf2f(v[0]), acc[0]); acc[1] = fmaf(W, bf2f(v[1]), acc[1]); \
      acc[2] = fmaf(W, bf2f(v[2]), acc[2]); acc[3] = fmaf(W, bf2f(v[3]), acc[3]); \
      acc[4] = fmaf(W, bf2f(v[4]), acc[4]); acc[5] = fmaf(W, bf2f(v[5]), acc[5]); \
      acc[6] = fmaf(W, bf2f(v[6]), acc[6]); acc[7] = fmaf(W, bf2f(v[7]), acc[7]); }
    if (xin0 & yin0) FMA8(w00, ibase);
    if (xin1 & yin0) FMA8(w10, ibase + 1);
    if (xin0 & yin1) FMA8(w01, ibase + sf);
    if (xin1 & yin1) FMA8(w11, ibase + sf + 1);
#undef FMA8
  }
  us8 o;
#pragma unroll
  for (int i = 0; i < 8; i++) o[i] = f2bf(acc[i]);
  *(us8*)(out + ((bt * 8 + h) * 32 + d4 * 8)) = o;
}

extern "C" void kernel_launch(void* const* d_in, const int* in_sizes, int n_in,
                              void* d_out, int out_size, void* d_ws, size_t ws_size,
                              hipStream_t stream)
{
  const float* in0  = (const float*)d_in[0];
  const float* in1  = (const float*)d_in[1];
  const float* in2  = (const float*)d_in[2];
  const float* pw0  = (const float*)d_in[3];
  const float* pb0  = (const float*)d_in[4];
  const float* pw1  = (const float*)d_in[5];
  const float* pb1  = (const float*)d_in[6];
  const float* pw2  = (const float*)d_in[7];
  const float* pb2  = (const float*)d_in[8];
  const float* buw0 = (const float*)d_in[9];
  const float* bub0 = (const float*)d_in[10];
  const float* gng  = (const float*)d_in[11];
  const float* gnb  = (const float*)d_in[12];
  const float* buw1 = (const float*)d_in[13];
  const float* bub1 = (const float*)d_in[14];
  const float* ln1g = (const float*)d_in[15];
  const float* ln1b = (const float*)d_in[16];
  const float* woff = (const float*)d_in[17];
  const float* boff = (const float*)d_in[18];
  const float* watt = (const float*)d_in[19];
  const float* batt = (const float*)d_in[20];
  const float* wval = (const float*)d_in[21];
  const float* bval = (const float*)d_in[22];
  const float* wout = (const float*)d_in[23];
  const float* bout = (const float*)d_in[24];
  const float* ln2g = (const float*)d_in[25];
  const float* ln2b = (const float*)d_in[26];
  const float* w1   = (const float*)d_in[27];
  const float* b1   = (const float*)d_in[28];
  const float* w2   = (const float*)d_in[29];
  const float* b2   = (const float*)d_in[30];
  float* out = (float*)d_out;

  const i64 TC = (i64)NTOK * 256;

  // ---- ws layout (f32 units) ----
  float* ws    = (float*)d_ws;
  float* feats = ws;                               // 2,793,472
  u16*   qb    = (u16*)(feats + 2793472);          // 11008x256 bf16
  u16*   valb  = qb + 2818048;
  u16*   sampb = valb + 2818048;
  float* U     = (float*)(sampb + 2818048);        // union region: 5,637,120 f32
  u16*   off16 = (u16*)U;                          // [10912][320] bf16
  u16*   att16 = off16 + 3491840;                  // [10912][160] bf16
  u16*   abuf0 = (u16*)U;                          // in0 A: 4,194,304 u16
  u16*   abuf1 = abuf0 + 4194304;                  // in1 A: 2,097,152 u16
  u16*   abuf2 = abuf1 + 2097152;                  // in2 A: 1,048,576 u16
  float* part  = U + 3670016;                      // split-K partials (<=524,288 f32)
  u16*   wb    = (u16*)(U + 5637120);              // 10,944,512 bf16
  float* bqkv  = (float*)(wb + 10944512);          // 4,608 f32
  float* m4gn  = bqkv + 4608;                      // 32,768 f32

  auto mg64 = [&](dim3 grid, const u16* A, const u16* B, int K,
                  float* C, float* C2, u16* C16, i64 sCm, const float* bias,
                  int relu, int addres, int qkv, int M, int N, int mbsh, i64 bCz, int KS) {
    mgemm_k<64><<<grid, dim3(256), 0, stream>>>(A, B, K, C, C2, C16, sCm, bias,
        relu, addres, qkv, M, N, mbsh, bCz, KS, part);
  };

  // ---- all conversions + input transposes in ONE dispatch ----
  cvt_mega_k<<<dim3(12438), dim3(256), 0, stream>>>(
      pw0, pw1, pw2, buw0, buw1, woff, watt, wval, wout, w1, w2,
      boff, batt, bval, in0, in1, in2, wb, bqkv, abuf0, abuf1, abuf2);

  // ---- projection GEMMs ----
  mg64(dim3(64, 4, 1), abuf0, wb, 512, feats, nullptr, nullptr, 256, pb0, 0, 0, 0,
       8192, 256, 12, TC, 1);
  mg64(dim3(16, 4, 1), abuf1, wb + 131072, 1024, feats + (i64)4096 * 256, nullptr,
       nullptr, 256, pb1, 0, 0, 0, 2048, 256, 10, TC, 1);
  mg64(dim3(4, 4, 4), abuf2, wb + 393216, 2048, nullptr, nullptr, nullptr, 256,
       nullptr, 0, 0, 0, 512, 256, 8, 0, 4);
  red_im2col_k<<<dim3(512 + 9216), dim3(256), 0, stream>>>(
      part, feats + (i64)5120 * 256, pb2, TC, in2, abuf0);

  // ---- bottom-up conv0 GEMM ----
  mg64(dim3(1, 4, 16), abuf0, wb + 917504, 18432, nullptr, nullptr, nullptr, 256,
       nullptr, 0, 0, 0, 128, 256, 6, 0, 16);
  reduce_k<<<dim3(128), dim3(256), 0, stream>>>(part, feats + (i64)5376 * 256, bub0,
      6, TC, 256, 128, 256, 16);

  // ---- GN+ReLU, bottom-up conv1 ----
  gn_relu_k<<<dim3(8, 2), dim3(256), 0, stream>>>(feats, m4gn, gng, gnb);
  im2col_bf16_k<<<dim3(288), dim3(256), 0, stream>>>(m4gn, abuf0, 256, 8, 8, 4, 4);
  mg64(dim3(1, 4, 4), abuf0, wb + 5636096, 2304, nullptr, nullptr, nullptr, 256,
       nullptr, 0, 0, 0, 32, 256, 4, 0, 4);
  reduce_k<<<dim3(32), dim3(256), 0, stream>>>(part, feats + (i64)5440 * 256, bub1,
      4, TC, 256, 32, 256, 4);

  // ---- 6 transformer layers (LN1 of 1..5 fused; last layer writes out) ----
  ln_k<<<dim3(2728), dim3(256), 0, stream>>>(feats, qb, ln1g, ln1b, BNROWS);
  for (int i = 0; i < NLAYERS; i++) {
    const u16* wbL = wb + 6225920 + (i64)i * 786432;
    mg64(dim3(86, 12, 1), qb, wbL, 256, (float*)off16, (float*)att16, valb, 0,
         bqkv + (i64)i * 768, 0, 0, 1, BNROWS, 768, 14, 0, 1);
    dsample_k<<<dim3(688, 2), dim3(256), 0, stream>>>(valb, off16, att16, sampb);
    mg64(dim3(86, 4, 1), sampb, wbL + 196608, 256, feats, nullptr, nullptr, 256,
         bout + (i64)i * 256, 0, 1, 0, BNROWS, 256, 14, 0, 1);
    int last = (i + 1 >= NLAYERS);
    ffn_fused_k<<<dim3(171), dim3(512), 0, stream>>>(feats, wbL + 262144,
        wbL + 524288, b1 + (i64)i * 1024, b2 + (i64)i * 256,
        ln2g + (i64)i * 256, ln2b + (i64)i * 256, BNROWS,
        last ? nullptr : qb,
        ln1g + (i64)(last ? 0 : i + 1) * 256,
        ln1b + (i64)(last ? 0 : i + 1) * 256,
        last ? out : nullptr);
  }
  (void)in_sizes; (void)n_in; (void)out_size; (void)ws_size;
}